// Round 9
// baseline (233.648 us; speedup 1.0000x reference)
//
#include <hip/hip_runtime.h>
#include <hip/hip_bf16.h>
#include <math.h>

// ---------------------------------------------------------------------------
// Problem constants
// ---------------------------------------------------------------------------
constexpr int B = 8;
constexpr int N = 2048;
constexpr int KNN = 20;
constexpr int H = 128;
constexpr int P = 3 * N;  // 6144 pixels per batch

// ws layout (float offsets)
constexpr int OWNPOS = 0;         // 64x3 normalized W_pos (pad 256)
constexpr int OWT2   = 8448;      // W2/D2 second-half TRANSPOSED [c<128][m<256] (32768)
constexpr int OWT3   = 41216;     // W3/D3 second-half transposed (32768)
constexpr int OPS1   = 73984;     // poolsum1 shadows [8][B][128][3] = 24576
constexpr int OPS2   = 98560;     // poolsum2 shadows = 24576
constexpr int OOUTS  = 123136;    // out shadows [8][B][384] = 24576
constexpr int OWB1   = 160000;    // Wbig1 256x128 bf16 hi/lo (16384 f)
constexpr int OWB2   = 176384;    // Wbig2 256x256 bf16 hi/lo (32768 f)
constexpr int OWB3   = 209152;    // Wbig3 256x256 bf16 hi/lo (32768 f)
constexpr int OIDX   = 241920;    // knn idx: 8*2048*20 ints = 327680
constexpr int OXP0   = 569600;    // Xp0 bf16 [b][P][128] (3145728 f-equiv)
constexpr int OXP2   = 569600;    // Xp2 bf16 [b][P][256] reuses Xp0 region
constexpr int OXP1   = 6861056;   // Xp1 bf16 [b][P][256] (6291456 f-equiv)
// max extent 13,152,512 floats ~= 52.6 MB

constexpr int ZERO_BASE = OPS1;   // prep zeroes [OPS1, OPS1+73728) = ps1+ps2+outs
constexpr int ZERO_CNT  = 73728;
constexpr int PREP_BLOCKS = 208;  // 832 waves = 832 rows

typedef __attribute__((ext_vector_type(8))) short bf16x8;
typedef __attribute__((ext_vector_type(4))) float f32x4;

__device__ __forceinline__ unsigned short f2bf(float x) {
  __hip_bfloat16 h = __float2bfloat16(x);
  return *(unsigned short*)&h;
}
__device__ __forceinline__ float bf2f(unsigned short u) {
  __hip_bfloat16 h;
  *(unsigned short*)&h = u;
  return __bfloat162float(h);
}
// pack x as (hi, lo) bf16 pair in one uint (hi at lower address)
__device__ __forceinline__ unsigned int packhl(float x) {
  unsigned short hi = f2bf(x);
  float lo = x - bf2f(hi);
  unsigned short ls = f2bf(lo);
  return (unsigned)hi | ((unsigned)ls << 16);
}

// ---------------------------------------------------------------------------
// Wave-wide bitonic sort of 64 (value,index) pairs, descending, tie->low idx.
// ---------------------------------------------------------------------------
__device__ __forceinline__ void wave_sort64(float& v, int& m, int lane) {
#pragma unroll
  for (int k = 2; k <= 64; k <<= 1) {
#pragma unroll
    for (int j = k >> 1; j > 0; j >>= 1) {
      float pv = __shfl_xor(v, j);
      int   pm = __shfl_xor(m, j);
      bool iam_lower   = (lane & j) == 0;
      bool dir_desc    = (lane & k) == 0;
      bool p_better    = (pv > v) || (pv == v && pm < m);
      bool want_better = (dir_desc == iam_lower);
      bool take        = (p_better == want_better);
      v = take ? pv : v;
      m = take ? pm : m;
    }
  }
}

// ---------------------------------------------------------------------------
// K1 (fused prep): zero shadows; normalize W rows; emit bf16 hi/lo packed
// first-C cols (stacked [Wn;D]); emit fp32 TRANSPOSED second-half cols.
// ---------------------------------------------------------------------------
__global__ __launch_bounds__(256) void prep_kernel(
    const float* __restrict__ Wpos, const float* __restrict__ W1,
    const float* __restrict__ D1, const float* __restrict__ W2,
    const float* __restrict__ D2, const float* __restrict__ W3,
    const float* __restrict__ D3, float* __restrict__ ws) {
  for (int i = blockIdx.x * 256 + threadIdx.x; i < ZERO_CNT; i += PREP_BLOCKS * 256)
    ws[ZERO_BASE + i] = 0.f;

  int r = blockIdx.x * 4 + (threadIdx.x >> 6);
  int lane = threadIdx.x & 63;
  const float* src;
  float* fdst = nullptr;
  float* tdst = nullptr;
  unsigned int* pdst = nullptr;
  int C, Cpack;
  bool norm = true;
  if (r < 64)       { src = Wpos + r * 3; fdst = ws + OWNPOS + r * 3; C = 3; Cpack = 0; }
  else if (r < 192) { int m = r - 64;  src = W1 + m * 64;  C = 64;  Cpack = 64;
                      pdst = (unsigned int*)(ws + OWB1) + m * 64; }
  else if (r < 320) { int m = r - 192; src = D1 + m * 64;  C = 64;  Cpack = 64; norm = false;
                      pdst = (unsigned int*)(ws + OWB1) + (m + 128) * 64; }
  else if (r < 448) { int m = r - 320; src = W2 + m * 256; C = 256; Cpack = 128;
                      pdst = (unsigned int*)(ws + OWB2) + m * 128;
                      tdst = ws + OWT2 + m; }
  else if (r < 576) { int m = r - 448; src = D2 + m * 256; C = 256; Cpack = 128; norm = false;
                      pdst = (unsigned int*)(ws + OWB2) + (m + 128) * 128;
                      tdst = ws + OWT2 + 128 + m; }
  else if (r < 704) { int m = r - 576; src = W3 + m * 256; C = 256; Cpack = 128;
                      pdst = (unsigned int*)(ws + OWB3) + m * 128;
                      tdst = ws + OWT3 + m; }
  else              { int m = r - 704; src = D3 + m * 256; C = 256; Cpack = 128; norm = false;
                      pdst = (unsigned int*)(ws + OWB3) + (m + 128) * 128;
                      tdst = ws + OWT3 + 128 + m; }

  float s = 1.f;
  if (norm) {
    float a = 0.f;
    for (int i = lane; i < C; i += 64) a += src[i];
#pragma unroll
    for (int off = 32; off > 0; off >>= 1) a += __shfl_xor(a, off);
    s = a;
  }
  for (int i = lane; i < C; i += 64) {
    float val = src[i] / s;  // exact when s==1
    if (fdst) fdst[i] = val;
    if (pdst && i < Cpack) pdst[i] = packhl(val);
    if (tdst && i >= 128) tdst[(i - 128) * 256] = val;
  }
}

// ---------------------------------------------------------------------------
// K2: exact top-20 KNN (unchanged from round 8).
// ---------------------------------------------------------------------------
__global__ __launch_bounds__(256, 4) void knn_kernel(const float* __restrict__ pc,
                                                     int* __restrict__ idxout) {
  __shared__ float4 spt[N];
  __shared__ unsigned short sbuf[4][512];
  int tid = threadIdx.x;
  int b = blockIdx.y;
  const float* pcb = pc + b * N * 3;
  for (int i = tid; i < N; i += 256) {
    float x = pcb[i * 3 + 0], y = pcb[i * 3 + 1], z = pcb[i * 3 + 2];
    float xx = __fadd_rn(__fadd_rn(__fmul_rn(x, x), __fmul_rn(y, y)), __fmul_rn(z, z));
    spt[i] = make_float4(2.f * x, 2.f * y, 2.f * z, xx);
  }
  __syncthreads();
  int wv = tid >> 6, lane = tid & 63;
  int q = blockIdx.x * 4 + wv;
  float4 qp = spt[q];
  float qx = 0.5f * qp.x, qy = 0.5f * qp.y, qz = 0.5f * qp.z, qxx = qp.w;

  float dv[32];
  float lmax = -INFINITY;
#pragma unroll
  for (int i = 0; i < 32; ++i) {
    float4 m = spt[i * 64 + lane];
    float A = __fadd_rn(__fadd_rn(__fmul_rn(m.x, qx), __fmul_rn(m.y, qy)),
                        __fmul_rn(m.z, qz));
    float d = __fsub_rn(__fsub_rn(A, qxx), m.w);
    dv[i] = d;
    lmax = fmaxf(lmax, d);
  }

  // value-only bitonic sort (descending) of the 64 lane-maxes; take #19
  float sv = lmax;
#pragma unroll
  for (int k = 2; k <= 64; k <<= 1) {
#pragma unroll
    for (int j = k >> 1; j > 0; j >>= 1) {
      float pv = __shfl_xor(sv, j);
      bool keep_max = ((lane & k) == 0) == ((lane & j) == 0);
      sv = keep_max ? fmaxf(sv, pv) : fminf(sv, pv);
    }
  }
  float tval = __shfl(sv, 19);  // 20th-largest lane-max <= V20 (provable)

  int base = 0;
#pragma unroll
  for (int i = 0; i < 32; ++i) {
    bool s = dv[i] >= tval;
    unsigned long long mk = __ballot(s);
    if (s) {
      int pos = base + (int)__popcll(mk & ((1ull << lane) - 1ull));
      if (pos < 512) sbuf[wv][pos] = (unsigned short)(i * 64 + lane);
    }
    base += (int)__popcll(mk);
  }
  int S = base;

  auto distOf = [&](int m) -> float {
    float4 mp = spt[m];
    float A = __fadd_rn(__fadd_rn(__fmul_rn(mp.x, qx), __fmul_rn(mp.y, qy)),
                        __fmul_rn(mp.z, qz));
    return __fsub_rn(__fsub_rn(A, qxx), mp.w);
  };

  float cv = -INFINITY;
  int cm = 0x7fffffff;
  if (S <= 64) {
    if (lane < S) { cm = sbuf[wv][lane]; cv = distOf(cm); }
    wave_sort64(cv, cm, lane);
  } else if (S <= 512) {
    int pos = 0;
    while (pos < S) {
      if (lane >= KNN) {
        int t = pos + lane - KNN;
        if (t < S) { cm = sbuf[wv][t]; cv = distOf(cm); }
        else       { cm = 0x7fffffff;  cv = -INFINITY; }
      }
      wave_sort64(cv, cm, lane);
      pos += 64 - KNN;
    }
  } else {
    int pos = 0;
    while (pos < N) {
      if (lane >= KNN) {
        int t = pos + lane - KNN;
        if (t < N) { cm = t; cv = distOf(t); }
        else       { cm = 0x7fffffff; cv = -INFINITY; }
      }
      wave_sort64(cv, cm, lane);
      pos += 64 - KNN;
    }
  }
  if (lane < KNN) idxout[(b * N + q) * KNN + lane] = cm;
}

// ---------------------------------------------------------------------------
// K3: edge features -> pos layer (64ch) -> VN-LeakyReLU -> mean over k ->
// direct bf16 hi/lo pack into Xp0.  Point cloud staged in LDS.
// ---------------------------------------------------------------------------
__global__ __launch_bounds__(256) void edge_pos_kernel(
    const float* __restrict__ pc, const int* __restrict__ knn,
    const float* __restrict__ Wn, const float* __restrict__ Dp,
    unsigned short* __restrict__ Xp0) {
  __shared__ float sp[N * 3];  // 24 KB
  int tid = threadIdx.x;
  int og = blockIdx.x, nt = blockIdx.y, b = blockIdx.z;
  const float* pcb = pc + (size_t)b * N * 3;
  for (int i = tid; i < N * 3; i += 256) sp[i] = pcb[i];
  __syncthreads();

  int n = nt * 256 + tid;
  float cx = sp[n * 3 + 0], cy = sp[n * 3 + 1], cz = sp[n * 3 + 2];

  float w[4][3], dw[4][3], acc[3][4];
#pragma unroll
  for (int j = 0; j < 4; ++j) {
    int o = og * 4 + j;
    w[j][0] = Wn[o * 3 + 0]; w[j][1] = Wn[o * 3 + 1]; w[j][2] = Wn[o * 3 + 2];
    dw[j][0] = Dp[o * 3 + 0]; dw[j][1] = Dp[o * 3 + 1]; dw[j][2] = Dp[o * 3 + 2];
    acc[0][j] = 0.f; acc[1][j] = 0.f; acc[2][j] = 0.f;
  }
  const int4* kn4 = (const int4*)(knn + ((size_t)b * N + n) * KNN);
  int kidx[20];
#pragma unroll
  for (int t = 0; t < 5; ++t) {
    int4 kv = kn4[t];
    kidx[t * 4 + 0] = kv.x; kidx[t * 4 + 1] = kv.y;
    kidx[t * 4 + 2] = kv.z; kidx[t * 4 + 3] = kv.w;
  }
#pragma unroll 4
  for (int k = 0; k < KNN; ++k) {
    int m = kidx[k];
    float nx = sp[m * 3 + 0], ny = sp[m * 3 + 1], nz = sp[m * 3 + 2];
    float ex = nx - cx, ey = ny - cy, ez = nz - cz;
    float rx = ny * cz - nz * cy;
    float ry = nz * cx - nx * cz;
    float rz = nx * cy - ny * cx;
#pragma unroll
    for (int j = 0; j < 4; ++j) {
      float px = fmaf(w[j][0], ex, fmaf(w[j][1], cx, w[j][2] * rx));
      float py = fmaf(w[j][0], ey, fmaf(w[j][1], cy, w[j][2] * ry));
      float pz = fmaf(w[j][0], ez, fmaf(w[j][1], cz, w[j][2] * rz));
      float dx = fmaf(dw[j][0], ex, fmaf(dw[j][1], cx, dw[j][2] * rx));
      float dy = fmaf(dw[j][0], ey, fmaf(dw[j][1], cy, dw[j][2] * ry));
      float dz = fmaf(dw[j][0], ez, fmaf(dw[j][1], cz, dw[j][2] * rz));
      float dot = fmaf(px, dx, fmaf(py, dy, pz * dz));
      float dns = fmaf(dx, dx, fmaf(dy, dy, dz * dz));
      float f = (dot < 0.f) ? dot / (dns + 1e-6f) : 0.f;
      acc[0][j] += px - f * dx;
      acc[1][j] += py - f * dy;
      acc[2][j] += pz - f * dz;
    }
  }
  int pbase = ((n >> 4) * 48) + (n & 15);
#pragma unroll
  for (int v = 0; v < 3; ++v) {
    uint4 vv;
    vv.x = packhl(acc[v][0] * (1.f / 20.f));
    vv.y = packhl(acc[v][1] * (1.f / 20.f));
    vv.z = packhl(acc[v][2] * (1.f / 20.f));
    vv.w = packhl(acc[v][3] * (1.f / 20.f));
    *(uint4*)(Xp0 + ((size_t)b * P + pbase + v * 16) * 128 + og * 8) = vv;
  }
}

// ---------------------------------------------------------------------------
// K9: merge 8 out shadows -> d_out (mean over N).
// ---------------------------------------------------------------------------
__global__ __launch_bounds__(256) void out_merge_kernel(
    const float* __restrict__ outs, float* __restrict__ out) {
  int idx = blockIdx.x * 256 + threadIdx.x;  // 3072
  if (idx >= B * 384) return;
  float s = 0.f;
#pragma unroll
  for (int k = 0; k < 8; ++k) s += outs[k * 3072 + idx];
  out[idx] = s * (1.f / 2048.f);
}

// ---------------------------------------------------------------------------
// K4/K6/K8: MFMA VNT layer, v2: NO LDS staging for X.  B-fragments are read
// directly from global (per (pixel,ks) the 4 q-frags cover exactly one 64B
// line, so traffic == staged version but overlapped with MFMA).  A and B
// both 1-deep software-pipelined.  K-loop has no barriers.  LDS holds only
// the fp32 out-tile (+ bias for HASPOOL).  Epilogue unchanged: out-tile ->
// lane-dense shadow atomics + coalesced Xq pack.
// ---------------------------------------------------------------------------
template <int K2, bool HASPOOL, bool LAST>
__global__ __launch_bounds__(256, 4) void gemm_vnt_kernel(
    const unsigned short* __restrict__ Xp, const unsigned short* __restrict__ Wb,
    const float* __restrict__ ps, const float* __restrict__ Wt,
    unsigned short* __restrict__ Xq, float* __restrict__ pool,
    float* __restrict__ outs) {
  constexpr int KS = K2 / 32;
  constexpr int LDO = 132;      // floats; out-tile row stride
  __shared__ __align__(16) float ot[48 * LDO];  // 25344 B
  __shared__ float sb[768];
  __shared__ float spool[384];
  int tid = threadIdx.x;
  int bid = blockIdx.x;
  int b = bid >> 7;
  int nt = bid & 127;
  int p0 = nt * 48;

  if (HASPOOL) {
    // pooled mean (sum of 8 shadow copies) -> LDS
    for (int i = tid; i < 384; i += 256) {
      float x = 0.f;
#pragma unroll
      for (int k = 0; k < 8; ++k) x += ps[k * 3072 + b * 384 + i];
      spool[i] = x * (1.f / 2048.f);
    }
    __syncthreads();
    // bias: thread == stacked row m (0..127 = Wn, 128..255 = D)
    float s0 = 0.f, s1 = 0.f, s2 = 0.f;
#pragma unroll 4
    for (int c = 0; c < 128; ++c) {
      float x = Wt[c * 256 + tid];
      s0 = fmaf(x, spool[c * 3 + 0], s0);
      s1 = fmaf(x, spool[c * 3 + 1], s1);
      s2 = fmaf(x, spool[c * 3 + 2], s2);
    }
    sb[tid * 3 + 0] = s0;
    sb[tid * 3 + 1] = s1;
    sb[tid * 3 + 2] = s2;
    __syncthreads();
  }

  int w = tid >> 6, lane = tid & 63;
  int q = lane >> 4, cl = lane & 15;

  f32x4 acc[2][2][3] = {};  // [t][pd][v]
  const unsigned short* wbase = Wb + (size_t)cl * K2 + q * 8;   // cl ignored via broadcast rows
  const unsigned short* xbase = Xp + ((size_t)b * P + p0 + cl) * K2 + q * 8;

  // 1-deep software pipeline: A (weights) and B (pixels) from global
  bf16x8 acur[2][2], anxt[2][2], bcur[3], bnxt[3];
#pragma unroll
  for (int t = 0; t < 2; ++t)
#pragma unroll
    for (int pd = 0; pd < 2; ++pd)
      acur[t][pd] = *(const bf16x8*)(wbase + (size_t)(32 * w + 16 * t + 128 * pd) * K2);
#pragma unroll
  for (int v = 0; v < 3; ++v)
    bcur[v] = *(const bf16x8*)(xbase + (size_t)(v * 16) * K2);

#pragma unroll
  for (int ks = 0; ks < KS; ++ks) {
    if (ks + 1 < KS) {
#pragma unroll
      for (int t = 0; t < 2; ++t)
#pragma unroll
        for (int pd = 0; pd < 2; ++pd)
          anxt[t][pd] = *(const bf16x8*)(wbase +
              (size_t)(32 * w + 16 * t + 128 * pd) * K2 + (ks + 1) * 32);
#pragma unroll
      for (int v = 0; v < 3; ++v)
        bnxt[v] = *(const bf16x8*)(xbase + (size_t)(v * 16) * K2 + (ks + 1) * 32);
    }
#pragma unroll
    for (int t = 0; t < 2; ++t)
#pragma unroll
      for (int pd = 0; pd < 2; ++pd)
#pragma unroll
        for (int v = 0; v < 3; ++v)
          acc[t][pd][v] = __builtin_amdgcn_mfma_f32_16x16x32_bf16(
              acur[t][pd], bcur[v], acc[t][pd][v], 0, 0, 0);
#pragma unroll
    for (int t = 0; t < 2; ++t)
#pragma unroll
      for (int pd = 0; pd < 2; ++pd)
        acur[t][pd] = anxt[t][pd];
#pragma unroll
    for (int v = 0; v < 3; ++v) bcur[v] = bnxt[v];
  }

  // activation -> LDS out-tile [pixel(48)][o(128)]
#pragma unroll
  for (int t = 0; t < 2; ++t) {
    float res[3][4];
#pragma unroll
    for (int r = 0; r < 4; ++r) {
      int o = 32 * w + 16 * t + 4 * q + r;
      float pv[3], dvv[3];
#pragma unroll
      for (int v = 0; v < 3; ++v) {
        pv[v] = acc[t][0][v][r] + (HASPOOL ? sb[o * 3 + v] : 0.f);
        dvv[v] = acc[t][1][v][r] + (HASPOOL ? sb[(128 + o) * 3 + v] : 0.f);
      }
      float dot = fmaf(pv[0], dvv[0], fmaf(pv[1], dvv[1], pv[2] * dvv[2]));
      float dns = fmaf(dvv[0], dvv[0], fmaf(dvv[1], dvv[1], dvv[2] * dvv[2]));
      float f = (dot < 0.f) ? dot / (dns + 1e-6f) : 0.f;
#pragma unroll
      for (int v = 0; v < 3; ++v) res[v][r] = pv[v] - f * dvv[v];
    }
    int o0 = 32 * w + 16 * t + 4 * q;
#pragma unroll
    for (int v = 0; v < 3; ++v) {
      f32x4 rv = {res[v][0], res[v][1], res[v][2], res[v][3]};
      *(f32x4*)(ot + (v * 16 + cl) * LDO + o0) = rv;
    }
  }
  __syncthreads();

  int shadow = (nt & 7) * 3072;
  for (int s = tid; s < 384; s += 256) {
    int o = s / 3, v = s % 3;
    float a2 = 0.f;
#pragma unroll
    for (int c = 0; c < 16; ++c) a2 += ot[(v * 16 + c) * LDO + o];
    if (LAST) atomicAdd(outs + shadow + b * 384 + s, a2);
    else      atomicAdd(pool + shadow + b * 384 + s, a2);
  }

  if (!LAST) {
    for (int s = tid; s < 1536; s += 256) {
      int pix = s >> 5, c4 = s & 31;
      const float* src = ot + pix * LDO + c4 * 4;
      uint4 vv;
      vv.x = packhl(src[0]);
      vv.y = packhl(src[1]);
      vv.z = packhl(src[2]);
      vv.w = packhl(src[3]);
      *(uint4*)(Xq + ((size_t)b * P + p0 + pix) * 256 + c4 * 8) = vv;
    }
  }
}

// ---------------------------------------------------------------------------
// launch
// ---------------------------------------------------------------------------
extern "C" void kernel_launch(void* const* d_in, const int* in_sizes, int n_in,
                              void* d_out, int out_size, void* d_ws, size_t ws_size,
                              hipStream_t stream) {
  (void)in_sizes; (void)n_in; (void)out_size; (void)ws_size;
  const float* pc   = (const float*)d_in[0];
  const float* Wpos = (const float*)d_in[1];
  const float* Dpos = (const float*)d_in[2];
  const float* W1   = (const float*)d_in[3];
  const float* D1   = (const float*)d_in[4];
  const float* W2   = (const float*)d_in[5];
  const float* D2   = (const float*)d_in[6];
  const float* W3   = (const float*)d_in[7];
  const float* D3   = (const float*)d_in[8];
  float* out = (float*)d_out;
  float* ws  = (float*)d_ws;

  prep_kernel<<<PREP_BLOCKS, 256, 0, stream>>>(Wpos, W1, D1, W2, D2, W3, D3, ws);
  knn_kernel<<<dim3(N / 4, B), 256, 0, stream>>>(pc, (int*)(ws + OIDX));
  edge_pos_kernel<<<dim3(16, 8, 8), 256, 0, stream>>>(
      pc, (const int*)(ws + OIDX), ws + OWNPOS, Dpos,
      (unsigned short*)(ws + OXP0));
  // layer1: K2=128 -> Xp1 + ps1 shadows
  gemm_vnt_kernel<128, false, false><<<1024, 256, 0, stream>>>(
      (const unsigned short*)(ws + OXP0), (const unsigned short*)(ws + OWB1),
      nullptr, nullptr, (unsigned short*)(ws + OXP1), ws + OPS1, nullptr);
  // layer2: bias prologue from ps1 + WT2 -> Xp2 + ps2 shadows
  gemm_vnt_kernel<256, true, false><<<1024, 256, 0, stream>>>(
      (const unsigned short*)(ws + OXP1), (const unsigned short*)(ws + OWB2),
      ws + OPS1, ws + OWT2, (unsigned short*)(ws + OXP2), ws + OPS2, nullptr);
  // layer3: bias prologue from ps2 + WT3 -> out shadows
  gemm_vnt_kernel<256, true, true><<<1024, 256, 0, stream>>>(
      (const unsigned short*)(ws + OXP2), (const unsigned short*)(ws + OWB3),
      ws + OPS2, ws + OWT3, nullptr, nullptr, ws + OOUTS);
  out_merge_kernel<<<12, 256, 0, stream>>>(ws + OOUTS, out);
}

// Round 10
// 227.536 us; speedup vs baseline: 1.0269x; 1.0269x over previous
//
#include <hip/hip_runtime.h>
#include <hip/hip_bf16.h>
#include <math.h>

// ---------------------------------------------------------------------------
// Problem constants
// ---------------------------------------------------------------------------
constexpr int B = 8;
constexpr int N = 2048;
constexpr int KNN = 20;
constexpr int H = 128;
constexpr int P = 3 * N;  // 6144 pixels per batch

// ws layout (float offsets)
constexpr int OWNPOS = 0;         // 64x3 normalized W_pos (pad 256)
constexpr int OWT2   = 8448;      // W2/D2 second-half TRANSPOSED [c<128][m<256] (32768)
constexpr int OWT3   = 41216;     // W3/D3 second-half transposed (32768)
constexpr int OPS1   = 73984;     // poolsum1 shadows [8][B][128][3] = 24576
constexpr int OPS2   = 98560;     // poolsum2 shadows = 24576
constexpr int OOUTS  = 123136;    // out shadows [8][B][384] = 24576
constexpr int OWB1   = 160000;    // Wbig1 256x128 bf16 hi/lo (16384 f)
constexpr int OWB2   = 176384;    // Wbig2 256x256 bf16 hi/lo (32768 f)
constexpr int OWB3   = 209152;    // Wbig3 256x256 bf16 hi/lo (32768 f)
constexpr int OIDX   = 241920;    // knn idx: 8*2048*20 ints = 327680
constexpr int OXP0   = 569600;    // Xp0 bf16 [b][P][128] (3145728 f-equiv)
constexpr int OXP2   = 569600;    // Xp2 bf16 [b][P][256] reuses Xp0 region
constexpr int OXP1   = 6861056;   // Xp1 bf16 [b][P][256] (6291456 f-equiv)
// max extent 13,152,512 floats ~= 52.6 MB

constexpr int ZERO_BASE = OPS1;   // prep zeroes [OPS1, OPS1+73728) = ps1+ps2+outs
constexpr int ZERO_CNT  = 73728;
constexpr int PREP_BLOCKS = 208;  // 832 waves = 832 rows

typedef __attribute__((ext_vector_type(8))) short bf16x8;
typedef __attribute__((ext_vector_type(4))) float f32x4;

__device__ __forceinline__ unsigned short f2bf(float x) {
  __hip_bfloat16 h = __float2bfloat16(x);
  return *(unsigned short*)&h;
}
__device__ __forceinline__ float bf2f(unsigned short u) {
  __hip_bfloat16 h;
  *(unsigned short*)&h = u;
  return __bfloat162float(h);
}
// pack x as (hi, lo) bf16 pair in one uint (hi at lower address)
__device__ __forceinline__ unsigned int packhl(float x) {
  unsigned short hi = f2bf(x);
  float lo = x - bf2f(hi);
  unsigned short ls = f2bf(lo);
  return (unsigned)hi | ((unsigned)ls << 16);
}

// ---------------------------------------------------------------------------
// Wave-wide bitonic sort of 64 (value,index) pairs, descending, tie->low idx.
// ---------------------------------------------------------------------------
__device__ __forceinline__ void wave_sort64(float& v, int& m, int lane) {
#pragma unroll
  for (int k = 2; k <= 64; k <<= 1) {
#pragma unroll
    for (int j = k >> 1; j > 0; j >>= 1) {
      float pv = __shfl_xor(v, j);
      int   pm = __shfl_xor(m, j);
      bool iam_lower   = (lane & j) == 0;
      bool dir_desc    = (lane & k) == 0;
      bool p_better    = (pv > v) || (pv == v && pm < m);
      bool want_better = (dir_desc == iam_lower);
      bool take        = (p_better == want_better);
      v = take ? pv : v;
      m = take ? pm : m;
    }
  }
}

// ---------------------------------------------------------------------------
// K1 (fused prep): zero shadows; normalize W rows; emit bf16 hi/lo packed
// first-C cols (stacked [Wn;D]); emit fp32 TRANSPOSED second-half cols.
// ---------------------------------------------------------------------------
__global__ __launch_bounds__(256) void prep_kernel(
    const float* __restrict__ Wpos, const float* __restrict__ W1,
    const float* __restrict__ D1, const float* __restrict__ W2,
    const float* __restrict__ D2, const float* __restrict__ W3,
    const float* __restrict__ D3, float* __restrict__ ws) {
  for (int i = blockIdx.x * 256 + threadIdx.x; i < ZERO_CNT; i += PREP_BLOCKS * 256)
    ws[ZERO_BASE + i] = 0.f;

  int r = blockIdx.x * 4 + (threadIdx.x >> 6);
  int lane = threadIdx.x & 63;
  const float* src;
  float* fdst = nullptr;
  float* tdst = nullptr;
  unsigned int* pdst = nullptr;
  int C, Cpack;
  bool norm = true;
  if (r < 64)       { src = Wpos + r * 3; fdst = ws + OWNPOS + r * 3; C = 3; Cpack = 0; }
  else if (r < 192) { int m = r - 64;  src = W1 + m * 64;  C = 64;  Cpack = 64;
                      pdst = (unsigned int*)(ws + OWB1) + m * 64; }
  else if (r < 320) { int m = r - 192; src = D1 + m * 64;  C = 64;  Cpack = 64; norm = false;
                      pdst = (unsigned int*)(ws + OWB1) + (m + 128) * 64; }
  else if (r < 448) { int m = r - 320; src = W2 + m * 256; C = 256; Cpack = 128;
                      pdst = (unsigned int*)(ws + OWB2) + m * 128;
                      tdst = ws + OWT2 + m; }
  else if (r < 576) { int m = r - 448; src = D2 + m * 256; C = 256; Cpack = 128; norm = false;
                      pdst = (unsigned int*)(ws + OWB2) + (m + 128) * 128;
                      tdst = ws + OWT2 + 128 + m; }
  else if (r < 704) { int m = r - 576; src = W3 + m * 256; C = 256; Cpack = 128;
                      pdst = (unsigned int*)(ws + OWB3) + m * 128;
                      tdst = ws + OWT3 + m; }
  else              { int m = r - 704; src = D3 + m * 256; C = 256; Cpack = 128; norm = false;
                      pdst = (unsigned int*)(ws + OWB3) + (m + 128) * 128;
                      tdst = ws + OWT3 + 128 + m; }

  float s = 1.f;
  if (norm) {
    float a = 0.f;
    for (int i = lane; i < C; i += 64) a += src[i];
#pragma unroll
    for (int off = 32; off > 0; off >>= 1) a += __shfl_xor(a, off);
    s = a;
  }
  for (int i = lane; i < C; i += 64) {
    float val = src[i] / s;  // exact when s==1
    if (fdst) fdst[i] = val;
    if (pdst && i < Cpack) pdst[i] = packhl(val);
    if (tdst && i >= 128) tdst[(i - 128) * 256] = val;
  }
}

// ---------------------------------------------------------------------------
// K2: exact top-20 KNN (unchanged from round 8).
// ---------------------------------------------------------------------------
__global__ __launch_bounds__(256, 4) void knn_kernel(const float* __restrict__ pc,
                                                     int* __restrict__ idxout) {
  __shared__ float4 spt[N];
  __shared__ unsigned short sbuf[4][512];
  int tid = threadIdx.x;
  int b = blockIdx.y;
  const float* pcb = pc + b * N * 3;
  for (int i = tid; i < N; i += 256) {
    float x = pcb[i * 3 + 0], y = pcb[i * 3 + 1], z = pcb[i * 3 + 2];
    float xx = __fadd_rn(__fadd_rn(__fmul_rn(x, x), __fmul_rn(y, y)), __fmul_rn(z, z));
    spt[i] = make_float4(2.f * x, 2.f * y, 2.f * z, xx);
  }
  __syncthreads();
  int wv = tid >> 6, lane = tid & 63;
  int q = blockIdx.x * 4 + wv;
  float4 qp = spt[q];
  float qx = 0.5f * qp.x, qy = 0.5f * qp.y, qz = 0.5f * qp.z, qxx = qp.w;

  float dv[32];
  float lmax = -INFINITY;
#pragma unroll
  for (int i = 0; i < 32; ++i) {
    float4 m = spt[i * 64 + lane];
    float A = __fadd_rn(__fadd_rn(__fmul_rn(m.x, qx), __fmul_rn(m.y, qy)),
                        __fmul_rn(m.z, qz));
    float d = __fsub_rn(__fsub_rn(A, qxx), m.w);
    dv[i] = d;
    lmax = fmaxf(lmax, d);
  }

  // value-only bitonic sort (descending) of the 64 lane-maxes; take #19
  float sv = lmax;
#pragma unroll
  for (int k = 2; k <= 64; k <<= 1) {
#pragma unroll
    for (int j = k >> 1; j > 0; j >>= 1) {
      float pv = __shfl_xor(sv, j);
      bool keep_max = ((lane & k) == 0) == ((lane & j) == 0);
      sv = keep_max ? fmaxf(sv, pv) : fminf(sv, pv);
    }
  }
  float tval = __shfl(sv, 19);  // 20th-largest lane-max <= V20 (provable)

  int base = 0;
#pragma unroll
  for (int i = 0; i < 32; ++i) {
    bool s = dv[i] >= tval;
    unsigned long long mk = __ballot(s);
    if (s) {
      int pos = base + (int)__popcll(mk & ((1ull << lane) - 1ull));
      if (pos < 512) sbuf[wv][pos] = (unsigned short)(i * 64 + lane);
    }
    base += (int)__popcll(mk);
  }
  int S = base;

  auto distOf = [&](int m) -> float {
    float4 mp = spt[m];
    float A = __fadd_rn(__fadd_rn(__fmul_rn(mp.x, qx), __fmul_rn(mp.y, qy)),
                        __fmul_rn(mp.z, qz));
    return __fsub_rn(__fsub_rn(A, qxx), mp.w);
  };

  float cv = -INFINITY;
  int cm = 0x7fffffff;
  if (S <= 64) {
    if (lane < S) { cm = sbuf[wv][lane]; cv = distOf(cm); }
    wave_sort64(cv, cm, lane);
  } else if (S <= 512) {
    int pos = 0;
    while (pos < S) {
      if (lane >= KNN) {
        int t = pos + lane - KNN;
        if (t < S) { cm = sbuf[wv][t]; cv = distOf(cm); }
        else       { cm = 0x7fffffff;  cv = -INFINITY; }
      }
      wave_sort64(cv, cm, lane);
      pos += 64 - KNN;
    }
  } else {
    int pos = 0;
    while (pos < N) {
      if (lane >= KNN) {
        int t = pos + lane - KNN;
        if (t < N) { cm = t; cv = distOf(t); }
        else       { cm = 0x7fffffff; cv = -INFINITY; }
      }
      wave_sort64(cv, cm, lane);
      pos += 64 - KNN;
    }
  }
  if (lane < KNN) idxout[(b * N + q) * KNN + lane] = cm;
}

// ---------------------------------------------------------------------------
// K3: edge features -> pos layer (64ch) -> VN-LeakyReLU -> mean over k ->
// direct bf16 hi/lo pack into Xp0.  Point cloud staged in LDS.
// ---------------------------------------------------------------------------
__global__ __launch_bounds__(256) void edge_pos_kernel(
    const float* __restrict__ pc, const int* __restrict__ knn,
    const float* __restrict__ Wn, const float* __restrict__ Dp,
    unsigned short* __restrict__ Xp0) {
  __shared__ float sp[N * 3];  // 24 KB
  int tid = threadIdx.x;
  int og = blockIdx.x, nt = blockIdx.y, b = blockIdx.z;
  const float* pcb = pc + (size_t)b * N * 3;
  for (int i = tid; i < N * 3; i += 256) sp[i] = pcb[i];
  __syncthreads();

  int n = nt * 256 + tid;
  float cx = sp[n * 3 + 0], cy = sp[n * 3 + 1], cz = sp[n * 3 + 2];

  float w[4][3], dw[4][3], acc[3][4];
#pragma unroll
  for (int j = 0; j < 4; ++j) {
    int o = og * 4 + j;
    w[j][0] = Wn[o * 3 + 0]; w[j][1] = Wn[o * 3 + 1]; w[j][2] = Wn[o * 3 + 2];
    dw[j][0] = Dp[o * 3 + 0]; dw[j][1] = Dp[o * 3 + 1]; dw[j][2] = Dp[o * 3 + 2];
    acc[0][j] = 0.f; acc[1][j] = 0.f; acc[2][j] = 0.f;
  }
  const int4* kn4 = (const int4*)(knn + ((size_t)b * N + n) * KNN);
  int kidx[20];
#pragma unroll
  for (int t = 0; t < 5; ++t) {
    int4 kv = kn4[t];
    kidx[t * 4 + 0] = kv.x; kidx[t * 4 + 1] = kv.y;
    kidx[t * 4 + 2] = kv.z; kidx[t * 4 + 3] = kv.w;
  }
#pragma unroll 4
  for (int k = 0; k < KNN; ++k) {
    int m = kidx[k];
    float nx = sp[m * 3 + 0], ny = sp[m * 3 + 1], nz = sp[m * 3 + 2];
    float ex = nx - cx, ey = ny - cy, ez = nz - cz;
    float rx = ny * cz - nz * cy;
    float ry = nz * cx - nx * cz;
    float rz = nx * cy - ny * cx;
#pragma unroll
    for (int j = 0; j < 4; ++j) {
      float px = fmaf(w[j][0], ex, fmaf(w[j][1], cx, w[j][2] * rx));
      float py = fmaf(w[j][0], ey, fmaf(w[j][1], cy, w[j][2] * ry));
      float pz = fmaf(w[j][0], ez, fmaf(w[j][1], cz, w[j][2] * rz));
      float dx = fmaf(dw[j][0], ex, fmaf(dw[j][1], cx, dw[j][2] * rx));
      float dy = fmaf(dw[j][0], ey, fmaf(dw[j][1], cy, dw[j][2] * ry));
      float dz = fmaf(dw[j][0], ez, fmaf(dw[j][1], cz, dw[j][2] * rz));
      float dot = fmaf(px, dx, fmaf(py, dy, pz * dz));
      float dns = fmaf(dx, dx, fmaf(dy, dy, dz * dz));
      float f = (dot < 0.f) ? dot / (dns + 1e-6f) : 0.f;
      acc[0][j] += px - f * dx;
      acc[1][j] += py - f * dy;
      acc[2][j] += pz - f * dz;
    }
  }
  int pbase = ((n >> 4) * 48) + (n & 15);
#pragma unroll
  for (int v = 0; v < 3; ++v) {
    uint4 vv;
    vv.x = packhl(acc[v][0] * (1.f / 20.f));
    vv.y = packhl(acc[v][1] * (1.f / 20.f));
    vv.z = packhl(acc[v][2] * (1.f / 20.f));
    vv.w = packhl(acc[v][3] * (1.f / 20.f));
    *(uint4*)(Xp0 + ((size_t)b * P + pbase + v * 16) * 128 + og * 8) = vv;
  }
}

// ---------------------------------------------------------------------------
// K9: merge 8 out shadows -> d_out (mean over N).
// ---------------------------------------------------------------------------
__global__ __launch_bounds__(256) void out_merge_kernel(
    const float* __restrict__ outs, float* __restrict__ out) {
  int idx = blockIdx.x * 256 + threadIdx.x;  // 3072
  if (idx >= B * 384) return;
  float s = 0.f;
#pragma unroll
  for (int k = 0; k < 8; ++k) s += outs[k * 3072 + idx];
  out[idx] = s * (1.f / 2048.f);
}

// ---------------------------------------------------------------------------
// K4/K6/K8: MFMA VNT layer, M-SPLIT version (round-8 staged structure).
// Each block computes HALF the output rows: o in [m0, m0+64) with their
// paired d-rows [128+m0, 128+m0+64), so VN-LeakyReLU stays block-local.
// Grid 2048 = 1024 tiles x 2 m-halves; bid = u*16 + (mhalf*8 + j) keeps both
// halves of tile u*8+j on the same XCD slot (bid mod 8 == j) so the shared
// X-tile dedupes in that XCD's L2.
// LDS: X-tile [48][K2] (padded) reused as fp32 out-tile [48][64] after the
// K-loop; bias (128 rows) computed in prologue for HASPOOL.
// ---------------------------------------------------------------------------
template <int K2, bool HASPOOL, bool LAST>
__global__ __launch_bounds__(256, 4) void gemm_vnt_kernel(
    const unsigned short* __restrict__ Xp, const unsigned short* __restrict__ Wb,
    const float* __restrict__ ps, const float* __restrict__ Wt,
    unsigned short* __restrict__ Xq, float* __restrict__ pool,
    float* __restrict__ outs) {
  constexpr int KS = K2 / 32;
  constexpr int LDR = K2 + 8;   // halves; X-tile row stride
  constexpr int LDO = 68;       // floats; out-tile row stride (272B, 16B-aligned)
  constexpr int XBYTES = 48 * LDR * 2;
  constexpr int OBYTES = 48 * LDO * 4;
  constexpr int SMEMB = (XBYTES > OBYTES) ? XBYTES : OBYTES;
  __shared__ __align__(16) char smem[SMEMB];
  unsigned short* xt = (unsigned short*)smem;
  float* ot = (float*)smem;
  __shared__ float sb[384];     // bias for this block's 128 stacked rows
  __shared__ float spool[384];
  int tid = threadIdx.x;
  int bid = blockIdx.x;
  int u = bid >> 4, l = bid & 15;
  int mhalf = l >> 3;
  int tile = u * 8 + (l & 7);
  int b = tile >> 7, nt = tile & 127;
  int p0 = nt * 48;
  int m0 = mhalf * 64;

  // stage X tile [48][K2] -> LDS
  for (int ch = tid; ch < 48 * (K2 / 8); ch += 256) {
    int rp = ch / (K2 / 8), cc = ch % (K2 / 8);
    *(uint4*)(xt + rp * LDR + cc * 8) =
        *(const uint4*)(Xp + ((size_t)b * P + p0 + rp) * K2 + cc * 8);
  }
  if (HASPOOL) {
    for (int i = tid; i < 384; i += 256) {
      float x = 0.f;
#pragma unroll
      for (int k = 0; k < 8; ++k) x += ps[k * 3072 + b * 384 + i];
      spool[i] = x * (1.f / 2048.f);
    }
  }
  __syncthreads();
  if (HASPOOL) {
    if (tid < 128) {
      // local stacked row tid -> global row: 0..63 = Wn rows m0+tid,
      // 64..127 = D rows 128+m0+(tid-64)  ==  64+m0+tid
      int grow = (tid < 64) ? (m0 + tid) : (64 + m0 + tid);
      float s0 = 0.f, s1 = 0.f, s2 = 0.f;
#pragma unroll 4
      for (int c = 0; c < 128; ++c) {
        float x = Wt[c * 256 + grow];
        s0 = fmaf(x, spool[c * 3 + 0], s0);
        s1 = fmaf(x, spool[c * 3 + 1], s1);
        s2 = fmaf(x, spool[c * 3 + 2], s2);
      }
      sb[tid * 3 + 0] = s0;
      sb[tid * 3 + 1] = s1;
      sb[tid * 3 + 2] = s2;
    }
    __syncthreads();
  }

  int w = tid >> 6, lane = tid & 63;
  int q = lane >> 4, cl = lane & 15;

  f32x4 acc[2][3] = {};  // [pd][v]
  const unsigned short* wbase = Wb + (size_t)cl * K2 + q * 8;
  int rowp = m0 + 16 * w;
  int rowd = 128 + m0 + 16 * w;

  bf16x8 acur[2], anxt[2];
  acur[0] = *(const bf16x8*)(wbase + (size_t)rowp * K2);
  acur[1] = *(const bf16x8*)(wbase + (size_t)rowd * K2);

#pragma unroll
  for (int ks = 0; ks < KS; ++ks) {
    if (ks + 1 < KS) {
      anxt[0] = *(const bf16x8*)(wbase + (size_t)rowp * K2 + (ks + 1) * 32);
      anxt[1] = *(const bf16x8*)(wbase + (size_t)rowd * K2 + (ks + 1) * 32);
    }
    bf16x8 bb[3];
#pragma unroll
    for (int v = 0; v < 3; ++v)
      bb[v] = *(const bf16x8*)(xt + (v * 16 + cl) * LDR + ks * 32 + q * 8);
#pragma unroll
    for (int pd = 0; pd < 2; ++pd)
#pragma unroll
      for (int v = 0; v < 3; ++v)
        acc[pd][v] = __builtin_amdgcn_mfma_f32_16x16x32_bf16(
            acur[pd], bb[v], acc[pd][v], 0, 0, 0);
    acur[0] = anxt[0];
    acur[1] = anxt[1];
  }
  __syncthreads();  // X-tile dead; buffer becomes the fp32 out-tile

  // activation -> LDS out-tile [pixel(48)][o_local(64)]
  {
    float res[3][4];
#pragma unroll
    for (int r = 0; r < 4; ++r) {
      int ol = 16 * w + 4 * q + r;
      float pv[3], dvv[3];
#pragma unroll
      for (int v = 0; v < 3; ++v) {
        pv[v]  = acc[0][v][r] + (HASPOOL ? sb[ol * 3 + v] : 0.f);
        dvv[v] = acc[1][v][r] + (HASPOOL ? sb[(64 + ol) * 3 + v] : 0.f);
      }
      float dot = fmaf(pv[0], dvv[0], fmaf(pv[1], dvv[1], pv[2] * dvv[2]));
      float dns = fmaf(dvv[0], dvv[0], fmaf(dvv[1], dvv[1], dvv[2] * dvv[2]));
      float f = (dot < 0.f) ? dot / (dns + 1e-6f) : 0.f;
#pragma unroll
      for (int v = 0; v < 3; ++v) res[v][r] = pv[v] - f * dvv[v];
    }
    int o0 = 16 * w + 4 * q;
#pragma unroll
    for (int v = 0; v < 3; ++v) {
      f32x4 rv = {res[v][0], res[v][1], res[v][2], res[v][3]};
      *(f32x4*)(ot + (v * 16 + cl) * LDO + o0) = rv;
    }
  }
  __syncthreads();

  // pool: 16 pixels per (o_local, v); lane-dense atomics into shadow nt&7
  int shadow = (nt & 7) * 3072;
  if (tid < 192) {
    int o = tid / 3, v = tid % 3;
    float a2 = 0.f;
#pragma unroll
    for (int c = 0; c < 16; ++c) a2 += ot[(v * 16 + c) * LDO + o];
    float* dst = (LAST ? outs : pool) + shadow + b * 384 + m0 * 3 + tid;
    atomicAdd(dst, a2);
  }

  // coalesced pack + store of this block's 64-o slice (not for last layer)
  if (!LAST) {
    for (int s = tid; s < 768; s += 256) {
      int pix = s >> 4, c4 = s & 15;   // c4: group of 4 o_locals
      const float* src = ot + pix * LDO + c4 * 4;
      uint4 vv;
      vv.x = packhl(src[0]);
      vv.y = packhl(src[1]);
      vv.z = packhl(src[2]);
      vv.w = packhl(src[3]);
      *(uint4*)(Xq + ((size_t)b * P + p0 + pix) * 256 + 2 * m0 + c4 * 8) = vv;
    }
  }
}

// ---------------------------------------------------------------------------
// launch
// ---------------------------------------------------------------------------
extern "C" void kernel_launch(void* const* d_in, const int* in_sizes, int n_in,
                              void* d_out, int out_size, void* d_ws, size_t ws_size,
                              hipStream_t stream) {
  (void)in_sizes; (void)n_in; (void)out_size; (void)ws_size;
  const float* pc   = (const float*)d_in[0];
  const float* Wpos = (const float*)d_in[1];
  const float* Dpos = (const float*)d_in[2];
  const float* W1   = (const float*)d_in[3];
  const float* D1   = (const float*)d_in[4];
  const float* W2   = (const float*)d_in[5];
  const float* D2   = (const float*)d_in[6];
  const float* W3   = (const float*)d_in[7];
  const float* D3   = (const float*)d_in[8];
  float* out = (float*)d_out;
  float* ws  = (float*)d_ws;

  prep_kernel<<<PREP_BLOCKS, 256, 0, stream>>>(Wpos, W1, D1, W2, D2, W3, D3, ws);
  knn_kernel<<<dim3(N / 4, B), 256, 0, stream>>>(pc, (int*)(ws + OIDX));
  edge_pos_kernel<<<dim3(16, 8, 8), 256, 0, stream>>>(
      pc, (const int*)(ws + OIDX), ws + OWNPOS, Dpos,
      (unsigned short*)(ws + OXP0));
  // layer1: K2=128 -> Xp1 + ps1 shadows
  gemm_vnt_kernel<128, false, false><<<2048, 256, 0, stream>>>(
      (const unsigned short*)(ws + OXP0), (const unsigned short*)(ws + OWB1),
      nullptr, nullptr, (unsigned short*)(ws + OXP1), ws + OPS1, nullptr);
  // layer2: bias prologue from ps1 + WT2 -> Xp2 + ps2 shadows
  gemm_vnt_kernel<256, true, false><<<2048, 256, 0, stream>>>(
      (const unsigned short*)(ws + OXP1), (const unsigned short*)(ws + OWB2),
      ws + OPS1, ws + OWT2, (unsigned short*)(ws + OXP2), ws + OPS2, nullptr);
  // layer3: bias prologue from ps2 + WT3 -> out shadows
  gemm_vnt_kernel<256, true, true><<<2048, 256, 0, stream>>>(
      (const unsigned short*)(ws + OXP2), (const unsigned short*)(ws + OWB3),
      ws + OPS2, ws + OWT3, nullptr, nullptr, ws + OOUTS);
  out_merge_kernel<<<12, 256, 0, stream>>>(ws + OOUTS, out);
}

// Round 11
// 209.417 us; speedup vs baseline: 1.1157x; 1.0865x over previous
//
#include <hip/hip_runtime.h>
#include <hip/hip_bf16.h>
#include <math.h>

// ---------------------------------------------------------------------------
// Problem constants
// ---------------------------------------------------------------------------
constexpr int B = 8;
constexpr int N = 2048;
constexpr int KNN = 20;
constexpr int H = 128;
constexpr int P = 3 * N;  // 6144 pixels per batch

// ws layout (float offsets)
constexpr int OWNPOS = 0;         // 64x3 normalized W_pos (pad 256)
constexpr int OWT2   = 8448;      // W2/D2 second-half TRANSPOSED [c<128][m<256] (32768)
constexpr int OWT3   = 41216;     // W3/D3 second-half transposed (32768)
constexpr int OPS1   = 73984;     // poolsum1 shadows [8][B][128][3] = 24576
constexpr int OPS2   = 98560;     // poolsum2 shadows = 24576
constexpr int OOUTS  = 123136;    // out shadows [8][B][384] = 24576
constexpr int OWB1   = 160000;    // Wbig1 256x128 bf16 hi/lo (16384 f)
constexpr int OWB2   = 176384;    // Wbig2 256x256 bf16 hi/lo (32768 f)
constexpr int OWB3   = 209152;    // Wbig3 256x256 bf16 hi/lo (32768 f)
constexpr int OXP0   = 569600;    // Xp0 bf16 [b][P][128] (3145728 f-equiv)
constexpr int OXP2   = 569600;    // Xp2 bf16 [b][P][256] reuses Xp0 region
constexpr int OXP1   = 6861056;   // Xp1 bf16 [b][P][256] (6291456 f-equiv)
// max extent 13,152,512 floats ~= 52.6 MB

constexpr int ZERO_BASE = OPS1;   // prep zeroes [OPS1, OPS1+73728) = ps1+ps2+outs
constexpr int ZERO_CNT  = 73728;
constexpr int PREP_BLOCKS = 208;  // 832 waves = 832 rows

typedef __attribute__((ext_vector_type(8))) short bf16x8;
typedef __attribute__((ext_vector_type(4))) float f32x4;

__device__ __forceinline__ unsigned short f2bf(float x) {
  __hip_bfloat16 h = __float2bfloat16(x);
  return *(unsigned short*)&h;
}
__device__ __forceinline__ float bf2f(unsigned short u) {
  __hip_bfloat16 h;
  *(unsigned short*)&h = u;
  return __bfloat162float(h);
}
// pack x as (hi, lo) bf16 pair in one uint (hi at lower address)
__device__ __forceinline__ unsigned int packhl(float x) {
  unsigned short hi = f2bf(x);
  float lo = x - bf2f(hi);
  unsigned short ls = f2bf(lo);
  return (unsigned)hi | ((unsigned)ls << 16);
}

// ---------------------------------------------------------------------------
// Wave-wide bitonic sort of 64 (value,index) pairs, descending, tie->low idx.
// ---------------------------------------------------------------------------
__device__ __forceinline__ void wave_sort64(float& v, int& m, int lane) {
#pragma unroll
  for (int k = 2; k <= 64; k <<= 1) {
#pragma unroll
    for (int j = k >> 1; j > 0; j >>= 1) {
      float pv = __shfl_xor(v, j);
      int   pm = __shfl_xor(m, j);
      bool iam_lower   = (lane & j) == 0;
      bool dir_desc    = (lane & k) == 0;
      bool p_better    = (pv > v) || (pv == v && pm < m);
      bool want_better = (dir_desc == iam_lower);
      bool take        = (p_better == want_better);
      v = take ? pv : v;
      m = take ? pm : m;
    }
  }
}

// ---------------------------------------------------------------------------
// K1 (fused prep): zero shadows; normalize W rows; emit bf16 hi/lo packed
// first-C cols (stacked [Wn;D]); emit fp32 TRANSPOSED second-half cols.
// ---------------------------------------------------------------------------
__global__ __launch_bounds__(256) void prep_kernel(
    const float* __restrict__ Wpos, const float* __restrict__ W1,
    const float* __restrict__ D1, const float* __restrict__ W2,
    const float* __restrict__ D2, const float* __restrict__ W3,
    const float* __restrict__ D3, float* __restrict__ ws) {
  for (int i = blockIdx.x * 256 + threadIdx.x; i < ZERO_CNT; i += PREP_BLOCKS * 256)
    ws[ZERO_BASE + i] = 0.f;

  int r = blockIdx.x * 4 + (threadIdx.x >> 6);
  int lane = threadIdx.x & 63;
  const float* src;
  float* fdst = nullptr;
  float* tdst = nullptr;
  unsigned int* pdst = nullptr;
  int C, Cpack;
  bool norm = true;
  if (r < 64)       { src = Wpos + r * 3; fdst = ws + OWNPOS + r * 3; C = 3; Cpack = 0; }
  else if (r < 192) { int m = r - 64;  src = W1 + m * 64;  C = 64;  Cpack = 64;
                      pdst = (unsigned int*)(ws + OWB1) + m * 64; }
  else if (r < 320) { int m = r - 192; src = D1 + m * 64;  C = 64;  Cpack = 64; norm = false;
                      pdst = (unsigned int*)(ws + OWB1) + (m + 128) * 64; }
  else if (r < 448) { int m = r - 320; src = W2 + m * 256; C = 256; Cpack = 128;
                      pdst = (unsigned int*)(ws + OWB2) + m * 128;
                      tdst = ws + OWT2 + m; }
  else if (r < 576) { int m = r - 448; src = D2 + m * 256; C = 256; Cpack = 128; norm = false;
                      pdst = (unsigned int*)(ws + OWB2) + (m + 128) * 128;
                      tdst = ws + OWT2 + 128 + m; }
  else if (r < 704) { int m = r - 576; src = W3 + m * 256; C = 256; Cpack = 128;
                      pdst = (unsigned int*)(ws + OWB3) + m * 128;
                      tdst = ws + OWT3 + m; }
  else              { int m = r - 704; src = D3 + m * 256; C = 256; Cpack = 128; norm = false;
                      pdst = (unsigned int*)(ws + OWB3) + (m + 128) * 128;
                      tdst = ws + OWT3 + 128 + m; }

  float s = 1.f;
  if (norm) {
    float a = 0.f;
    for (int i = lane; i < C; i += 64) a += src[i];
#pragma unroll
    for (int off = 32; off > 0; off >>= 1) a += __shfl_xor(a, off);
    s = a;
  }
  for (int i = lane; i < C; i += 64) {
    float val = src[i] / s;  // exact when s==1
    if (fdst) fdst[i] = val;
    if (pdst && i < Cpack) pdst[i] = packhl(val);
    if (tdst && i >= 128) tdst[(i - 128) * 256] = val;
  }
}

// ---------------------------------------------------------------------------
// K2 (FUSED): exact top-20 KNN + edge features + pos layer + VN-LeakyReLU +
// mean over k -> bf16 hi/lo pack into Xp0.
// One wave per query.  After the top-20 sort the wave's lanes 0..19 hold the
// neighbor indices; lane k reads its neighbor's float4 from LDS once, and
// the k-loop broadcasts coords via __shfl (VALU, no LDS latency).  Lane o
// (0..63) computes output channel o with the SAME fp32 op order as the old
// edge_pos kernel (bitwise-identical output).  The staged coords are 2x
// pre-scaled; multiplying by 0.5f recovers the exact raw values.
// Eliminates: idx traffic (5.2MB), a launch, 16x point re-staging.
// ---------------------------------------------------------------------------
__global__ __launch_bounds__(256, 4) void knn_edge_kernel(
    const float* __restrict__ pc, const float* __restrict__ Wn,
    const float* __restrict__ Dp, unsigned short* __restrict__ Xp0) {
  __shared__ float4 spt[N];                 // 32 KB
  __shared__ unsigned short sbuf[4][512];   // 4 KB
  int tid = threadIdx.x;
  int b = blockIdx.y;
  const float* pcb = pc + (size_t)b * N * 3;
  for (int i = tid; i < N; i += 256) {
    float x = pcb[i * 3 + 0], y = pcb[i * 3 + 1], z = pcb[i * 3 + 2];
    float xx = __fadd_rn(__fadd_rn(__fmul_rn(x, x), __fmul_rn(y, y)), __fmul_rn(z, z));
    spt[i] = make_float4(2.f * x, 2.f * y, 2.f * z, xx);
  }
  __syncthreads();
  int wv = tid >> 6, lane = tid & 63;
  int q = blockIdx.x * 4 + wv;
  float4 qp = spt[q];
  float qx = 0.5f * qp.x, qy = 0.5f * qp.y, qz = 0.5f * qp.z, qxx = qp.w;

  float dv[32];
  float lmax = -INFINITY;
#pragma unroll
  for (int i = 0; i < 32; ++i) {
    float4 m = spt[i * 64 + lane];
    float A = __fadd_rn(__fadd_rn(__fmul_rn(m.x, qx), __fmul_rn(m.y, qy)),
                        __fmul_rn(m.z, qz));
    float d = __fsub_rn(__fsub_rn(A, qxx), m.w);
    dv[i] = d;
    lmax = fmaxf(lmax, d);
  }

  // value-only bitonic sort (descending) of the 64 lane-maxes; take #19
  float sv = lmax;
#pragma unroll
  for (int k = 2; k <= 64; k <<= 1) {
#pragma unroll
    for (int j = k >> 1; j > 0; j >>= 1) {
      float pv = __shfl_xor(sv, j);
      bool keep_max = ((lane & k) == 0) == ((lane & j) == 0);
      sv = keep_max ? fmaxf(sv, pv) : fminf(sv, pv);
    }
  }
  float tval = __shfl(sv, 19);  // 20th-largest lane-max <= V20 (provable)

  int base = 0;
#pragma unroll
  for (int i = 0; i < 32; ++i) {
    bool s = dv[i] >= tval;
    unsigned long long mk = __ballot(s);
    if (s) {
      int pos = base + (int)__popcll(mk & ((1ull << lane) - 1ull));
      if (pos < 512) sbuf[wv][pos] = (unsigned short)(i * 64 + lane);
    }
    base += (int)__popcll(mk);
  }
  int S = base;

  auto distOf = [&](int m) -> float {
    float4 mp = spt[m];
    float A = __fadd_rn(__fadd_rn(__fmul_rn(mp.x, qx), __fmul_rn(mp.y, qy)),
                        __fmul_rn(mp.z, qz));
    return __fsub_rn(__fsub_rn(A, qxx), mp.w);
  };

  float cv = -INFINITY;
  int cm = 0x7fffffff;
  if (S <= 64) {
    if (lane < S) { cm = sbuf[wv][lane]; cv = distOf(cm); }
    wave_sort64(cv, cm, lane);
  } else if (S <= 512) {
    int pos = 0;
    while (pos < S) {
      if (lane >= KNN) {
        int t = pos + lane - KNN;
        if (t < S) { cm = sbuf[wv][t]; cv = distOf(cm); }
        else       { cm = 0x7fffffff;  cv = -INFINITY; }
      }
      wave_sort64(cv, cm, lane);
      pos += 64 - KNN;
    }
  } else {
    int pos = 0;
    while (pos < N) {
      if (lane >= KNN) {
        int t = pos + lane - KNN;
        if (t < N) { cm = t; cv = distOf(t); }
        else       { cm = 0x7fffffff; cv = -INFINITY; }
      }
      wave_sort64(cv, cm, lane);
      pos += 64 - KNN;
    }
  }

  // ---- edge + pos layer (lane o = channel o) -------------------------------
  // lane k<20 fetches its neighbor's staged float4 (parallel LDS read)
  float4 nb = (lane < KNN) ? spt[cm] : make_float4(0.f, 0.f, 0.f, 0.f);
  int o = lane;
  float w0 = Wn[o * 3 + 0], w1 = Wn[o * 3 + 1], w2 = Wn[o * 3 + 2];
  float e0 = Dp[o * 3 + 0], e1 = Dp[o * 3 + 1], e2 = Dp[o * 3 + 2];
  float cx = qx, cy = qy, cz = qz;  // exact raw coords (0.5 * 2x)
  float ax = 0.f, ay = 0.f, az = 0.f;
#pragma unroll 4
  for (int k = 0; k < KNN; ++k) {
    float nx = 0.5f * __shfl(nb.x, k);
    float ny = 0.5f * __shfl(nb.y, k);
    float nz = 0.5f * __shfl(nb.z, k);
    float ex = nx - cx, ey = ny - cy, ez = nz - cz;
    float rx = ny * cz - nz * cy;
    float ry = nz * cx - nx * cz;
    float rz = nx * cy - ny * cx;
    float px = fmaf(w0, ex, fmaf(w1, cx, w2 * rx));
    float py = fmaf(w0, ey, fmaf(w1, cy, w2 * ry));
    float pz = fmaf(w0, ez, fmaf(w1, cz, w2 * rz));
    float dx = fmaf(e0, ex, fmaf(e1, cx, e2 * rx));
    float dy = fmaf(e0, ey, fmaf(e1, cy, e2 * ry));
    float dz = fmaf(e0, ez, fmaf(e1, cz, e2 * rz));
    float dot = fmaf(px, dx, fmaf(py, dy, pz * dz));
    float dns = fmaf(dx, dx, fmaf(dy, dy, dz * dz));
    float f = (dot < 0.f) ? dot / (dns + 1e-6f) : 0.f;
    ax += px - f * dx;
    ay += py - f * dy;
    az += pz - f * dz;
  }
  // store channel o of pixel q for v=0..2; contiguous 256B per (v) wave-store
  int pbase = ((q >> 4) * 48) + (q & 15);
  unsigned short* dst = Xp0 + ((size_t)b * P + pbase) * 128 + 2 * o;
  *(unsigned int*)(dst)              = packhl(ax * (1.f / 20.f));
  *(unsigned int*)(dst + 16 * 128)   = packhl(ay * (1.f / 20.f));
  *(unsigned int*)(dst + 32 * 128)   = packhl(az * (1.f / 20.f));
}

// ---------------------------------------------------------------------------
// K9: merge 8 out shadows -> d_out (mean over N).
// ---------------------------------------------------------------------------
__global__ __launch_bounds__(256) void out_merge_kernel(
    const float* __restrict__ outs, float* __restrict__ out) {
  int idx = blockIdx.x * 256 + threadIdx.x;  // 3072
  if (idx >= B * 384) return;
  float s = 0.f;
#pragma unroll
  for (int k = 0; k < 8; ++k) s += outs[k * 3072 + idx];
  out[idx] = s * (1.f / 2048.f);
}

// ---------------------------------------------------------------------------
// K4/K6/K8: MFMA VNT layer (round-8 proven form: LDS-staged X, full 256
// rows per block, grid 1024, in-kernel bias prologue, LDS out-tile epilogue).
// ---------------------------------------------------------------------------
template <int K2, bool HASPOOL, bool LAST>
__global__ __launch_bounds__(256, 4) void gemm_vnt_kernel(
    const unsigned short* __restrict__ Xp, const unsigned short* __restrict__ Wb,
    const float* __restrict__ ps, const float* __restrict__ Wt,
    unsigned short* __restrict__ Xq, float* __restrict__ pool,
    float* __restrict__ outs) {
  constexpr int KS = K2 / 32;
  constexpr int LDR = K2 + 8;   // halves; X-tile row stride
  constexpr int LDO = 132;      // floats; out-tile row stride
  __shared__ __align__(16) char smem[48 * LDO * 4];  // 25344 B, dual-purpose
  unsigned short* xt = (unsigned short*)smem;
  float* ot = (float*)smem;
  __shared__ float sb[768];
  __shared__ float spool[384];
  int tid = threadIdx.x;
  int bid = blockIdx.x;
  int b = bid >> 7;
  int nt = bid & 127;
  int p0 = nt * 48;

  // stage X tile [48][K2] -> LDS
  for (int ch = tid; ch < 48 * (K2 / 8); ch += 256) {
    int rp = ch / (K2 / 8), cc = ch % (K2 / 8);
    *(uint4*)(xt + rp * LDR + cc * 8) =
        *(const uint4*)(Xp + ((size_t)b * P + p0 + rp) * K2 + cc * 8);
  }
  if (HASPOOL) {
    // pooled mean (sum of 8 shadow copies) -> LDS
    for (int i = tid; i < 384; i += 256) {
      float x = 0.f;
#pragma unroll
      for (int k = 0; k < 8; ++k) x += ps[k * 3072 + b * 384 + i];
      spool[i] = x * (1.f / 2048.f);
    }
  }
  __syncthreads();
  if (HASPOOL) {
    // bias prologue: thread == stacked row m (0..127 = Wn, 128..255 = D)
    float s0 = 0.f, s1 = 0.f, s2 = 0.f;
#pragma unroll 4
    for (int c = 0; c < 128; ++c) {
      float x = Wt[c * 256 + tid];
      s0 = fmaf(x, spool[c * 3 + 0], s0);
      s1 = fmaf(x, spool[c * 3 + 1], s1);
      s2 = fmaf(x, spool[c * 3 + 2], s2);
    }
    sb[tid * 3 + 0] = s0;
    sb[tid * 3 + 1] = s1;
    sb[tid * 3 + 2] = s2;
    __syncthreads();
  }

  int w = tid >> 6, lane = tid & 63;
  int q = lane >> 4, cl = lane & 15;

  f32x4 acc[2][2][3] = {};  // [t][pd][v]
  const unsigned short* wbase = Wb + (size_t)cl * K2 + q * 8;

  bf16x8 acur[2][2], anxt[2][2];
#pragma unroll
  for (int t = 0; t < 2; ++t)
#pragma unroll
    for (int pd = 0; pd < 2; ++pd)
      acur[t][pd] = *(const bf16x8*)(wbase + (size_t)(32 * w + 16 * t + 128 * pd) * K2);

#pragma unroll
  for (int ks = 0; ks < KS; ++ks) {
    if (ks + 1 < KS) {
#pragma unroll
      for (int t = 0; t < 2; ++t)
#pragma unroll
        for (int pd = 0; pd < 2; ++pd)
          anxt[t][pd] = *(const bf16x8*)(wbase +
              (size_t)(32 * w + 16 * t + 128 * pd) * K2 + (ks + 1) * 32);
    }
    bf16x8 bb[3];
#pragma unroll
    for (int v = 0; v < 3; ++v)
      bb[v] = *(const bf16x8*)(xt + (v * 16 + cl) * LDR + ks * 32 + q * 8);
#pragma unroll
    for (int t = 0; t < 2; ++t)
#pragma unroll
      for (int pd = 0; pd < 2; ++pd)
#pragma unroll
        for (int v = 0; v < 3; ++v)
          acc[t][pd][v] = __builtin_amdgcn_mfma_f32_16x16x32_bf16(
              acur[t][pd], bb[v], acc[t][pd][v], 0, 0, 0);
#pragma unroll
    for (int t = 0; t < 2; ++t)
#pragma unroll
      for (int pd = 0; pd < 2; ++pd)
        acur[t][pd] = anxt[t][pd];
  }
  __syncthreads();  // X-tile dead; buffer becomes the fp32 out-tile

#pragma unroll
  for (int t = 0; t < 2; ++t) {
    float res[3][4];
#pragma unroll
    for (int r = 0; r < 4; ++r) {
      int o = 32 * w + 16 * t + 4 * q + r;
      float pv[3], dvv[3];
#pragma unroll
      for (int v = 0; v < 3; ++v) {
        pv[v] = acc[t][0][v][r] + (HASPOOL ? sb[o * 3 + v] : 0.f);
        dvv[v] = acc[t][1][v][r] + (HASPOOL ? sb[(128 + o) * 3 + v] : 0.f);
      }
      float dot = fmaf(pv[0], dvv[0], fmaf(pv[1], dvv[1], pv[2] * dvv[2]));
      float dns = fmaf(dvv[0], dvv[0], fmaf(dvv[1], dvv[1], dvv[2] * dvv[2]));
      float f = (dot < 0.f) ? dot / (dns + 1e-6f) : 0.f;
#pragma unroll
      for (int v = 0; v < 3; ++v) res[v][r] = pv[v] - f * dvv[v];
    }
    int o0 = 32 * w + 16 * t + 4 * q;
#pragma unroll
    for (int v = 0; v < 3; ++v) {
      f32x4 rv = {res[v][0], res[v][1], res[v][2], res[v][3]};
      *(f32x4*)(ot + (v * 16 + cl) * LDO + o0) = rv;
    }
  }
  __syncthreads();

  int shadow = (nt & 7) * 3072;
  for (int s = tid; s < 384; s += 256) {
    int o = s / 3, v = s % 3;
    float a2 = 0.f;
#pragma unroll
    for (int c = 0; c < 16; ++c) a2 += ot[(v * 16 + c) * LDO + o];
    if (LAST) atomicAdd(outs + shadow + b * 384 + s, a2);
    else      atomicAdd(pool + shadow + b * 384 + s, a2);
  }

  if (!LAST) {
    for (int s = tid; s < 1536; s += 256) {
      int pix = s >> 5, c4 = s & 31;
      const float* src = ot + pix * LDO + c4 * 4;
      uint4 vv;
      vv.x = packhl(src[0]);
      vv.y = packhl(src[1]);
      vv.z = packhl(src[2]);
      vv.w = packhl(src[3]);
      *(uint4*)(Xq + ((size_t)b * P + p0 + pix) * 256 + c4 * 8) = vv;
    }
  }
}

// ---------------------------------------------------------------------------
// launch
// ---------------------------------------------------------------------------
extern "C" void kernel_launch(void* const* d_in, const int* in_sizes, int n_in,
                              void* d_out, int out_size, void* d_ws, size_t ws_size,
                              hipStream_t stream) {
  (void)in_sizes; (void)n_in; (void)out_size; (void)ws_size;
  const float* pc   = (const float*)d_in[0];
  const float* Wpos = (const float*)d_in[1];
  const float* Dpos = (const float*)d_in[2];
  const float* W1   = (const float*)d_in[3];
  const float* D1   = (const float*)d_in[4];
  const float* W2   = (const float*)d_in[5];
  const float* D2   = (const float*)d_in[6];
  const float* W3   = (const float*)d_in[7];
  const float* D3   = (const float*)d_in[8];
  float* out = (float*)d_out;
  float* ws  = (float*)d_ws;

  prep_kernel<<<PREP_BLOCKS, 256, 0, stream>>>(Wpos, W1, D1, W2, D2, W3, D3, ws);
  // fused KNN + edge + pos layer -> Xp0
  knn_edge_kernel<<<dim3(N / 4, B), 256, 0, stream>>>(
      pc, ws + OWNPOS, Dpos, (unsigned short*)(ws + OXP0));
  // layer1: K2=128 -> Xp1 + ps1 shadows
  gemm_vnt_kernel<128, false, false><<<1024, 256, 0, stream>>>(
      (const unsigned short*)(ws + OXP0), (const unsigned short*)(ws + OWB1),
      nullptr, nullptr, (unsigned short*)(ws + OXP1), ws + OPS1, nullptr);
  // layer2: bias prologue from ps1 + WT2 -> Xp2 + ps2 shadows
  gemm_vnt_kernel<256, true, false><<<1024, 256, 0, stream>>>(
      (const unsigned short*)(ws + OXP1), (const unsigned short*)(ws + OWB2),
      ws + OPS1, ws + OWT2, (unsigned short*)(ws + OXP2), ws + OPS2, nullptr);
  // layer3: bias prologue from ps2 + WT3 -> out shadows
  gemm_vnt_kernel<256, true, true><<<1024, 256, 0, stream>>>(
      (const unsigned short*)(ws + OXP2), (const unsigned short*)(ws + OWB3),
      ws + OPS2, ws + OWT3, nullptr, nullptr, ws + OOUTS);
  out_merge_kernel<<<12, 256, 0, stream>>>(ws + OOUTS, out);
}

// Round 12
// 202.187 us; speedup vs baseline: 1.1556x; 1.0358x over previous
//
#include <hip/hip_runtime.h>
#include <hip/hip_bf16.h>
#include <math.h>

// ---------------------------------------------------------------------------
// Problem constants
// ---------------------------------------------------------------------------
constexpr int B = 8;
constexpr int N = 2048;
constexpr int KNN = 20;
constexpr int H = 128;
constexpr int P = 3 * N;  // 6144 pixels per batch

// ws layout (float offsets)
constexpr int OWNPOS = 0;         // 64x3 normalized W_pos (pad 256)
constexpr int OWT2   = 8448;      // W2/D2 second-half TRANSPOSED [c<128][m<256] (32768)
constexpr int OWT3   = 41216;     // W3/D3 second-half transposed (32768)
constexpr int OPS1   = 73984;     // poolsum1 shadows [8][B][128][3] = 24576
constexpr int OPS2   = 98560;     // poolsum2 shadows = 24576
constexpr int OOUTS  = 123136;    // out shadows [8][B][384] = 24576
constexpr int OWB1   = 160000;    // Wbig1 256x128 bf16 hi/lo (16384 f)
constexpr int OWB2   = 176384;    // Wbig2 256x256 bf16 hi/lo (32768 f)
constexpr int OWB3   = 209152;    // Wbig3 256x256 bf16 hi/lo (32768 f)
constexpr int OXP0   = 569600;    // Xp0 bf16 [b][P][128] (3145728 f-equiv)
constexpr int OXP2   = 569600;    // Xp2 bf16 [b][P][256] reuses Xp0 region
constexpr int OXP1   = 6861056;   // Xp1 bf16 [b][P][256] (6291456 f-equiv)
// max extent 13,152,512 floats ~= 52.6 MB

constexpr int ZERO_BASE = OPS1;   // prep zeroes [OPS1, OPS1+73728) = ps1+ps2+outs
constexpr int ZERO_CNT  = 73728;
constexpr int PREP_BLOCKS = 208;  // 832 waves = 832 rows

typedef __attribute__((ext_vector_type(8))) short bf16x8;
typedef __attribute__((ext_vector_type(4))) float f32x4;

__device__ __forceinline__ unsigned short f2bf(float x) {
  __hip_bfloat16 h = __float2bfloat16(x);
  return *(unsigned short*)&h;
}
__device__ __forceinline__ float bf2f(unsigned short u) {
  __hip_bfloat16 h;
  *(unsigned short*)&h = u;
  return __bfloat162float(h);
}
// pack x as (hi, lo) bf16 pair in one uint (hi at lower address)
__device__ __forceinline__ unsigned int packhl(float x) {
  unsigned short hi = f2bf(x);
  float lo = x - bf2f(hi);
  unsigned short ls = f2bf(lo);
  return (unsigned)hi | ((unsigned)ls << 16);
}

// ---------------------------------------------------------------------------
// Wave-wide bitonic sort of 64 (value,index) pairs, descending, tie->low idx.
// ---------------------------------------------------------------------------
__device__ __forceinline__ void wave_sort64(float& v, int& m, int lane) {
#pragma unroll
  for (int k = 2; k <= 64; k <<= 1) {
#pragma unroll
    for (int j = k >> 1; j > 0; j >>= 1) {
      float pv = __shfl_xor(v, j);
      int   pm = __shfl_xor(m, j);
      bool iam_lower   = (lane & j) == 0;
      bool dir_desc    = (lane & k) == 0;
      bool p_better    = (pv > v) || (pv == v && pm < m);
      bool want_better = (dir_desc == iam_lower);
      bool take        = (p_better == want_better);
      v = take ? pv : v;
      m = take ? pm : m;
    }
  }
}

// ---------------------------------------------------------------------------
// K1 (fused prep): zero shadows; normalize W rows; emit bf16 hi/lo packed
// first-C cols (stacked [Wn;D]); emit fp32 TRANSPOSED second-half cols.
// ---------------------------------------------------------------------------
__global__ __launch_bounds__(256) void prep_kernel(
    const float* __restrict__ Wpos, const float* __restrict__ W1,
    const float* __restrict__ D1, const float* __restrict__ W2,
    const float* __restrict__ D2, const float* __restrict__ W3,
    const float* __restrict__ D3, float* __restrict__ ws) {
  for (int i = blockIdx.x * 256 + threadIdx.x; i < ZERO_CNT; i += PREP_BLOCKS * 256)
    ws[ZERO_BASE + i] = 0.f;

  int r = blockIdx.x * 4 + (threadIdx.x >> 6);
  int lane = threadIdx.x & 63;
  const float* src;
  float* fdst = nullptr;
  float* tdst = nullptr;
  unsigned int* pdst = nullptr;
  int C, Cpack;
  bool norm = true;
  if (r < 64)       { src = Wpos + r * 3; fdst = ws + OWNPOS + r * 3; C = 3; Cpack = 0; }
  else if (r < 192) { int m = r - 64;  src = W1 + m * 64;  C = 64;  Cpack = 64;
                      pdst = (unsigned int*)(ws + OWB1) + m * 64; }
  else if (r < 320) { int m = r - 192; src = D1 + m * 64;  C = 64;  Cpack = 64; norm = false;
                      pdst = (unsigned int*)(ws + OWB1) + (m + 128) * 64; }
  else if (r < 448) { int m = r - 320; src = W2 + m * 256; C = 256; Cpack = 128;
                      pdst = (unsigned int*)(ws + OWB2) + m * 128;
                      tdst = ws + OWT2 + m; }
  else if (r < 576) { int m = r - 448; src = D2 + m * 256; C = 256; Cpack = 128; norm = false;
                      pdst = (unsigned int*)(ws + OWB2) + (m + 128) * 128;
                      tdst = ws + OWT2 + 128 + m; }
  else if (r < 704) { int m = r - 576; src = W3 + m * 256; C = 256; Cpack = 128;
                      pdst = (unsigned int*)(ws + OWB3) + m * 128;
                      tdst = ws + OWT3 + m; }
  else              { int m = r - 704; src = D3 + m * 256; C = 256; Cpack = 128; norm = false;
                      pdst = (unsigned int*)(ws + OWB3) + (m + 128) * 128;
                      tdst = ws + OWT3 + 128 + m; }

  float s = 1.f;
  if (norm) {
    float a = 0.f;
    for (int i = lane; i < C; i += 64) a += src[i];
#pragma unroll
    for (int off = 32; off > 0; off >>= 1) a += __shfl_xor(a, off);
    s = a;
  }
  for (int i = lane; i < C; i += 64) {
    float val = src[i] / s;  // exact when s==1
    if (fdst) fdst[i] = val;
    if (pdst && i < Cpack) pdst[i] = packhl(val);
    if (tdst && i >= 128) tdst[(i - 128) * 256] = val;
  }
}

// ---------------------------------------------------------------------------
// K2 (FUSED): exact top-20 KNN + edge features + pos layer + VN-LeakyReLU +
// mean over k -> bf16 hi/lo pack into Xp0.
// VALU-diet version (round 12):
//  - compact via per-lane 32-bit survivor mask + shfl prefix scan (replaces
//    32 serial ballot iterations); unordered buffer is selection-invariant.
//  - edge loop: neighbors stashed (pre-halved) in LDS by lanes 0..19, k-loop
//    does one broadcast ds_read_b128/iter instead of 3 __shfl (VALU->LDS pipe).
//  - f = dot/(dns+eps) via v_rcp + 1 Newton (tolerance-protected; distances
//    used for SELECTION remain bit-exact).
//  - k-invariant w1*c / e1*c terms hoisted.
// ---------------------------------------------------------------------------
__global__ __launch_bounds__(256, 4) void knn_edge_kernel(
    const float* __restrict__ pc, const float* __restrict__ Wn,
    const float* __restrict__ Dp, unsigned short* __restrict__ Xp0) {
  __shared__ float4 spt[N];                 // 32 KB (2x,2y,2z,xx)
  __shared__ unsigned short sbuf[4][512];   // 4 KB
  __shared__ float4 snb[4][KNN];            // 1.25 KB halved neighbor coords
  int tid = threadIdx.x;
  int b = blockIdx.y;
  const float* pcb = pc + (size_t)b * N * 3;
  for (int i = tid; i < N; i += 256) {
    float x = pcb[i * 3 + 0], y = pcb[i * 3 + 1], z = pcb[i * 3 + 2];
    float xx = __fadd_rn(__fadd_rn(__fmul_rn(x, x), __fmul_rn(y, y)), __fmul_rn(z, z));
    spt[i] = make_float4(2.f * x, 2.f * y, 2.f * z, xx);
  }
  __syncthreads();
  int wv = tid >> 6, lane = tid & 63;
  int q = blockIdx.x * 4 + wv;
  float4 qp = spt[q];
  float qx = 0.5f * qp.x, qy = 0.5f * qp.y, qz = 0.5f * qp.z, qxx = qp.w;

  float dv[32];
  float lmax = -INFINITY;
#pragma unroll
  for (int i = 0; i < 32; ++i) {
    float4 m = spt[i * 64 + lane];
    float A = __fadd_rn(__fadd_rn(__fmul_rn(m.x, qx), __fmul_rn(m.y, qy)),
                        __fmul_rn(m.z, qz));
    float d = __fsub_rn(__fsub_rn(A, qxx), m.w);
    dv[i] = d;
    lmax = fmaxf(lmax, d);
  }

  // value-only bitonic sort (descending) of the 64 lane-maxes; take #19
  float sv = lmax;
#pragma unroll
  for (int k = 2; k <= 64; k <<= 1) {
#pragma unroll
    for (int j = k >> 1; j > 0; j >>= 1) {
      float pv = __shfl_xor(sv, j);
      bool keep_max = ((lane & k) == 0) == ((lane & j) == 0);
      sv = keep_max ? fmaxf(sv, pv) : fminf(sv, pv);
    }
  }
  float tval = __shfl(sv, 19);  // 20th-largest lane-max <= V20 (provable)

  // registerized compact: per-lane survivor mask + prefix scan (unordered)
  unsigned msk = 0u;
#pragma unroll
  for (int i = 0; i < 32; ++i) msk |= (dv[i] >= tval) ? (1u << i) : 0u;
  int cnt = __popc(msk);
  int scan = cnt;
#pragma unroll
  for (int off = 1; off < 64; off <<= 1) {
    int t = __shfl_up(scan, off);
    scan += (lane >= off) ? t : 0;
  }
  int S = __shfl(scan, 63);
  int pos = scan - cnt;  // exclusive prefix
  unsigned mm = msk;
  while (mm) {
    int i = __ffs(mm) - 1;
    mm &= mm - 1;
    if (pos < 512) sbuf[wv][pos] = (unsigned short)(i * 64 + lane);
    ++pos;
  }

  auto distOf = [&](int m) -> float {
    float4 mp = spt[m];
    float A = __fadd_rn(__fadd_rn(__fmul_rn(mp.x, qx), __fmul_rn(mp.y, qy)),
                        __fmul_rn(mp.z, qz));
    return __fsub_rn(__fsub_rn(A, qxx), mp.w);
  };

  float cv = -INFINITY;
  int cm = 0x7fffffff;
  if (S <= 64) {
    if (lane < S) { cm = sbuf[wv][lane]; cv = distOf(cm); }
    wave_sort64(cv, cm, lane);
  } else if (S <= 512) {
    int p2 = 0;
    while (p2 < S) {
      if (lane >= KNN) {
        int t = p2 + lane - KNN;
        if (t < S) { cm = sbuf[wv][t]; cv = distOf(cm); }
        else       { cm = 0x7fffffff;  cv = -INFINITY; }
      }
      wave_sort64(cv, cm, lane);
      p2 += 64 - KNN;
    }
  } else {
    int p2 = 0;
    while (p2 < N) {
      if (lane >= KNN) {
        int t = p2 + lane - KNN;
        if (t < N) { cm = t; cv = distOf(t); }
        else       { cm = 0x7fffffff; cv = -INFINITY; }
      }
      wave_sort64(cv, cm, lane);
      p2 += 64 - KNN;
    }
  }

  // ---- edge + pos layer (lane o = channel o) -------------------------------
  // lanes 0..19 stash halved neighbor coords in LDS (same-wave RAW; compiler
  // orders via lgkmcnt — pattern proven by the sbuf use above)
  if (lane < KNN) {
    float4 t = spt[cm];
    snb[wv][lane] = make_float4(0.5f * t.x, 0.5f * t.y, 0.5f * t.z, 0.f);
  }
  int o = lane;
  float w0 = Wn[o * 3 + 0], w1 = Wn[o * 3 + 1], w2 = Wn[o * 3 + 2];
  float e0 = Dp[o * 3 + 0], e1 = Dp[o * 3 + 1], e2 = Dp[o * 3 + 2];
  float cx = qx, cy = qy, cz = qz;  // exact raw coords (0.5 * 2x)
  // hoisted k-invariant terms
  float pcx = w1 * cx, pcy = w1 * cy, pcz = w1 * cz;
  float dcx = e1 * cx, dcy = e1 * cy, dcz = e1 * cz;
  float ax = 0.f, ay = 0.f, az = 0.f;
#pragma unroll 4
  for (int k = 0; k < KNN; ++k) {
    float4 nb = snb[wv][k];   // broadcast LDS read
    float nx = nb.x, ny = nb.y, nz = nb.z;
    float ex = nx - cx, ey = ny - cy, ez = nz - cz;
    float rx = ny * cz - nz * cy;
    float ry = nz * cx - nx * cz;
    float rz = nx * cy - ny * cx;
    float px = fmaf(w0, ex, fmaf(w2, rx, pcx));
    float py = fmaf(w0, ey, fmaf(w2, ry, pcy));
    float pz = fmaf(w0, ez, fmaf(w2, rz, pcz));
    float dx = fmaf(e0, ex, fmaf(e2, rx, dcx));
    float dy = fmaf(e0, ey, fmaf(e2, ry, dcy));
    float dz = fmaf(e0, ez, fmaf(e2, rz, dcz));
    float dot = fmaf(px, dx, fmaf(py, dy, pz * dz));
    float dns = fmaf(dx, dx, fmaf(dy, dy, dz * dz)) + 1e-6f;
    float r0 = __builtin_amdgcn_rcpf(dns);
    r0 = r0 * fmaf(-dns, r0, 2.0f);          // 1 Newton step
    float f = (dot < 0.f) ? dot * r0 : 0.f;
    ax = fmaf(-f, dx, px) + ax;
    ay = fmaf(-f, dy, py) + ay;
    az = fmaf(-f, dz, pz) + az;
  }
  // store channel o of pixel q for v=0..2; contiguous 256B per (v) wave-store
  int pbase = ((q >> 4) * 48) + (q & 15);
  unsigned short* dst = Xp0 + ((size_t)b * P + pbase) * 128 + 2 * o;
  *(unsigned int*)(dst)              = packhl(ax * (1.f / 20.f));
  *(unsigned int*)(dst + 16 * 128)   = packhl(ay * (1.f / 20.f));
  *(unsigned int*)(dst + 32 * 128)   = packhl(az * (1.f / 20.f));
}

// ---------------------------------------------------------------------------
// K9: merge 8 out shadows -> d_out (mean over N).
// ---------------------------------------------------------------------------
__global__ __launch_bounds__(256) void out_merge_kernel(
    const float* __restrict__ outs, float* __restrict__ out) {
  int idx = blockIdx.x * 256 + threadIdx.x;  // 3072
  if (idx >= B * 384) return;
  float s = 0.f;
#pragma unroll
  for (int k = 0; k < 8; ++k) s += outs[k * 3072 + idx];
  out[idx] = s * (1.f / 2048.f);
}

// ---------------------------------------------------------------------------
// K4/K6/K8: MFMA VNT layer (round-8 proven form: LDS-staged X, full 256
// rows per block, grid 1024, in-kernel bias prologue, LDS out-tile epilogue).
// ---------------------------------------------------------------------------
template <int K2, bool HASPOOL, bool LAST>
__global__ __launch_bounds__(256, 4) void gemm_vnt_kernel(
    const unsigned short* __restrict__ Xp, const unsigned short* __restrict__ Wb,
    const float* __restrict__ ps, const float* __restrict__ Wt,
    unsigned short* __restrict__ Xq, float* __restrict__ pool,
    float* __restrict__ outs) {
  constexpr int KS = K2 / 32;
  constexpr int LDR = K2 + 8;   // halves; X-tile row stride
  constexpr int LDO = 132;      // floats; out-tile row stride
  __shared__ __align__(16) char smem[48 * LDO * 4];  // 25344 B, dual-purpose
  unsigned short* xt = (unsigned short*)smem;
  float* ot = (float*)smem;
  __shared__ float sb[768];
  __shared__ float spool[384];
  int tid = threadIdx.x;
  int bid = blockIdx.x;
  int b = bid >> 7;
  int nt = bid & 127;
  int p0 = nt * 48;

  // stage X tile [48][K2] -> LDS
  for (int ch = tid; ch < 48 * (K2 / 8); ch += 256) {
    int rp = ch / (K2 / 8), cc = ch % (K2 / 8);
    *(uint4*)(xt + rp * LDR + cc * 8) =
        *(const uint4*)(Xp + ((size_t)b * P + p0 + rp) * K2 + cc * 8);
  }
  if (HASPOOL) {
    // pooled mean (sum of 8 shadow copies) -> LDS
    for (int i = tid; i < 384; i += 256) {
      float x = 0.f;
#pragma unroll
      for (int k = 0; k < 8; ++k) x += ps[k * 3072 + b * 384 + i];
      spool[i] = x * (1.f / 2048.f);
    }
  }
  __syncthreads();
  if (HASPOOL) {
    // bias prologue: thread == stacked row m (0..127 = Wn, 128..255 = D)
    float s0 = 0.f, s1 = 0.f, s2 = 0.f;
#pragma unroll 4
    for (int c = 0; c < 128; ++c) {
      float x = Wt[c * 256 + tid];
      s0 = fmaf(x, spool[c * 3 + 0], s0);
      s1 = fmaf(x, spool[c * 3 + 1], s1);
      s2 = fmaf(x, spool[c * 3 + 2], s2);
    }
    sb[tid * 3 + 0] = s0;
    sb[tid * 3 + 1] = s1;
    sb[tid * 3 + 2] = s2;
    __syncthreads();
  }

  int w = tid >> 6, lane = tid & 63;
  int q = lane >> 4, cl = lane & 15;

  f32x4 acc[2][2][3] = {};  // [t][pd][v]
  const unsigned short* wbase = Wb + (size_t)cl * K2 + q * 8;

  bf16x8 acur[2][2], anxt[2][2];
#pragma unroll
  for (int t = 0; t < 2; ++t)
#pragma unroll
    for (int pd = 0; pd < 2; ++pd)
      acur[t][pd] = *(const bf16x8*)(wbase + (size_t)(32 * w + 16 * t + 128 * pd) * K2);

#pragma unroll
  for (int ks = 0; ks < KS; ++ks) {
    if (ks + 1 < KS) {
#pragma unroll
      for (int t = 0; t < 2; ++t)
#pragma unroll
        for (int pd = 0; pd < 2; ++pd)
          anxt[t][pd] = *(const bf16x8*)(wbase +
              (size_t)(32 * w + 16 * t + 128 * pd) * K2 + (ks + 1) * 32);
    }
    bf16x8 bb[3];
#pragma unroll
    for (int v = 0; v < 3; ++v)
      bb[v] = *(const bf16x8*)(xt + (v * 16 + cl) * LDR + ks * 32 + q * 8);
#pragma unroll
    for (int t = 0; t < 2; ++t)
#pragma unroll
      for (int pd = 0; pd < 2; ++pd)
#pragma unroll
        for (int v = 0; v < 3; ++v)
          acc[t][pd][v] = __builtin_amdgcn_mfma_f32_16x16x32_bf16(
              acur[t][pd], bb[v], acc[t][pd][v], 0, 0, 0);
#pragma unroll
    for (int t = 0; t < 2; ++t)
#pragma unroll
      for (int pd = 0; pd < 2; ++pd)
        acur[t][pd] = anxt[t][pd];
  }
  __syncthreads();  // X-tile dead; buffer becomes the fp32 out-tile

#pragma unroll
  for (int t = 0; t < 2; ++t) {
    float res[3][4];
#pragma unroll
    for (int r = 0; r < 4; ++r) {
      int o = 32 * w + 16 * t + 4 * q + r;
      float pv[3], dvv[3];
#pragma unroll
      for (int v = 0; v < 3; ++v) {
        pv[v] = acc[t][0][v][r] + (HASPOOL ? sb[o * 3 + v] : 0.f);
        dvv[v] = acc[t][1][v][r] + (HASPOOL ? sb[(128 + o) * 3 + v] : 0.f);
      }
      float dot = fmaf(pv[0], dvv[0], fmaf(pv[1], dvv[1], pv[2] * dvv[2]));
      float dns = fmaf(dvv[0], dvv[0], fmaf(dvv[1], dvv[1], dvv[2] * dvv[2]));
      float f = (dot < 0.f) ? dot / (dns + 1e-6f) : 0.f;
#pragma unroll
      for (int v = 0; v < 3; ++v) res[v][r] = pv[v] - f * dvv[v];
    }
    int o0 = 32 * w + 16 * t + 4 * q;
#pragma unroll
    for (int v = 0; v < 3; ++v) {
      f32x4 rv = {res[v][0], res[v][1], res[v][2], res[v][3]};
      *(f32x4*)(ot + (v * 16 + cl) * LDO + o0) = rv;
    }
  }
  __syncthreads();

  int shadow = (nt & 7) * 3072;
  for (int s = tid; s < 384; s += 256) {
    int o = s / 3, v = s % 3;
    float a2 = 0.f;
#pragma unroll
    for (int c = 0; c < 16; ++c) a2 += ot[(v * 16 + c) * LDO + o];
    if (LAST) atomicAdd(outs + shadow + b * 384 + s, a2);
    else      atomicAdd(pool + shadow + b * 384 + s, a2);
  }

  if (!LAST) {
    for (int s = tid; s < 1536; s += 256) {
      int pix = s >> 5, c4 = s & 31;
      const float* src = ot + pix * LDO + c4 * 4;
      uint4 vv;
      vv.x = packhl(src[0]);
      vv.y = packhl(src[1]);
      vv.z = packhl(src[2]);
      vv.w = packhl(src[3]);
      *(uint4*)(Xq + ((size_t)b * P + p0 + pix) * 256 + c4 * 8) = vv;
    }
  }
}

// ---------------------------------------------------------------------------
// launch
// ---------------------------------------------------------------------------
extern "C" void kernel_launch(void* const* d_in, const int* in_sizes, int n_in,
                              void* d_out, int out_size, void* d_ws, size_t ws_size,
                              hipStream_t stream) {
  (void)in_sizes; (void)n_in; (void)out_size; (void)ws_size;
  const float* pc   = (const float*)d_in[0];
  const float* Wpos = (const float*)d_in[1];
  const float* Dpos = (const float*)d_in[2];
  const float* W1   = (const float*)d_in[3];
  const float* D1   = (const float*)d_in[4];
  const float* W2   = (const float*)d_in[5];
  const float* D2   = (const float*)d_in[6];
  const float* W3   = (const float*)d_in[7];
  const float* D3   = (const float*)d_in[8];
  float* out = (float*)d_out;
  float* ws  = (float*)d_ws;

  prep_kernel<<<PREP_BLOCKS, 256, 0, stream>>>(Wpos, W1, D1, W2, D2, W3, D3, ws);
  // fused KNN + edge + pos layer -> Xp0
  knn_edge_kernel<<<dim3(N / 4, B), 256, 0, stream>>>(
      pc, ws + OWNPOS, Dpos, (unsigned short*)(ws + OXP0));
  // layer1: K2=128 -> Xp1 + ps1 shadows
  gemm_vnt_kernel<128, false, false><<<1024, 256, 0, stream>>>(
      (const unsigned short*)(ws + OXP0), (const unsigned short*)(ws + OWB1),
      nullptr, nullptr, (unsigned short*)(ws + OXP1), ws + OPS1, nullptr);
  // layer2: bias prologue from ps1 + WT2 -> Xp2 + ps2 shadows
  gemm_vnt_kernel<256, true, false><<<1024, 256, 0, stream>>>(
      (const unsigned short*)(ws + OXP1), (const unsigned short*)(ws + OWB2),
      ws + OPS1, ws + OWT2, (unsigned short*)(ws + OXP2), ws + OPS2, nullptr);
  // layer3: bias prologue from ps2 + WT3 -> out shadows
  gemm_vnt_kernel<256, true, true><<<1024, 256, 0, stream>>>(
      (const unsigned short*)(ws + OXP2), (const unsigned short*)(ws + OWB3),
      ws + OPS2, ws + OWT3, nullptr, nullptr, ws + OOUTS);
  out_merge_kernel<<<12, 256, 0, stream>>>(ws + OOUTS, out);
}

// Round 13
// 196.623 us; speedup vs baseline: 1.1883x; 1.0283x over previous
//
#include <hip/hip_runtime.h>
#include <hip/hip_bf16.h>
#include <math.h>

// ---------------------------------------------------------------------------
// Problem constants
// ---------------------------------------------------------------------------
constexpr int B = 8;
constexpr int N = 2048;
constexpr int KNN = 20;
constexpr int H = 128;
constexpr int P = 3 * N;  // 6144 pixels per batch
constexpr int QPW = 8;    // queries (waves) per knn_edge block

// ws layout (float offsets)
constexpr int OWNPOS = 0;         // 64x3 normalized W_pos (pad 256)
constexpr int OWT2   = 8448;      // W2/D2 second-half TRANSPOSED [c<128][m<256] (32768)
constexpr int OWT3   = 41216;     // W3/D3 second-half transposed (32768)
constexpr int OPS1   = 73984;     // poolsum1 shadows [8][B][128][3] = 24576
constexpr int OPS2   = 98560;     // poolsum2 shadows = 24576
constexpr int OOUTS  = 123136;    // out shadows [8][B][384] = 24576
constexpr int OWB1   = 160000;    // Wbig1 256x128 bf16 hi/lo (16384 f)
constexpr int OWB2   = 176384;    // Wbig2 256x256 bf16 hi/lo (32768 f)
constexpr int OWB3   = 209152;    // Wbig3 256x256 bf16 hi/lo (32768 f)
constexpr int OXP0   = 569600;    // Xp0 bf16 [b][P][128] (3145728 f-equiv)
constexpr int OXP2   = 569600;    // Xp2 bf16 [b][P][256] reuses Xp0 region
constexpr int OXP1   = 6861056;   // Xp1 bf16 [b][P][256] (6291456 f-equiv)
// max extent 13,152,512 floats ~= 52.6 MB

constexpr int ZERO_BASE = OPS1;   // prep zeroes [OPS1, OPS1+73728) = ps1+ps2+outs
constexpr int ZERO_CNT  = 73728;
constexpr int PREP_BLOCKS = 208;  // 832 waves = 832 rows

typedef __attribute__((ext_vector_type(8))) short bf16x8;
typedef __attribute__((ext_vector_type(4))) float f32x4;

__device__ __forceinline__ unsigned short f2bf(float x) {
  __hip_bfloat16 h = __float2bfloat16(x);
  return *(unsigned short*)&h;
}
__device__ __forceinline__ float bf2f(unsigned short u) {
  __hip_bfloat16 h;
  *(unsigned short*)&h = u;
  return __bfloat162float(h);
}
// pack x as (hi, lo) bf16 pair in one uint (hi at lower address)
__device__ __forceinline__ unsigned int packhl(float x) {
  unsigned short hi = f2bf(x);
  float lo = x - bf2f(hi);
  unsigned short ls = f2bf(lo);
  return (unsigned)hi | ((unsigned)ls << 16);
}

// ---------------------------------------------------------------------------
// Wave-wide bitonic sort of 64 (value,index) pairs, descending, tie->low idx.
// ---------------------------------------------------------------------------
__device__ __forceinline__ void wave_sort64(float& v, int& m, int lane) {
#pragma unroll
  for (int k = 2; k <= 64; k <<= 1) {
#pragma unroll
    for (int j = k >> 1; j > 0; j >>= 1) {
      float pv = __shfl_xor(v, j);
      int   pm = __shfl_xor(m, j);
      bool iam_lower   = (lane & j) == 0;
      bool dir_desc    = (lane & k) == 0;
      bool p_better    = (pv > v) || (pv == v && pm < m);
      bool want_better = (dir_desc == iam_lower);
      bool take        = (p_better == want_better);
      v = take ? pv : v;
      m = take ? pm : m;
    }
  }
}

// ---------------------------------------------------------------------------
// K1 (fused prep): zero shadows; normalize W rows; emit bf16 hi/lo packed
// first-C cols (stacked [Wn;D]); emit fp32 TRANSPOSED second-half cols.
// ---------------------------------------------------------------------------
__global__ __launch_bounds__(256) void prep_kernel(
    const float* __restrict__ Wpos, const float* __restrict__ W1,
    const float* __restrict__ D1, const float* __restrict__ W2,
    const float* __restrict__ D2, const float* __restrict__ W3,
    const float* __restrict__ D3, float* __restrict__ ws) {
  for (int i = blockIdx.x * 256 + threadIdx.x; i < ZERO_CNT; i += PREP_BLOCKS * 256)
    ws[ZERO_BASE + i] = 0.f;

  int r = blockIdx.x * 4 + (threadIdx.x >> 6);
  int lane = threadIdx.x & 63;
  const float* src;
  float* fdst = nullptr;
  float* tdst = nullptr;
  unsigned int* pdst = nullptr;
  int C, Cpack;
  bool norm = true;
  if (r < 64)       { src = Wpos + r * 3; fdst = ws + OWNPOS + r * 3; C = 3; Cpack = 0; }
  else if (r < 192) { int m = r - 64;  src = W1 + m * 64;  C = 64;  Cpack = 64;
                      pdst = (unsigned int*)(ws + OWB1) + m * 64; }
  else if (r < 320) { int m = r - 192; src = D1 + m * 64;  C = 64;  Cpack = 64; norm = false;
                      pdst = (unsigned int*)(ws + OWB1) + (m + 128) * 64; }
  else if (r < 448) { int m = r - 320; src = W2 + m * 256; C = 256; Cpack = 128;
                      pdst = (unsigned int*)(ws + OWB2) + m * 128;
                      tdst = ws + OWT2 + m; }
  else if (r < 576) { int m = r - 448; src = D2 + m * 256; C = 256; Cpack = 128; norm = false;
                      pdst = (unsigned int*)(ws + OWB2) + (m + 128) * 128;
                      tdst = ws + OWT2 + 128 + m; }
  else if (r < 704) { int m = r - 576; src = W3 + m * 256; C = 256; Cpack = 128;
                      pdst = (unsigned int*)(ws + OWB3) + m * 128;
                      tdst = ws + OWT3 + m; }
  else              { int m = r - 704; src = D3 + m * 256; C = 256; Cpack = 128; norm = false;
                      pdst = (unsigned int*)(ws + OWB3) + (m + 128) * 128;
                      tdst = ws + OWT3 + 128 + m; }

  float s = 1.f;
  if (norm) {
    float a = 0.f;
    for (int i = lane; i < C; i += 64) a += src[i];
#pragma unroll
    for (int off = 32; off > 0; off >>= 1) a += __shfl_xor(a, off);
    s = a;
  }
  for (int i = lane; i < C; i += 64) {
    float val = src[i] / s;  // exact when s==1
    if (fdst) fdst[i] = val;
    if (pdst && i < Cpack) pdst[i] = packhl(val);
    if (tdst && i >= 128) tdst[(i - 128) * 256] = val;
  }
}

// ---------------------------------------------------------------------------
// K2 (FUSED): exact top-20 KNN + edge + pos layer + VN-LeakyReLU + mean-k.
// Round 13: 512-thread blocks = 8 queries/block.  One 32KB point staging
// serves 8 waves; LDS/block ~38.4KB -> 4 blocks/CU -> 32 waves/CU (HW max).
// sbuf capped at 192 survivors/wave (E[S]~24); exact full-scan fallback for
// S>192 retained.  Per-wave algorithm unchanged from round 12.
// ---------------------------------------------------------------------------
__global__ __launch_bounds__(512, 8) void knn_edge_kernel(
    const float* __restrict__ pc, const float* __restrict__ Wn,
    const float* __restrict__ Dp, unsigned short* __restrict__ Xp0) {
  __shared__ float4 spt[N];                   // 32 KB (2x,2y,2z,xx)
  __shared__ unsigned short sbuf[QPW][192];   // 3 KB
  __shared__ float4 snb[QPW][KNN];            // 2.5 KB halved neighbor coords
  int tid = threadIdx.x;
  int b = blockIdx.y;
  const float* pcb = pc + (size_t)b * N * 3;
  for (int i = tid; i < N; i += 512) {
    float x = pcb[i * 3 + 0], y = pcb[i * 3 + 1], z = pcb[i * 3 + 2];
    float xx = __fadd_rn(__fadd_rn(__fmul_rn(x, x), __fmul_rn(y, y)), __fmul_rn(z, z));
    spt[i] = make_float4(2.f * x, 2.f * y, 2.f * z, xx);
  }
  __syncthreads();
  int wv = tid >> 6, lane = tid & 63;
  int q = blockIdx.x * QPW + wv;
  float4 qp = spt[q];
  float qx = 0.5f * qp.x, qy = 0.5f * qp.y, qz = 0.5f * qp.z, qxx = qp.w;

  float dv[32];
  float lmax = -INFINITY;
#pragma unroll
  for (int i = 0; i < 32; ++i) {
    float4 m = spt[i * 64 + lane];
    float A = __fadd_rn(__fadd_rn(__fmul_rn(m.x, qx), __fmul_rn(m.y, qy)),
                        __fmul_rn(m.z, qz));
    float d = __fsub_rn(__fsub_rn(A, qxx), m.w);
    dv[i] = d;
    lmax = fmaxf(lmax, d);
  }

  // value-only bitonic sort (descending) of the 64 lane-maxes; take #19
  float sv = lmax;
#pragma unroll
  for (int k = 2; k <= 64; k <<= 1) {
#pragma unroll
    for (int j = k >> 1; j > 0; j >>= 1) {
      float pv = __shfl_xor(sv, j);
      bool keep_max = ((lane & k) == 0) == ((lane & j) == 0);
      sv = keep_max ? fmaxf(sv, pv) : fminf(sv, pv);
    }
  }
  float tval = __shfl(sv, 19);  // 20th-largest lane-max <= V20 (provable)

  // registerized compact: per-lane survivor mask + shfl prefix scan
  unsigned msk = 0u;
#pragma unroll
  for (int i = 0; i < 32; ++i) msk |= (dv[i] >= tval) ? (1u << i) : 0u;
  int cnt = __popc(msk);
  int scan = cnt;
#pragma unroll
  for (int off = 1; off < 64; off <<= 1) {
    int t = __shfl_up(scan, off);
    scan += (lane >= off) ? t : 0;
  }
  int S = __shfl(scan, 63);
  int pos = scan - cnt;  // exclusive prefix
  unsigned mm = msk;
  while (mm) {
    int i = __ffs(mm) - 1;
    mm &= mm - 1;
    if (pos < 192) sbuf[wv][pos] = (unsigned short)(i * 64 + lane);
    ++pos;
  }

  auto distOf = [&](int m) -> float {
    float4 mp = spt[m];
    float A = __fadd_rn(__fadd_rn(__fmul_rn(mp.x, qx), __fmul_rn(mp.y, qy)),
                        __fmul_rn(mp.z, qz));
    return __fsub_rn(__fsub_rn(A, qxx), mp.w);
  };

  float cv = -INFINITY;
  int cm = 0x7fffffff;
  if (S <= 64) {
    if (lane < S) { cm = sbuf[wv][lane]; cv = distOf(cm); }
    wave_sort64(cv, cm, lane);
  } else if (S <= 192) {
    int p2 = 0;
    while (p2 < S) {
      if (lane >= KNN) {
        int t = p2 + lane - KNN;
        if (t < S) { cm = sbuf[wv][t]; cv = distOf(cm); }
        else       { cm = 0x7fffffff;  cv = -INFINITY; }
      }
      wave_sort64(cv, cm, lane);
      p2 += 64 - KNN;
    }
  } else {
    int p2 = 0;
    while (p2 < N) {
      if (lane >= KNN) {
        int t = p2 + lane - KNN;
        if (t < N) { cm = t; cv = distOf(t); }
        else       { cm = 0x7fffffff; cv = -INFINITY; }
      }
      wave_sort64(cv, cm, lane);
      p2 += 64 - KNN;
    }
  }

  // ---- edge + pos layer (lane o = channel o) -------------------------------
  if (lane < KNN) {
    float4 t = spt[cm];
    snb[wv][lane] = make_float4(0.5f * t.x, 0.5f * t.y, 0.5f * t.z, 0.f);
  }
  int o = lane;
  float w0 = Wn[o * 3 + 0], w1 = Wn[o * 3 + 1], w2 = Wn[o * 3 + 2];
  float e0 = Dp[o * 3 + 0], e1 = Dp[o * 3 + 1], e2 = Dp[o * 3 + 2];
  float cx = qx, cy = qy, cz = qz;  // exact raw coords (0.5 * 2x)
  float pcx = w1 * cx, pcy = w1 * cy, pcz = w1 * cz;
  float dcx = e1 * cx, dcy = e1 * cy, dcz = e1 * cz;
  float ax = 0.f, ay = 0.f, az = 0.f;
#pragma unroll 4
  for (int k = 0; k < KNN; ++k) {
    float4 nb = snb[wv][k];   // broadcast LDS read
    float nx = nb.x, ny = nb.y, nz = nb.z;
    float ex = nx - cx, ey = ny - cy, ez = nz - cz;
    float rx = ny * cz - nz * cy;
    float ry = nz * cx - nx * cz;
    float rz = nx * cy - ny * cx;
    float px = fmaf(w0, ex, fmaf(w2, rx, pcx));
    float py = fmaf(w0, ey, fmaf(w2, ry, pcy));
    float pz = fmaf(w0, ez, fmaf(w2, rz, pcz));
    float dx = fmaf(e0, ex, fmaf(e2, rx, dcx));
    float dy = fmaf(e0, ey, fmaf(e2, ry, dcy));
    float dz = fmaf(e0, ez, fmaf(e2, rz, dcz));
    float dot = fmaf(px, dx, fmaf(py, dy, pz * dz));
    float dns = fmaf(dx, dx, fmaf(dy, dy, dz * dz)) + 1e-6f;
    float r0 = __builtin_amdgcn_rcpf(dns);
    r0 = r0 * fmaf(-dns, r0, 2.0f);          // 1 Newton step
    float f = (dot < 0.f) ? dot * r0 : 0.f;
    ax = fmaf(-f, dx, px) + ax;
    ay = fmaf(-f, dy, py) + ay;
    az = fmaf(-f, dz, pz) + az;
  }
  // store channel o of pixel q; contiguous 256B per (v) wave-store
  int pbase = ((q >> 4) * 48) + (q & 15);
  unsigned short* dst = Xp0 + ((size_t)b * P + pbase) * 128 + 2 * o;
  *(unsigned int*)(dst)              = packhl(ax * (1.f / 20.f));
  *(unsigned int*)(dst + 16 * 128)   = packhl(ay * (1.f / 20.f));
  *(unsigned int*)(dst + 32 * 128)   = packhl(az * (1.f / 20.f));
}

// ---------------------------------------------------------------------------
// K9: merge 8 out shadows -> d_out (mean over N).
// ---------------------------------------------------------------------------
__global__ __launch_bounds__(256) void out_merge_kernel(
    const float* __restrict__ outs, float* __restrict__ out) {
  int idx = blockIdx.x * 256 + threadIdx.x;  // 3072
  if (idx >= B * 384) return;
  float s = 0.f;
#pragma unroll
  for (int k = 0; k < 8; ++k) s += outs[k * 3072 + idx];
  out[idx] = s * (1.f / 2048.f);
}

// ---------------------------------------------------------------------------
// K4/K6/K8: MFMA VNT layer (round-8 proven form: LDS-staged X, full 256
// rows per block, grid 1024, in-kernel bias prologue, LDS out-tile epilogue).
// ---------------------------------------------------------------------------
template <int K2, bool HASPOOL, bool LAST>
__global__ __launch_bounds__(256, 4) void gemm_vnt_kernel(
    const unsigned short* __restrict__ Xp, const unsigned short* __restrict__ Wb,
    const float* __restrict__ ps, const float* __restrict__ Wt,
    unsigned short* __restrict__ Xq, float* __restrict__ pool,
    float* __restrict__ outs) {
  constexpr int KS = K2 / 32;
  constexpr int LDR = K2 + 8;   // halves; X-tile row stride
  constexpr int LDO = 132;      // floats; out-tile row stride
  __shared__ __align__(16) char smem[48 * LDO * 4];  // 25344 B, dual-purpose
  unsigned short* xt = (unsigned short*)smem;
  float* ot = (float*)smem;
  __shared__ float sb[768];
  __shared__ float spool[384];
  int tid = threadIdx.x;
  int bid = blockIdx.x;
  int b = bid >> 7;
  int nt = bid & 127;
  int p0 = nt * 48;

  // stage X tile [48][K2] -> LDS
  for (int ch = tid; ch < 48 * (K2 / 8); ch += 256) {
    int rp = ch / (K2 / 8), cc = ch % (K2 / 8);
    *(uint4*)(xt + rp * LDR + cc * 8) =
        *(const uint4*)(Xp + ((size_t)b * P + p0 + rp) * K2 + cc * 8);
  }
  if (HASPOOL) {
    // pooled mean (sum of 8 shadow copies) -> LDS
    for (int i = tid; i < 384; i += 256) {
      float x = 0.f;
#pragma unroll
      for (int k = 0; k < 8; ++k) x += ps[k * 3072 + b * 384 + i];
      spool[i] = x * (1.f / 2048.f);
    }
  }
  __syncthreads();
  if (HASPOOL) {
    // bias prologue: thread == stacked row m (0..127 = Wn, 128..255 = D)
    float s0 = 0.f, s1 = 0.f, s2 = 0.f;
#pragma unroll 4
    for (int c = 0; c < 128; ++c) {
      float x = Wt[c * 256 + tid];
      s0 = fmaf(x, spool[c * 3 + 0], s0);
      s1 = fmaf(x, spool[c * 3 + 1], s1);
      s2 = fmaf(x, spool[c * 3 + 2], s2);
    }
    sb[tid * 3 + 0] = s0;
    sb[tid * 3 + 1] = s1;
    sb[tid * 3 + 2] = s2;
    __syncthreads();
  }

  int w = tid >> 6, lane = tid & 63;
  int q = lane >> 4, cl = lane & 15;

  f32x4 acc[2][2][3] = {};  // [t][pd][v]
  const unsigned short* wbase = Wb + (size_t)cl * K2 + q * 8;

  bf16x8 acur[2][2], anxt[2][2];
#pragma unroll
  for (int t = 0; t < 2; ++t)
#pragma unroll
    for (int pd = 0; pd < 2; ++pd)
      acur[t][pd] = *(const bf16x8*)(wbase + (size_t)(32 * w + 16 * t + 128 * pd) * K2);

#pragma unroll
  for (int ks = 0; ks < KS; ++ks) {
    if (ks + 1 < KS) {
#pragma unroll
      for (int t = 0; t < 2; ++t)
#pragma unroll
        for (int pd = 0; pd < 2; ++pd)
          anxt[t][pd] = *(const bf16x8*)(wbase +
              (size_t)(32 * w + 16 * t + 128 * pd) * K2 + (ks + 1) * 32);
    }
    bf16x8 bb[3];
#pragma unroll
    for (int v = 0; v < 3; ++v)
      bb[v] = *(const bf16x8*)(xt + (v * 16 + cl) * LDR + ks * 32 + q * 8);
#pragma unroll
    for (int t = 0; t < 2; ++t)
#pragma unroll
      for (int pd = 0; pd < 2; ++pd)
#pragma unroll
        for (int v = 0; v < 3; ++v)
          acc[t][pd][v] = __builtin_amdgcn_mfma_f32_16x16x32_bf16(
              acur[t][pd], bb[v], acc[t][pd][v], 0, 0, 0);
#pragma unroll
    for (int t = 0; t < 2; ++t)
#pragma unroll
      for (int pd = 0; pd < 2; ++pd)
        acur[t][pd] = anxt[t][pd];
  }
  __syncthreads();  // X-tile dead; buffer becomes the fp32 out-tile

#pragma unroll
  for (int t = 0; t < 2; ++t) {
    float res[3][4];
#pragma unroll
    for (int r = 0; r < 4; ++r) {
      int o = 32 * w + 16 * t + 4 * q + r;
      float pv[3], dvv[3];
#pragma unroll
      for (int v = 0; v < 3; ++v) {
        pv[v] = acc[t][0][v][r] + (HASPOOL ? sb[o * 3 + v] : 0.f);
        dvv[v] = acc[t][1][v][r] + (HASPOOL ? sb[(128 + o) * 3 + v] : 0.f);
      }
      float dot = fmaf(pv[0], dvv[0], fmaf(pv[1], dvv[1], pv[2] * dvv[2]));
      float dns = fmaf(dvv[0], dvv[0], fmaf(dvv[1], dvv[1], dvv[2] * dvv[2]));
      float f = (dot < 0.f) ? dot / (dns + 1e-6f) : 0.f;
#pragma unroll
      for (int v = 0; v < 3; ++v) res[v][r] = pv[v] - f * dvv[v];
    }
    int o0 = 32 * w + 16 * t + 4 * q;
#pragma unroll
    for (int v = 0; v < 3; ++v) {
      f32x4 rv = {res[v][0], res[v][1], res[v][2], res[v][3]};
      *(f32x4*)(ot + (v * 16 + cl) * LDO + o0) = rv;
    }
  }
  __syncthreads();

  int shadow = (nt & 7) * 3072;
  for (int s = tid; s < 384; s += 256) {
    int o = s / 3, v = s % 3;
    float a2 = 0.f;
#pragma unroll
    for (int c = 0; c < 16; ++c) a2 += ot[(v * 16 + c) * LDO + o];
    if (LAST) atomicAdd(outs + shadow + b * 384 + s, a2);
    else      atomicAdd(pool + shadow + b * 384 + s, a2);
  }

  if (!LAST) {
    for (int s = tid; s < 1536; s += 256) {
      int pix = s >> 5, c4 = s & 31;
      const float* src = ot + pix * LDO + c4 * 4;
      uint4 vv;
      vv.x = packhl(src[0]);
      vv.y = packhl(src[1]);
      vv.z = packhl(src[2]);
      vv.w = packhl(src[3]);
      *(uint4*)(Xq + ((size_t)b * P + p0 + pix) * 256 + c4 * 8) = vv;
    }
  }
}

// ---------------------------------------------------------------------------
// launch
// ---------------------------------------------------------------------------
extern "C" void kernel_launch(void* const* d_in, const int* in_sizes, int n_in,
                              void* d_out, int out_size, void* d_ws, size_t ws_size,
                              hipStream_t stream) {
  (void)in_sizes; (void)n_in; (void)out_size; (void)ws_size;
  const float* pc   = (const float*)d_in[0];
  const float* Wpos = (const float*)d_in[1];
  const float* Dpos = (const float*)d_in[2];
  const float* W1   = (const float*)d_in[3];
  const float* D1   = (const float*)d_in[4];
  const float* W2   = (const float*)d_in[5];
  const float* D2   = (const float*)d_in[6];
  const float* W3   = (const float*)d_in[7];
  const float* D3   = (const float*)d_in[8];
  float* out = (float*)d_out;
  float* ws  = (float*)d_ws;

  prep_kernel<<<PREP_BLOCKS, 256, 0, stream>>>(Wpos, W1, D1, W2, D2, W3, D3, ws);
  // fused KNN + edge + pos layer -> Xp0  (8 queries per 512-thread block)
  knn_edge_kernel<<<dim3(N / QPW, B), 512, 0, stream>>>(
      pc, ws + OWNPOS, Dpos, (unsigned short*)(ws + OXP0));
  // layer1: K2=128 -> Xp1 + ps1 shadows
  gemm_vnt_kernel<128, false, false><<<1024, 256, 0, stream>>>(
      (const unsigned short*)(ws + OXP0), (const unsigned short*)(ws + OWB1),
      nullptr, nullptr, (unsigned short*)(ws + OXP1), ws + OPS1, nullptr);
  // layer2: bias prologue from ps1 + WT2 -> Xp2 + ps2 shadows
  gemm_vnt_kernel<256, true, false><<<1024, 256, 0, stream>>>(
      (const unsigned short*)(ws + OXP1), (const unsigned short*)(ws + OWB2),
      ws + OPS1, ws + OWT2, (unsigned short*)(ws + OXP2), ws + OPS2, nullptr);
  // layer3: bias prologue from ps2 + WT3 -> out shadows
  gemm_vnt_kernel<256, true, true><<<1024, 256, 0, stream>>>(
      (const unsigned short*)(ws + OXP2), (const unsigned short*)(ws + OWB3),
      ws + OPS2, ws + OWT3, nullptr, nullptr, ws + OOUTS);
  out_merge_kernel<<<12, 256, 0, stream>>>(ws + OOUTS, out);
}

// Round 14
// 194.382 us; speedup vs baseline: 1.2020x; 1.0115x over previous
//
#include <hip/hip_runtime.h>
#include <hip/hip_bf16.h>
#include <math.h>

// ---------------------------------------------------------------------------
// Problem constants
// ---------------------------------------------------------------------------
constexpr int B = 8;
constexpr int N = 2048;
constexpr int KNN = 20;
constexpr int H = 128;
constexpr int P = 3 * N;  // 6144 pixels per batch
constexpr int QPW = 8;    // queries (waves) per knn_edge block

// ws layout (float offsets)
constexpr int OWT2   = 8448;      // W2/D2 second-half TRANSPOSED [c<128][m<256] (32768)
constexpr int OWT3   = 41216;     // W3/D3 second-half transposed (32768)
constexpr int OPS1   = 73984;     // poolsum1 shadows [8][B][128][3] = 24576
constexpr int OPS2   = 98560;     // poolsum2 shadows = 24576
constexpr int OOUTS  = 123136;    // out shadows [8][B][384] = 24576
constexpr int OWB1   = 160000;    // Wbig1 256x128 bf16 hi/lo (16384 f)
constexpr int OWB2   = 176384;    // Wbig2 256x256 bf16 hi/lo (32768 f)
constexpr int OWB3   = 209152;    // Wbig3 256x256 bf16 hi/lo (32768 f)
constexpr int OXP0   = 569600;    // Xp0 bf16 [b][P][128] (3145728 f-equiv)
constexpr int OXP2   = 569600;    // Xp2 bf16 [b][P][256] reuses Xp0 region
constexpr int OXP1   = 6861056;   // Xp1 bf16 [b][P][256] (6291456 f-equiv)
// max extent 13,152,512 floats ~= 52.6 MB

constexpr int ZERO_BASE = OPS1;   // zeroed region = ps1+ps2+outs
constexpr int ZERO_CNT  = 73728;

typedef __attribute__((ext_vector_type(8))) short bf16x8;
typedef __attribute__((ext_vector_type(4))) float f32x4;

__device__ __forceinline__ unsigned short f2bf(float x) {
  __hip_bfloat16 h = __float2bfloat16(x);
  return *(unsigned short*)&h;
}
__device__ __forceinline__ float bf2f(unsigned short u) {
  __hip_bfloat16 h;
  *(unsigned short*)&h = u;
  return __bfloat162float(h);
}
// pack x as (hi, lo) bf16 pair in one uint (hi at lower address)
__device__ __forceinline__ unsigned int packhl(float x) {
  unsigned short hi = f2bf(x);
  float lo = x - bf2f(hi);
  unsigned short ls = f2bf(lo);
  return (unsigned)hi | ((unsigned)ls << 16);
}

// ---------------------------------------------------------------------------
// Wave-wide bitonic sort of 64 (value,index) pairs, descending, tie->low idx.
// ---------------------------------------------------------------------------
__device__ __forceinline__ void wave_sort64(float& v, int& m, int lane) {
#pragma unroll
  for (int k = 2; k <= 64; k <<= 1) {
#pragma unroll
    for (int j = k >> 1; j > 0; j >>= 1) {
      float pv = __shfl_xor(v, j);
      int   pm = __shfl_xor(m, j);
      bool iam_lower   = (lane & j) == 0;
      bool dir_desc    = (lane & k) == 0;
      bool p_better    = (pv > v) || (pv == v && pm < m);
      bool want_better = (dir_desc == iam_lower);
      bool take        = (p_better == want_better);
      v = take ? pv : v;
      m = take ? pm : m;
    }
  }
}

// ---------------------------------------------------------------------------
// K2 (FUSED, round 14): prep (weight pack/normalize/transpose + shadow zero)
// folded into knn_edge.  Blocks 0..95 each run 8 prep rows (one per wave);
// zeroing distributed one store/thread over the first blocks.  W_pos is
// normalized per-lane at the edge stage (butterfly-order sum (w0+w2)+w1 and
// IEEE divide -> bit-identical to the old prep output).  prep outputs are
// consumed only by the gemm launches that follow on the stream.
// Per-wave KNN/edge algorithm unchanged from round 13.
// ---------------------------------------------------------------------------
__global__ __launch_bounds__(512, 8) void knn_edge_kernel(
    const float* __restrict__ pc, const float* __restrict__ Wpos,
    const float* __restrict__ Dp,
    const float* __restrict__ W1, const float* __restrict__ D1,
    const float* __restrict__ W2, const float* __restrict__ D2,
    const float* __restrict__ W3, const float* __restrict__ D3,
    float* __restrict__ ws) {
  __shared__ float4 spt[N];                   // 32 KB (2x,2y,2z,xx)
  __shared__ unsigned short sbuf[QPW][192];   // 3 KB
  __shared__ float4 snb[QPW][KNN];            // 2.5 KB halved neighbor coords
  int tid = threadIdx.x;
  int b = blockIdx.y;
  int bid = blockIdx.y * gridDim.x + blockIdx.x;  // 0..2047
  int wv = tid >> 6, lane = tid & 63;
  unsigned short* Xp0 = (unsigned short*)(ws + OXP0);

  // ---- folded prep: distributed shadow zeroing (1 store/thread) ----------
  {
    int zi = bid * 512 + tid;
    if (zi < ZERO_CNT) ws[ZERO_BASE + zi] = 0.f;
  }
  // ---- folded prep: 768 weight rows over blocks 0..95 (one wave/row) -----
  if (bid < 96) {
    int rr = bid * 8 + wv;  // 0..767
    const float* src;
    float* tdst = nullptr;
    unsigned int* pdst;
    int C, Cpack;
    bool norm;
    if (rr < 128)      { src = W1 + rr * 64;            C = 64;  Cpack = 64;  norm = true;
                         pdst = (unsigned int*)(ws + OWB1) + rr * 64; }
    else if (rr < 256) { int m = rr - 128; src = D1 + m * 64;  C = 64;  Cpack = 64;  norm = false;
                         pdst = (unsigned int*)(ws + OWB1) + (m + 128) * 64; }
    else if (rr < 384) { int m = rr - 256; src = W2 + m * 256; C = 256; Cpack = 128; norm = true;
                         pdst = (unsigned int*)(ws + OWB2) + m * 128; tdst = ws + OWT2 + m; }
    else if (rr < 512) { int m = rr - 384; src = D2 + m * 256; C = 256; Cpack = 128; norm = false;
                         pdst = (unsigned int*)(ws + OWB2) + (m + 128) * 128; tdst = ws + OWT2 + 128 + m; }
    else if (rr < 640) { int m = rr - 512; src = W3 + m * 256; C = 256; Cpack = 128; norm = true;
                         pdst = (unsigned int*)(ws + OWB3) + m * 128; tdst = ws + OWT3 + m; }
    else               { int m = rr - 640; src = D3 + m * 256; C = 256; Cpack = 128; norm = false;
                         pdst = (unsigned int*)(ws + OWB3) + (m + 128) * 128; tdst = ws + OWT3 + 128 + m; }
    float s = 1.f;
    if (norm) {
      float a = 0.f;
      for (int i = lane; i < C; i += 64) a += src[i];
#pragma unroll
      for (int off = 32; off > 0; off >>= 1) a += __shfl_xor(a, off);
      s = a;
    }
    for (int i = lane; i < C; i += 64) {
      float val = src[i] / s;  // exact when s==1
      if (i < Cpack) pdst[i] = packhl(val);
      if (tdst && i >= 128) tdst[(i - 128) * 256] = val;
    }
  }

  // ---- stage point cloud ---------------------------------------------------
  const float* pcb = pc + (size_t)b * N * 3;
  for (int i = tid; i < N; i += 512) {
    float x = pcb[i * 3 + 0], y = pcb[i * 3 + 1], z = pcb[i * 3 + 2];
    float xx = __fadd_rn(__fadd_rn(__fmul_rn(x, x), __fmul_rn(y, y)), __fmul_rn(z, z));
    spt[i] = make_float4(2.f * x, 2.f * y, 2.f * z, xx);
  }
  __syncthreads();
  int q = blockIdx.x * QPW + wv;
  float4 qp = spt[q];
  float qx = 0.5f * qp.x, qy = 0.5f * qp.y, qz = 0.5f * qp.z, qxx = qp.w;

  float dv[32];
  float lmax = -INFINITY;
#pragma unroll
  for (int i = 0; i < 32; ++i) {
    float4 m = spt[i * 64 + lane];
    float A = __fadd_rn(__fadd_rn(__fmul_rn(m.x, qx), __fmul_rn(m.y, qy)),
                        __fmul_rn(m.z, qz));
    float d = __fsub_rn(__fsub_rn(A, qxx), m.w);
    dv[i] = d;
    lmax = fmaxf(lmax, d);
  }

  // value-only bitonic sort (descending) of the 64 lane-maxes; take #19
  float sv = lmax;
#pragma unroll
  for (int k = 2; k <= 64; k <<= 1) {
#pragma unroll
    for (int j = k >> 1; j > 0; j >>= 1) {
      float pv = __shfl_xor(sv, j);
      bool keep_max = ((lane & k) == 0) == ((lane & j) == 0);
      sv = keep_max ? fmaxf(sv, pv) : fminf(sv, pv);
    }
  }
  float tval = __shfl(sv, 19);  // 20th-largest lane-max <= V20 (provable)

  // registerized compact: per-lane survivor mask + shfl prefix scan
  unsigned msk = 0u;
#pragma unroll
  for (int i = 0; i < 32; ++i) msk |= (dv[i] >= tval) ? (1u << i) : 0u;
  int cnt = __popc(msk);
  int scan = cnt;
#pragma unroll
  for (int off = 1; off < 64; off <<= 1) {
    int t = __shfl_up(scan, off);
    scan += (lane >= off) ? t : 0;
  }
  int S = __shfl(scan, 63);
  int pos = scan - cnt;  // exclusive prefix
  unsigned mm = msk;
  while (mm) {
    int i = __ffs(mm) - 1;
    mm &= mm - 1;
    if (pos < 192) sbuf[wv][pos] = (unsigned short)(i * 64 + lane);
    ++pos;
  }

  auto distOf = [&](int m) -> float {
    float4 mp = spt[m];
    float A = __fadd_rn(__fadd_rn(__fmul_rn(mp.x, qx), __fmul_rn(mp.y, qy)),
                        __fmul_rn(mp.z, qz));
    return __fsub_rn(__fsub_rn(A, qxx), mp.w);
  };

  float cv = -INFINITY;
  int cm = 0x7fffffff;
  if (S <= 64) {
    if (lane < S) { cm = sbuf[wv][lane]; cv = distOf(cm); }
    wave_sort64(cv, cm, lane);
  } else if (S <= 192) {
    int p2 = 0;
    while (p2 < S) {
      if (lane >= KNN) {
        int t = p2 + lane - KNN;
        if (t < S) { cm = sbuf[wv][t]; cv = distOf(cm); }
        else       { cm = 0x7fffffff;  cv = -INFINITY; }
      }
      wave_sort64(cv, cm, lane);
      p2 += 64 - KNN;
    }
  } else {
    int p2 = 0;
    while (p2 < N) {
      if (lane >= KNN) {
        int t = p2 + lane - KNN;
        if (t < N) { cm = t; cv = distOf(t); }
        else       { cm = 0x7fffffff; cv = -INFINITY; }
      }
      wave_sort64(cv, cm, lane);
      p2 += 64 - KNN;
    }
  }

  // ---- edge + pos layer (lane o = channel o) -------------------------------
  if (lane < KNN) {
    float4 t = spt[cm];
    snb[wv][lane] = make_float4(0.5f * t.x, 0.5f * t.y, 0.5f * t.z, 0.f);
  }
  int o = lane;
  // per-lane W_pos row normalization (bit-identical to old prep: butterfly
  // sum order for 3 elements == (w0+w2)+w1; IEEE divide per element)
  float w0 = Wpos[o * 3 + 0], w1 = Wpos[o * 3 + 1], w2 = Wpos[o * 3 + 2];
  {
    float s = (w0 + w2) + w1;
    w0 = w0 / s; w1 = w1 / s; w2 = w2 / s;
  }
  float e0 = Dp[o * 3 + 0], e1 = Dp[o * 3 + 1], e2 = Dp[o * 3 + 2];
  float cx = qx, cy = qy, cz = qz;  // exact raw coords (0.5 * 2x)
  float pcx = w1 * cx, pcy = w1 * cy, pcz = w1 * cz;
  float dcx = e1 * cx, dcy = e1 * cy, dcz = e1 * cz;
  float ax = 0.f, ay = 0.f, az = 0.f;
#pragma unroll 4
  for (int k = 0; k < KNN; ++k) {
    float4 nb = snb[wv][k];   // broadcast LDS read
    float nx = nb.x, ny = nb.y, nz = nb.z;
    float ex = nx - cx, ey = ny - cy, ez = nz - cz;
    float rx = ny * cz - nz * cy;
    float ry = nz * cx - nx * cz;
    float rz = nx * cy - ny * cx;
    float px = fmaf(w0, ex, fmaf(w2, rx, pcx));
    float py = fmaf(w0, ey, fmaf(w2, ry, pcy));
    float pz = fmaf(w0, ez, fmaf(w2, rz, pcz));
    float dx = fmaf(e0, ex, fmaf(e2, rx, dcx));
    float dy = fmaf(e0, ey, fmaf(e2, ry, dcy));
    float dz = fmaf(e0, ez, fmaf(e2, rz, dcz));
    float dot = fmaf(px, dx, fmaf(py, dy, pz * dz));
    float dns = fmaf(dx, dx, fmaf(dy, dy, dz * dz)) + 1e-6f;
    float r0 = __builtin_amdgcn_rcpf(dns);
    r0 = r0 * fmaf(-dns, r0, 2.0f);          // 1 Newton step
    float f = (dot < 0.f) ? dot * r0 : 0.f;
    ax = fmaf(-f, dx, px) + ax;
    ay = fmaf(-f, dy, py) + ay;
    az = fmaf(-f, dz, pz) + az;
  }
  // store channel o of pixel q; contiguous 256B per (v) wave-store
  int pbase = ((q >> 4) * 48) + (q & 15);
  unsigned short* dst = Xp0 + ((size_t)b * P + pbase) * 128 + 2 * o;
  *(unsigned int*)(dst)              = packhl(ax * (1.f / 20.f));
  *(unsigned int*)(dst + 16 * 128)   = packhl(ay * (1.f / 20.f));
  *(unsigned int*)(dst + 32 * 128)   = packhl(az * (1.f / 20.f));
}

// ---------------------------------------------------------------------------
// K9: merge 8 out shadows -> d_out (mean over N).
// ---------------------------------------------------------------------------
__global__ __launch_bounds__(256) void out_merge_kernel(
    const float* __restrict__ outs, float* __restrict__ out) {
  int idx = blockIdx.x * 256 + threadIdx.x;  // 3072
  if (idx >= B * 384) return;
  float s = 0.f;
#pragma unroll
  for (int k = 0; k < 8; ++k) s += outs[k * 3072 + idx];
  out[idx] = s * (1.f / 2048.f);
}

// ---------------------------------------------------------------------------
// K4/K6/K8: MFMA VNT layer (round-8 proven form: LDS-staged X, full 256
// rows per block, grid 1024, in-kernel bias prologue, LDS out-tile epilogue).
// ---------------------------------------------------------------------------
template <int K2, bool HASPOOL, bool LAST>
__global__ __launch_bounds__(256, 4) void gemm_vnt_kernel(
    const unsigned short* __restrict__ Xp, const unsigned short* __restrict__ Wb,
    const float* __restrict__ ps, const float* __restrict__ Wt,
    unsigned short* __restrict__ Xq, float* __restrict__ pool,
    float* __restrict__ outs) {
  constexpr int KS = K2 / 32;
  constexpr int LDR = K2 + 8;   // halves; X-tile row stride
  constexpr int LDO = 132;      // floats; out-tile row stride
  __shared__ __align__(16) char smem[48 * LDO * 4];  // 25344 B, dual-purpose
  unsigned short* xt = (unsigned short*)smem;
  float* ot = (float*)smem;
  __shared__ float sb[768];
  __shared__ float spool[384];
  int tid = threadIdx.x;
  int bid = blockIdx.x;
  int b = bid >> 7;
  int nt = bid & 127;
  int p0 = nt * 48;

  // stage X tile [48][K2] -> LDS
  for (int ch = tid; ch < 48 * (K2 / 8); ch += 256) {
    int rp = ch / (K2 / 8), cc = ch % (K2 / 8);
    *(uint4*)(xt + rp * LDR + cc * 8) =
        *(const uint4*)(Xp + ((size_t)b * P + p0 + rp) * K2 + cc * 8);
  }
  if (HASPOOL) {
    // pooled mean (sum of 8 shadow copies) -> LDS
    for (int i = tid; i < 384; i += 256) {
      float x = 0.f;
#pragma unroll
      for (int k = 0; k < 8; ++k) x += ps[k * 3072 + b * 384 + i];
      spool[i] = x * (1.f / 2048.f);
    }
  }
  __syncthreads();
  if (HASPOOL) {
    // bias prologue: thread == stacked row m (0..127 = Wn, 128..255 = D)
    float s0 = 0.f, s1 = 0.f, s2 = 0.f;
#pragma unroll 4
    for (int c = 0; c < 128; ++c) {
      float x = Wt[c * 256 + tid];
      s0 = fmaf(x, spool[c * 3 + 0], s0);
      s1 = fmaf(x, spool[c * 3 + 1], s1);
      s2 = fmaf(x, spool[c * 3 + 2], s2);
    }
    sb[tid * 3 + 0] = s0;
    sb[tid * 3 + 1] = s1;
    sb[tid * 3 + 2] = s2;
    __syncthreads();
  }

  int w = tid >> 6, lane = tid & 63;
  int q = lane >> 4, cl = lane & 15;

  f32x4 acc[2][2][3] = {};  // [t][pd][v]
  const unsigned short* wbase = Wb + (size_t)cl * K2 + q * 8;

  bf16x8 acur[2][2], anxt[2][2];
#pragma unroll
  for (int t = 0; t < 2; ++t)
#pragma unroll
    for (int pd = 0; pd < 2; ++pd)
      acur[t][pd] = *(const bf16x8*)(wbase + (size_t)(32 * w + 16 * t + 128 * pd) * K2);

#pragma unroll
  for (int ks = 0; ks < KS; ++ks) {
    if (ks + 1 < KS) {
#pragma unroll
      for (int t = 0; t < 2; ++t)
#pragma unroll
        for (int pd = 0; pd < 2; ++pd)
          anxt[t][pd] = *(const bf16x8*)(wbase +
              (size_t)(32 * w + 16 * t + 128 * pd) * K2 + (ks + 1) * 32);
    }
    bf16x8 bb[3];
#pragma unroll
    for (int v = 0; v < 3; ++v)
      bb[v] = *(const bf16x8*)(xt + (v * 16 + cl) * LDR + ks * 32 + q * 8);
#pragma unroll
    for (int t = 0; t < 2; ++t)
#pragma unroll
      for (int pd = 0; pd < 2; ++pd)
#pragma unroll
        for (int v = 0; v < 3; ++v)
          acc[t][pd][v] = __builtin_amdgcn_mfma_f32_16x16x32_bf16(
              acur[t][pd], bb[v], acc[t][pd][v], 0, 0, 0);
#pragma unroll
    for (int t = 0; t < 2; ++t)
#pragma unroll
      for (int pd = 0; pd < 2; ++pd)
        acur[t][pd] = anxt[t][pd];
  }
  __syncthreads();  // X-tile dead; buffer becomes the fp32 out-tile

#pragma unroll
  for (int t = 0; t < 2; ++t) {
    float res[3][4];
#pragma unroll
    for (int r = 0; r < 4; ++r) {
      int o = 32 * w + 16 * t + 4 * q + r;
      float pv[3], dvv[3];
#pragma unroll
      for (int v = 0; v < 3; ++v) {
        pv[v] = acc[t][0][v][r] + (HASPOOL ? sb[o * 3 + v] : 0.f);
        dvv[v] = acc[t][1][v][r] + (HASPOOL ? sb[(128 + o) * 3 + v] : 0.f);
      }
      float dot = fmaf(pv[0], dvv[0], fmaf(pv[1], dvv[1], pv[2] * dvv[2]));
      float dns = fmaf(dvv[0], dvv[0], fmaf(dvv[1], dvv[1], dvv[2] * dvv[2]));
      float f = (dot < 0.f) ? dot / (dns + 1e-6f) : 0.f;
#pragma unroll
      for (int v = 0; v < 3; ++v) res[v][r] = pv[v] - f * dvv[v];
    }
    int o0 = 32 * w + 16 * t + 4 * q;
#pragma unroll
    for (int v = 0; v < 3; ++v) {
      f32x4 rv = {res[v][0], res[v][1], res[v][2], res[v][3]};
      *(f32x4*)(ot + (v * 16 + cl) * LDO + o0) = rv;
    }
  }
  __syncthreads();

  int shadow = (nt & 7) * 3072;
  for (int s = tid; s < 384; s += 256) {
    int o = s / 3, v = s % 3;
    float a2 = 0.f;
#pragma unroll
    for (int c = 0; c < 16; ++c) a2 += ot[(v * 16 + c) * LDO + o];
    if (LAST) atomicAdd(outs + shadow + b * 384 + s, a2);
    else      atomicAdd(pool + shadow + b * 384 + s, a2);
  }

  if (!LAST) {
    for (int s = tid; s < 1536; s += 256) {
      int pix = s >> 5, c4 = s & 31;
      const float* src = ot + pix * LDO + c4 * 4;
      uint4 vv;
      vv.x = packhl(src[0]);
      vv.y = packhl(src[1]);
      vv.z = packhl(src[2]);
      vv.w = packhl(src[3]);
      *(uint4*)(Xq + ((size_t)b * P + p0 + pix) * 256 + c4 * 8) = vv;
    }
  }
}

// ---------------------------------------------------------------------------
// launch
// ---------------------------------------------------------------------------
extern "C" void kernel_launch(void* const* d_in, const int* in_sizes, int n_in,
                              void* d_out, int out_size, void* d_ws, size_t ws_size,
                              hipStream_t stream) {
  (void)in_sizes; (void)n_in; (void)out_size; (void)ws_size;
  const float* pc   = (const float*)d_in[0];
  const float* Wpos = (const float*)d_in[1];
  const float* Dpos = (const float*)d_in[2];
  const float* W1   = (const float*)d_in[3];
  const float* D1   = (const float*)d_in[4];
  const float* W2   = (const float*)d_in[5];
  const float* D2   = (const float*)d_in[6];
  const float* W3   = (const float*)d_in[7];
  const float* D3   = (const float*)d_in[8];
  float* out = (float*)d_out;
  float* ws  = (float*)d_ws;

  // fused prep + KNN + edge + pos layer -> Xp0 (+ packed weights, zeroed shadows)
  knn_edge_kernel<<<dim3(N / QPW, B), 512, 0, stream>>>(
      pc, Wpos, Dpos, W1, D1, W2, D2, W3, D3, ws);
  // layer1: K2=128 -> Xp1 + ps1 shadows
  gemm_vnt_kernel<128, false, false><<<1024, 256, 0, stream>>>(
      (const unsigned short*)(ws + OXP0), (const unsigned short*)(ws + OWB1),
      nullptr, nullptr, (unsigned short*)(ws + OXP1), ws + OPS1, nullptr);
  // layer2: bias prologue from ps1 + WT2 -> Xp2 + ps2 shadows
  gemm_vnt_kernel<256, true, false><<<1024, 256, 0, stream>>>(
      (const unsigned short*)(ws + OXP1), (const unsigned short*)(ws + OWB2),
      ws + OPS1, ws + OWT2, (unsigned short*)(ws + OXP2), ws + OPS2, nullptr);
  // layer3: bias prologue from ps2 + WT3 -> out shadows
  gemm_vnt_kernel<256, true, true><<<1024, 256, 0, stream>>>(
      (const unsigned short*)(ws + OXP2), (const unsigned short*)(ws + OWB3),
      ws + OPS2, ws + OWT3, nullptr, nullptr, ws + OOUTS);
  out_merge_kernel<<<12, 256, 0, stream>>>(ws + OOUTS, out);
}

// Round 15
// 179.615 us; speedup vs baseline: 1.3008x; 1.0822x over previous
//
#include <hip/hip_runtime.h>
#include <hip/hip_bf16.h>
#include <math.h>

// ---------------------------------------------------------------------------
// Problem constants
// ---------------------------------------------------------------------------
constexpr int B = 8;
constexpr int N = 2048;
constexpr int KNN = 20;
constexpr int H = 128;
constexpr int P = 3 * N;  // 6144 pixels per batch
constexpr int QPW = 8;    // queries (waves) per knn_edge block

// ws layout (float offsets)
constexpr int OWT2   = 8448;      // W2/D2 second-half TRANSPOSED [c<128][m<256] (32768)
constexpr int OWT3   = 41216;     // W3/D3 second-half transposed (32768)
constexpr int OPS1   = 73984;     // poolsum1 shadows [8][B][128][3] = 24576
constexpr int OPS2   = 98560;     // poolsum2 shadows = 24576
constexpr int OOUTS  = 123136;    // out shadows [8][B][384] = 24576
constexpr int OWB1   = 160000;    // Wbig1 bf16 hi/lo, FRAGMENT-MAJOR [ks][256][32h] (16384 f)
constexpr int OWB2   = 176384;    // Wbig2 fragment-major (32768 f)
constexpr int OWB3   = 209152;    // Wbig3 fragment-major (32768 f)
constexpr int OXP0   = 569600;    // Xp0 bf16 [b][P][128] (3145728 f-equiv)
constexpr int OXP2   = 569600;    // Xp2 bf16 [b][P][256] reuses Xp0 region
constexpr int OXP1   = 6861056;   // Xp1 bf16 [b][P][256] (6291456 f-equiv)
// max extent 13,152,512 floats ~= 52.6 MB

constexpr int ZERO_BASE = OPS1;   // zeroed region = ps1+ps2+outs
constexpr int ZERO_CNT  = 73728;

typedef __attribute__((ext_vector_type(8))) short bf16x8;
typedef __attribute__((ext_vector_type(4))) float f32x4;

__device__ __forceinline__ unsigned short f2bf(float x) {
  __hip_bfloat16 h = __float2bfloat16(x);
  return *(unsigned short*)&h;
}
__device__ __forceinline__ float bf2f(unsigned short u) {
  __hip_bfloat16 h;
  *(unsigned short*)&h = u;
  return __bfloat162float(h);
}
// pack x as (hi, lo) bf16 pair in one uint (hi at lower address)
__device__ __forceinline__ unsigned int packhl(float x) {
  unsigned short hi = f2bf(x);
  float lo = x - bf2f(hi);
  unsigned short ls = f2bf(lo);
  return (unsigned)hi | ((unsigned)ls << 16);
}

// ---------------------------------------------------------------------------
// Wave-wide bitonic sort of 64 (value,index) pairs, descending, tie->low idx.
// ---------------------------------------------------------------------------
__device__ __forceinline__ void wave_sort64(float& v, int& m, int lane) {
#pragma unroll
  for (int k = 2; k <= 64; k <<= 1) {
#pragma unroll
    for (int j = k >> 1; j > 0; j >>= 1) {
      float pv = __shfl_xor(v, j);
      int   pm = __shfl_xor(m, j);
      bool iam_lower   = (lane & j) == 0;
      bool dir_desc    = (lane & k) == 0;
      bool p_better    = (pv > v) || (pv == v && pm < m);
      bool want_better = (dir_desc == iam_lower);
      bool take        = (p_better == want_better);
      v = take ? pv : v;
      m = take ? pm : m;
    }
  }
}

// ---------------------------------------------------------------------------
// K2 (FUSED): prep (weight pack/normalize/transpose + shadow zero) + KNN +
// edge + pos layer.  Weight pack now emits the FRAGMENT-MAJOR layout
// [ks][stacked row m][32 halves]: uint index (i>>4)*4096 + m*16 + (i&15).
// One wave's A-fragment in the gemm then reads a contiguous 1KB region
// (16B/lane) instead of 16 scattered 64B lines.  Values unchanged.
// ---------------------------------------------------------------------------
__global__ __launch_bounds__(512, 8) void knn_edge_kernel(
    const float* __restrict__ pc, const float* __restrict__ Wpos,
    const float* __restrict__ Dp,
    const float* __restrict__ W1, const float* __restrict__ D1,
    const float* __restrict__ W2, const float* __restrict__ D2,
    const float* __restrict__ W3, const float* __restrict__ D3,
    float* __restrict__ ws) {
  __shared__ float4 spt[N];                   // 32 KB (2x,2y,2z,xx)
  __shared__ unsigned short sbuf[QPW][192];   // 3 KB
  __shared__ float4 snb[QPW][KNN];            // 2.5 KB halved neighbor coords
  int tid = threadIdx.x;
  int b = blockIdx.y;
  int bid = blockIdx.y * gridDim.x + blockIdx.x;  // 0..2047
  int wv = tid >> 6, lane = tid & 63;
  unsigned short* Xp0 = (unsigned short*)(ws + OXP0);

  // ---- folded prep: distributed shadow zeroing (1 store/thread) ----------
  {
    int zi = bid * 512 + tid;
    if (zi < ZERO_CNT) ws[ZERO_BASE + zi] = 0.f;
  }
  // ---- folded prep: 768 weight rows over blocks 0..95 (one wave/row) -----
  if (bid < 96) {
    int rr = bid * 8 + wv;  // 0..767
    const float* src;
    float* tdst = nullptr;
    unsigned int* pdst;   // base of fragment-major region + m*16
    int C, Cpack;
    bool norm;
    if (rr < 128)      { src = W1 + rr * 64;            C = 64;  Cpack = 64;  norm = true;
                         pdst = (unsigned int*)(ws + OWB1) + rr * 16; }
    else if (rr < 256) { int m = rr - 128; src = D1 + m * 64;  C = 64;  Cpack = 64;  norm = false;
                         pdst = (unsigned int*)(ws + OWB1) + (m + 128) * 16; }
    else if (rr < 384) { int m = rr - 256; src = W2 + m * 256; C = 256; Cpack = 128; norm = true;
                         pdst = (unsigned int*)(ws + OWB2) + m * 16; tdst = ws + OWT2 + m; }
    else if (rr < 512) { int m = rr - 384; src = D2 + m * 256; C = 256; Cpack = 128; norm = false;
                         pdst = (unsigned int*)(ws + OWB2) + (m + 128) * 16; tdst = ws + OWT2 + 128 + m; }
    else if (rr < 640) { int m = rr - 512; src = W3 + m * 256; C = 256; Cpack = 128; norm = true;
                         pdst = (unsigned int*)(ws + OWB3) + m * 16; tdst = ws + OWT3 + m; }
    else               { int m = rr - 640; src = D3 + m * 256; C = 256; Cpack = 128; norm = false;
                         pdst = (unsigned int*)(ws + OWB3) + (m + 128) * 16; tdst = ws + OWT3 + 128 + m; }
    float s = 1.f;
    if (norm) {
      float a = 0.f;
      for (int i = lane; i < C; i += 64) a += src[i];
#pragma unroll
      for (int off = 32; off > 0; off >>= 1) a += __shfl_xor(a, off);
      s = a;
    }
    for (int i = lane; i < C; i += 64) {
      float val = src[i] / s;  // exact when s==1
      if (i < Cpack) pdst[(i >> 4) * 4096 + (i & 15)] = packhl(val);
      if (tdst && i >= 128) tdst[(i - 128) * 256] = val;
    }
  }

  // ---- stage point cloud ---------------------------------------------------
  const float* pcb = pc + (size_t)b * N * 3;
  for (int i = tid; i < N; i += 512) {
    float x = pcb[i * 3 + 0], y = pcb[i * 3 + 1], z = pcb[i * 3 + 2];
    float xx = __fadd_rn(__fadd_rn(__fmul_rn(x, x), __fmul_rn(y, y)), __fmul_rn(z, z));
    spt[i] = make_float4(2.f * x, 2.f * y, 2.f * z, xx);
  }
  __syncthreads();
  int q = blockIdx.x * QPW + wv;
  float4 qp = spt[q];
  float qx = 0.5f * qp.x, qy = 0.5f * qp.y, qz = 0.5f * qp.z, qxx = qp.w;

  float dv[32];
  float lmax = -INFINITY;
#pragma unroll
  for (int i = 0; i < 32; ++i) {
    float4 m = spt[i * 64 + lane];
    float A = __fadd_rn(__fadd_rn(__fmul_rn(m.x, qx), __fmul_rn(m.y, qy)),
                        __fmul_rn(m.z, qz));
    float d = __fsub_rn(__fsub_rn(A, qxx), m.w);
    dv[i] = d;
    lmax = fmaxf(lmax, d);
  }

  // value-only bitonic sort (descending) of the 64 lane-maxes; take #19
  float sv = lmax;
#pragma unroll
  for (int k = 2; k <= 64; k <<= 1) {
#pragma unroll
    for (int j = k >> 1; j > 0; j >>= 1) {
      float pv = __shfl_xor(sv, j);
      bool keep_max = ((lane & k) == 0) == ((lane & j) == 0);
      sv = keep_max ? fmaxf(sv, pv) : fminf(sv, pv);
    }
  }
  float tval = __shfl(sv, 19);  // 20th-largest lane-max <= V20 (provable)

  // registerized compact: per-lane survivor mask + shfl prefix scan
  unsigned msk = 0u;
#pragma unroll
  for (int i = 0; i < 32; ++i) msk |= (dv[i] >= tval) ? (1u << i) : 0u;
  int cnt = __popc(msk);
  int scan = cnt;
#pragma unroll
  for (int off = 1; off < 64; off <<= 1) {
    int t = __shfl_up(scan, off);
    scan += (lane >= off) ? t : 0;
  }
  int S = __shfl(scan, 63);
  int pos = scan - cnt;  // exclusive prefix
  unsigned mm = msk;
  while (mm) {
    int i = __ffs(mm) - 1;
    mm &= mm - 1;
    if (pos < 192) sbuf[wv][pos] = (unsigned short)(i * 64 + lane);
    ++pos;
  }

  auto distOf = [&](int m) -> float {
    float4 mp = spt[m];
    float A = __fadd_rn(__fadd_rn(__fmul_rn(mp.x, qx), __fmul_rn(mp.y, qy)),
                        __fmul_rn(mp.z, qz));
    return __fsub_rn(__fsub_rn(A, qxx), mp.w);
  };

  float cv = -INFINITY;
  int cm = 0x7fffffff;
  if (S <= 64) {
    if (lane < S) { cm = sbuf[wv][lane]; cv = distOf(cm); }
    wave_sort64(cv, cm, lane);
  } else if (S <= 192) {
    int p2 = 0;
    while (p2 < S) {
      if (lane >= KNN) {
        int t = p2 + lane - KNN;
        if (t < S) { cm = sbuf[wv][t]; cv = distOf(cm); }
        else       { cm = 0x7fffffff;  cv = -INFINITY; }
      }
      wave_sort64(cv, cm, lane);
      p2 += 64 - KNN;
    }
  } else {
    int p2 = 0;
    while (p2 < N) {
      if (lane >= KNN) {
        int t = p2 + lane - KNN;
        if (t < N) { cm = t; cv = distOf(t); }
        else       { cm = 0x7fffffff; cv = -INFINITY; }
      }
      wave_sort64(cv, cm, lane);
      p2 += 64 - KNN;
    }
  }

  // ---- edge + pos layer (lane o = channel o) -------------------------------
  if (lane < KNN) {
    float4 t = spt[cm];
    snb[wv][lane] = make_float4(0.5f * t.x, 0.5f * t.y, 0.5f * t.z, 0.f);
  }
  int o = lane;
  // per-lane W_pos row normalization (bit-identical to old prep)
  float w0 = Wpos[o * 3 + 0], w1 = Wpos[o * 3 + 1], w2 = Wpos[o * 3 + 2];
  {
    float s = (w0 + w2) + w1;
    w0 = w0 / s; w1 = w1 / s; w2 = w2 / s;
  }
  float e0 = Dp[o * 3 + 0], e1 = Dp[o * 3 + 1], e2 = Dp[o * 3 + 2];
  float cx = qx, cy = qy, cz = qz;  // exact raw coords (0.5 * 2x)
  float pcx = w1 * cx, pcy = w1 * cy, pcz = w1 * cz;
  float dcx = e1 * cx, dcy = e1 * cy, dcz = e1 * cz;
  float ax = 0.f, ay = 0.f, az = 0.f;
#pragma unroll 4
  for (int k = 0; k < KNN; ++k) {
    float4 nb = snb[wv][k];   // broadcast LDS read
    float nx = nb.x, ny = nb.y, nz = nb.z;
    float ex = nx - cx, ey = ny - cy, ez = nz - cz;
    float rx = ny * cz - nz * cy;
    float ry = nz * cx - nx * cz;
    float rz = nx * cy - ny * cx;
    float px = fmaf(w0, ex, fmaf(w2, rx, pcx));
    float py = fmaf(w0, ey, fmaf(w2, ry, pcy));
    float pz = fmaf(w0, ez, fmaf(w2, rz, pcz));
    float dx = fmaf(e0, ex, fmaf(e2, rx, dcx));
    float dy = fmaf(e0, ey, fmaf(e2, ry, dcy));
    float dz = fmaf(e0, ez, fmaf(e2, rz, dcz));
    float dot = fmaf(px, dx, fmaf(py, dy, pz * dz));
    float dns = fmaf(dx, dx, fmaf(dy, dy, dz * dz)) + 1e-6f;
    float r0 = __builtin_amdgcn_rcpf(dns);
    r0 = r0 * fmaf(-dns, r0, 2.0f);          // 1 Newton step
    float f = (dot < 0.f) ? dot * r0 : 0.f;
    ax = fmaf(-f, dx, px) + ax;
    ay = fmaf(-f, dy, py) + ay;
    az = fmaf(-f, dz, pz) + az;
  }
  // store channel o of pixel q; contiguous 256B per (v) wave-store
  int pbase = ((q >> 4) * 48) + (q & 15);
  unsigned short* dst = Xp0 + ((size_t)b * P + pbase) * 128 + 2 * o;
  *(unsigned int*)(dst)              = packhl(ax * (1.f / 20.f));
  *(unsigned int*)(dst + 16 * 128)   = packhl(ay * (1.f / 20.f));
  *(unsigned int*)(dst + 32 * 128)   = packhl(az * (1.f / 20.f));
}

// ---------------------------------------------------------------------------
// K9: merge 8 out shadows -> d_out (mean over N).
// ---------------------------------------------------------------------------
__global__ __launch_bounds__(256) void out_merge_kernel(
    const float* __restrict__ outs, float* __restrict__ out) {
  int idx = blockIdx.x * 256 + threadIdx.x;  // 3072
  if (idx >= B * 384) return;
  float s = 0.f;
#pragma unroll
  for (int k = 0; k < 8; ++k) s += outs[k * 3072 + idx];
  out[idx] = s * (1.f / 2048.f);
}

// ---------------------------------------------------------------------------
// K4/K6/K8: MFMA VNT layer.  Weights now read from the FRAGMENT-MAJOR layout:
// one wave's A-fragment = contiguous 1KB (16B/lane), addr =
// (row + cl)*32 + q*8 + ks*8192 halves.  Register contents identical to the
// old scattered layout -> bit-identical results.  Everything else unchanged.
// ---------------------------------------------------------------------------
template <int K2, bool HASPOOL, bool LAST>
__global__ __launch_bounds__(256, 4) void gemm_vnt_kernel(
    const unsigned short* __restrict__ Xp, const unsigned short* __restrict__ Wb,
    const float* __restrict__ ps, const float* __restrict__ Wt,
    unsigned short* __restrict__ Xq, float* __restrict__ pool,
    float* __restrict__ outs) {
  constexpr int KS = K2 / 32;
  constexpr int LDR = K2 + 8;   // halves; X-tile row stride
  constexpr int LDO = 132;      // floats; out-tile row stride
  __shared__ __align__(16) char smem[48 * LDO * 4];  // 25344 B, dual-purpose
  unsigned short* xt = (unsigned short*)smem;
  float* ot = (float*)smem;
  __shared__ float sb[768];
  __shared__ float spool[384];
  int tid = threadIdx.x;
  int bid = blockIdx.x;
  int b = bid >> 7;
  int nt = bid & 127;
  int p0 = nt * 48;

  // stage X tile [48][K2] -> LDS
  for (int ch = tid; ch < 48 * (K2 / 8); ch += 256) {
    int rp = ch / (K2 / 8), cc = ch % (K2 / 8);
    *(uint4*)(xt + rp * LDR + cc * 8) =
        *(const uint4*)(Xp + ((size_t)b * P + p0 + rp) * K2 + cc * 8);
  }
  if (HASPOOL) {
    // pooled mean (sum of 8 shadow copies) -> LDS
    for (int i = tid; i < 384; i += 256) {
      float x = 0.f;
#pragma unroll
      for (int k = 0; k < 8; ++k) x += ps[k * 3072 + b * 384 + i];
      spool[i] = x * (1.f / 2048.f);
    }
  }
  __syncthreads();
  if (HASPOOL) {
    // bias prologue: thread == stacked row m (0..127 = Wn, 128..255 = D)
    float s0 = 0.f, s1 = 0.f, s2 = 0.f;
#pragma unroll 4
    for (int c = 0; c < 128; ++c) {
      float x = Wt[c * 256 + tid];
      s0 = fmaf(x, spool[c * 3 + 0], s0);
      s1 = fmaf(x, spool[c * 3 + 1], s1);
      s2 = fmaf(x, spool[c * 3 + 2], s2);
    }
    sb[tid * 3 + 0] = s0;
    sb[tid * 3 + 1] = s1;
    sb[tid * 3 + 2] = s2;
    __syncthreads();
  }

  int w = tid >> 6, lane = tid & 63;
  int q = lane >> 4, cl = lane & 15;

  f32x4 acc[2][2][3] = {};  // [t][pd][v]

  bf16x8 acur[2][2], anxt[2][2];
#pragma unroll
  for (int t = 0; t < 2; ++t)
#pragma unroll
    for (int pd = 0; pd < 2; ++pd)
      acur[t][pd] = *(const bf16x8*)(Wb +
          (size_t)(32 * w + 16 * t + 128 * pd + cl) * 32 + q * 8);

#pragma unroll
  for (int ks = 0; ks < KS; ++ks) {
    if (ks + 1 < KS) {
#pragma unroll
      for (int t = 0; t < 2; ++t)
#pragma unroll
        for (int pd = 0; pd < 2; ++pd)
          anxt[t][pd] = *(const bf16x8*)(Wb +
              (size_t)(32 * w + 16 * t + 128 * pd + cl) * 32 + q * 8 +
              (ks + 1) * 8192);
    }
    bf16x8 bb[3];
#pragma unroll
    for (int v = 0; v < 3; ++v)
      bb[v] = *(const bf16x8*)(xt + (v * 16 + cl) * LDR + ks * 32 + q * 8);
#pragma unroll
    for (int t = 0; t < 2; ++t)
#pragma unroll
      for (int pd = 0; pd < 2; ++pd)
#pragma unroll
        for (int v = 0; v < 3; ++v)
          acc[t][pd][v] = __builtin_amdgcn_mfma_f32_16x16x32_bf16(
              acur[t][pd], bb[v], acc[t][pd][v], 0, 0, 0);
#pragma unroll
    for (int t = 0; t < 2; ++t)
#pragma unroll
      for (int pd = 0; pd < 2; ++pd)
        acur[t][pd] = anxt[t][pd];
  }
  __syncthreads();  // X-tile dead; buffer becomes the fp32 out-tile

#pragma unroll
  for (int t = 0; t < 2; ++t) {
    float res[3][4];
#pragma unroll
    for (int r = 0; r < 4; ++r) {
      int o = 32 * w + 16 * t + 4 * q + r;
      float pv[3], dvv[3];
#pragma unroll
      for (int v = 0; v < 3; ++v) {
        pv[v] = acc[t][0][v][r] + (HASPOOL ? sb[o * 3 + v] : 0.f);
        dvv[v] = acc[t][1][v][r] + (HASPOOL ? sb[(128 + o) * 3 + v] : 0.f);
      }
      float dot = fmaf(pv[0], dvv[0], fmaf(pv[1], dvv[1], pv[2] * dvv[2]));
      float dns = fmaf(dvv[0], dvv[0], fmaf(dvv[1], dvv[1], dvv[2] * dvv[2]));
      float f = (dot < 0.f) ? dot / (dns + 1e-6f) : 0.f;
#pragma unroll
      for (int v = 0; v < 3; ++v) res[v][r] = pv[v] - f * dvv[v];
    }
    int o0 = 32 * w + 16 * t + 4 * q;
#pragma unroll
    for (int v = 0; v < 3; ++v) {
      f32x4 rv = {res[v][0], res[v][1], res[v][2], res[v][3]};
      *(f32x4*)(ot + (v * 16 + cl) * LDO + o0) = rv;
    }
  }
  __syncthreads();

  int shadow = (nt & 7) * 3072;
  for (int s = tid; s < 384; s += 256) {
    int o = s / 3, v = s % 3;
    float a2 = 0.f;
#pragma unroll
    for (int c = 0; c < 16; ++c) a2 += ot[(v * 16 + c) * LDO + o];
    if (LAST) atomicAdd(outs + shadow + b * 384 + s, a2);
    else      atomicAdd(pool + shadow + b * 384 + s, a2);
  }

  if (!LAST) {
    for (int s = tid; s < 1536; s += 256) {
      int pix = s >> 5, c4 = s & 31;
      const float* src = ot + pix * LDO + c4 * 4;
      uint4 vv;
      vv.x = packhl(src[0]);
      vv.y = packhl(src[1]);
      vv.z = packhl(src[2]);
      vv.w = packhl(src[3]);
      *(uint4*)(Xq + ((size_t)b * P + p0 + pix) * 256 + c4 * 8) = vv;
    }
  }
}

// ---------------------------------------------------------------------------
// launch
// ---------------------------------------------------------------------------
extern "C" void kernel_launch(void* const* d_in, const int* in_sizes, int n_in,
                              void* d_out, int out_size, void* d_ws, size_t ws_size,
                              hipStream_t stream) {
  (void)in_sizes; (void)n_in; (void)out_size; (void)ws_size;
  const float* pc   = (const float*)d_in[0];
  const float* Wpos = (const float*)d_in[1];
  const float* Dpos = (const float*)d_in[2];
  const float* W1   = (const float*)d_in[3];
  const float* D1   = (const float*)d_in[4];
  const float* W2   = (const float*)d_in[5];
  const float* D2   = (const float*)d_in[6];
  const float* W3   = (const float*)d_in[7];
  const float* D3   = (const float*)d_in[8];
  float* out = (float*)d_out;
  float* ws  = (float*)d_ws;

  // fused prep + KNN + edge + pos layer -> Xp0 (+ packed weights, zeroed shadows)
  knn_edge_kernel<<<dim3(N / QPW, B), 512, 0, stream>>>(
      pc, Wpos, Dpos, W1, D1, W2, D2, W3, D3, ws);
  // layer1: K2=128 -> Xp1 + ps1 shadows
  gemm_vnt_kernel<128, false, false><<<1024, 256, 0, stream>>>(
      (const unsigned short*)(ws + OXP0), (const unsigned short*)(ws + OWB1),
      nullptr, nullptr, (unsigned short*)(ws + OXP1), ws + OPS1, nullptr);
  // layer2: bias prologue from ps1 + WT2 -> Xp2 + ps2 shadows
  gemm_vnt_kernel<256, true, false><<<1024, 256, 0, stream>>>(
      (const unsigned short*)(ws + OXP1), (const unsigned short*)(ws + OWB2),
      ws + OPS1, ws + OWT2, (unsigned short*)(ws + OXP2), ws + OPS2, nullptr);
  // layer3: bias prologue from ps2 + WT3 -> out shadows
  gemm_vnt_kernel<256, true, true><<<1024, 256, 0, stream>>>(
      (const unsigned short*)(ws + OXP2), (const unsigned short*)(ws + OWB3),
      ws + OPS2, ws + OWT3, nullptr, nullptr, ws + OOUTS);
  out_merge_kernel<<<12, 256, 0, stream>>>(ws + OOUTS, out);
}

// Round 16
// 176.838 us; speedup vs baseline: 1.3213x; 1.0157x over previous
//
#include <hip/hip_runtime.h>
#include <hip/hip_bf16.h>
#include <math.h>

// ---------------------------------------------------------------------------
// Problem constants
// ---------------------------------------------------------------------------
constexpr int B = 8;
constexpr int N = 2048;
constexpr int KNN = 20;
constexpr int H = 128;
constexpr int P = 3 * N;  // 6144 pixels per batch
constexpr int QPW = 8;    // queries (waves) per knn_edge block

// ws layout (float offsets)
constexpr int OWT2   = 8448;      // W2/D2 second-half TRANSPOSED [c<128][m<256] (32768)
constexpr int OWT3   = 41216;     // W3/D3 second-half transposed (32768)
constexpr int OPS1   = 73984;     // poolsum1 shadows [8][B][128][3] = 24576
constexpr int OPS2   = 98560;     // poolsum2 shadows = 24576
constexpr int OOUTS  = 123136;    // out shadows [8][B][384] = 24576
constexpr int OWB1   = 160000;    // Wbig1 bf16 hi/lo, FRAGMENT-MAJOR [ks][256][32h] (16384 f)
constexpr int OWB2   = 176384;    // Wbig2 fragment-major (32768 f)
constexpr int OWB3   = 209152;    // Wbig3 fragment-major (32768 f)
constexpr int OXP0   = 569600;    // Xp0 bf16 [b][P][128] (3145728 f-equiv)
constexpr int OXP2   = 569600;    // Xp2 bf16 [b][P][256] reuses Xp0 region
constexpr int OXP1   = 6861056;   // Xp1 bf16 [b][P][256] (6291456 f-equiv)
// max extent 13,152,512 floats ~= 52.6 MB

constexpr int ZERO_BASE = OPS1;   // zeroed region = ps1+ps2+outs
constexpr int ZERO_CNT  = 73728;

typedef __attribute__((ext_vector_type(8))) short bf16x8;
typedef __attribute__((ext_vector_type(4))) float f32x4;

__device__ __forceinline__ unsigned short f2bf(float x) {
  __hip_bfloat16 h = __float2bfloat16(x);
  return *(unsigned short*)&h;
}
__device__ __forceinline__ float bf2f(unsigned short u) {
  __hip_bfloat16 h;
  *(unsigned short*)&h = u;
  return __bfloat162float(h);
}
// pack x as (hi, lo) bf16 pair in one uint (hi at lower address)
__device__ __forceinline__ unsigned int packhl(float x) {
  unsigned short hi = f2bf(x);
  float lo = x - bf2f(hi);
  unsigned short ls = f2bf(lo);
  return (unsigned)hi | ((unsigned)ls << 16);
}

// ---------------------------------------------------------------------------
// Wave-wide bitonic sort of 64 u64 keys, descending (larger key = better).
// Key = ord(value)<<32 | ~index  ==>  value desc, ties -> smaller index.
// Isomorphic to the proven (value,index) comparator sort.
// ---------------------------------------------------------------------------
__device__ __forceinline__ void wave_sort_key(unsigned long long& k, int lane) {
#pragma unroll
  for (int kk = 2; kk <= 64; kk <<= 1) {
#pragma unroll
    for (int j = kk >> 1; j > 0; j >>= 1) {
      unsigned long long pk =
          (unsigned long long)__shfl_xor((long long)k, j);
      bool iam_lower   = (lane & j) == 0;
      bool dir_desc    = (lane & kk) == 0;
      bool p_better    = pk > k;
      bool want_better = (dir_desc == iam_lower);
      k = (p_better == want_better) ? pk : k;
    }
  }
}

// ---------------------------------------------------------------------------
// K2 (FUSED): prep (weight pack fragment-major + normalize + transpose +
// shadow zero) + exact top-20 KNN + edge + pos layer + mean-k -> Xp0.
// Round 16 VALU diet: u64-key survivor sort; per-neighbor e/r geometry
// computed once by lane k<20 and stashed in LDS (overlays the dead sbuf
// region); Wpos/Dp loads hoisted to kernel entry.
// ---------------------------------------------------------------------------
__global__ __launch_bounds__(512, 8) void knn_edge_kernel(
    const float* __restrict__ pc, const float* __restrict__ Wpos,
    const float* __restrict__ Dp,
    const float* __restrict__ W1, const float* __restrict__ D1,
    const float* __restrict__ W2, const float* __restrict__ D2,
    const float* __restrict__ W3, const float* __restrict__ D3,
    float* __restrict__ ws) {
  __shared__ float4 spt[N];                       // 32 KB (2x,2y,2z,xx)
  // per-wave union: phase1 = survivor idx buffer (192 u16 = 384B),
  //                 phase2 = e/r stash (20 x 32B = 640B)
  __shared__ __align__(16) unsigned char sphase[QPW][640];   // 5 KB
  int tid = threadIdx.x;
  int b = blockIdx.y;
  int bid = blockIdx.y * gridDim.x + blockIdx.x;  // 0..2047
  int wv = tid >> 6, lane = tid & 63;
  unsigned short* Xp0 = (unsigned short*)(ws + OXP0);
  unsigned short* sbufw = (unsigned short*)sphase[wv];
  float4* erw = (float4*)sphase[wv];

  // hoisted edge-phase weight loads (latency hidden under distance pass)
  int o = lane;
  float w0 = Wpos[o * 3 + 0], w1 = Wpos[o * 3 + 1], w2 = Wpos[o * 3 + 2];
  float e0 = Dp[o * 3 + 0], e1 = Dp[o * 3 + 1], e2 = Dp[o * 3 + 2];

  // ---- folded prep: distributed shadow zeroing (1 store/thread) ----------
  {
    int zi = bid * 512 + tid;
    if (zi < ZERO_CNT) ws[ZERO_BASE + zi] = 0.f;
  }
  // ---- folded prep: 768 weight rows over blocks 0..95 (one wave/row) -----
  if (bid < 96) {
    int rr = bid * 8 + wv;  // 0..767
    const float* src;
    float* tdst = nullptr;
    unsigned int* pdst;   // base of fragment-major region + m*16
    int C, Cpack;
    bool norm;
    if (rr < 128)      { src = W1 + rr * 64;            C = 64;  Cpack = 64;  norm = true;
                         pdst = (unsigned int*)(ws + OWB1) + rr * 16; }
    else if (rr < 256) { int m = rr - 128; src = D1 + m * 64;  C = 64;  Cpack = 64;  norm = false;
                         pdst = (unsigned int*)(ws + OWB1) + (m + 128) * 16; }
    else if (rr < 384) { int m = rr - 256; src = W2 + m * 256; C = 256; Cpack = 128; norm = true;
                         pdst = (unsigned int*)(ws + OWB2) + m * 16; tdst = ws + OWT2 + m; }
    else if (rr < 512) { int m = rr - 384; src = D2 + m * 256; C = 256; Cpack = 128; norm = false;
                         pdst = (unsigned int*)(ws + OWB2) + (m + 128) * 16; tdst = ws + OWT2 + 128 + m; }
    else if (rr < 640) { int m = rr - 512; src = W3 + m * 256; C = 256; Cpack = 128; norm = true;
                         pdst = (unsigned int*)(ws + OWB3) + m * 16; tdst = ws + OWT3 + m; }
    else               { int m = rr - 640; src = D3 + m * 256; C = 256; Cpack = 128; norm = false;
                         pdst = (unsigned int*)(ws + OWB3) + (m + 128) * 16; tdst = ws + OWT3 + 128 + m; }
    float s = 1.f;
    if (norm) {
      float a = 0.f;
      for (int i = lane; i < C; i += 64) a += src[i];
#pragma unroll
      for (int off = 32; off > 0; off >>= 1) a += __shfl_xor(a, off);
      s = a;
    }
    for (int i = lane; i < C; i += 64) {
      float val = src[i] / s;  // exact when s==1
      if (i < Cpack) pdst[(i >> 4) * 4096 + (i & 15)] = packhl(val);
      if (tdst && i >= 128) tdst[(i - 128) * 256] = val;
    }
  }

  // ---- stage point cloud ---------------------------------------------------
  const float* pcb = pc + (size_t)b * N * 3;
  for (int i = tid; i < N; i += 512) {
    float x = pcb[i * 3 + 0], y = pcb[i * 3 + 1], z = pcb[i * 3 + 2];
    float xx = __fadd_rn(__fadd_rn(__fmul_rn(x, x), __fmul_rn(y, y)), __fmul_rn(z, z));
    spt[i] = make_float4(2.f * x, 2.f * y, 2.f * z, xx);
  }
  __syncthreads();
  int q = blockIdx.x * QPW + wv;
  float4 qp = spt[q];
  float qx = 0.5f * qp.x, qy = 0.5f * qp.y, qz = 0.5f * qp.z, qxx = qp.w;

  float dv[32];
  float lmax = -INFINITY;
#pragma unroll
  for (int i = 0; i < 32; ++i) {
    float4 m = spt[i * 64 + lane];
    float A = __fadd_rn(__fadd_rn(__fmul_rn(m.x, qx), __fmul_rn(m.y, qy)),
                        __fmul_rn(m.z, qz));
    float d = __fsub_rn(__fsub_rn(A, qxx), m.w);
    dv[i] = d;
    lmax = fmaxf(lmax, d);
  }

  // value-only bitonic sort (descending) of the 64 lane-maxes; take #19
  float sv = lmax;
#pragma unroll
  for (int k = 2; k <= 64; k <<= 1) {
#pragma unroll
    for (int j = k >> 1; j > 0; j >>= 1) {
      float pv = __shfl_xor(sv, j);
      bool keep_max = ((lane & k) == 0) == ((lane & j) == 0);
      sv = keep_max ? fmaxf(sv, pv) : fminf(sv, pv);
    }
  }
  float tval = __shfl(sv, 19);  // 20th-largest lane-max <= V20 (provable)

  // registerized compact: per-lane survivor mask + shfl prefix scan
  unsigned msk = 0u;
#pragma unroll
  for (int i = 0; i < 32; ++i) msk |= (dv[i] >= tval) ? (1u << i) : 0u;
  int cnt = __popc(msk);
  int scan = cnt;
#pragma unroll
  for (int off = 1; off < 64; off <<= 1) {
    int t = __shfl_up(scan, off);
    scan += (lane >= off) ? t : 0;
  }
  int S = __shfl(scan, 63);
  int pos = scan - cnt;  // exclusive prefix
  unsigned mm = msk;
  while (mm) {
    int i = __ffs(mm) - 1;
    mm &= mm - 1;
    if (pos < 192) sbufw[pos] = (unsigned short)(i * 64 + lane);
    ++pos;
  }

  auto distOf = [&](int m) -> float {
    float4 mp = spt[m];
    float A = __fadd_rn(__fadd_rn(__fmul_rn(mp.x, qx), __fmul_rn(mp.y, qy)),
                        __fmul_rn(mp.z, qz));
    return __fsub_rn(__fsub_rn(A, qxx), mp.w);
  };
  auto mkkey = [&](int m) -> unsigned long long {
    float d = distOf(m);
    unsigned u = __float_as_uint(d);
    u ^= (u >> 31) ? 0xFFFFFFFFu : 0x80000000u;
    return ((unsigned long long)u << 32) | (unsigned)(~m);
  };

  unsigned long long key = 0ULL;  // padding key: below every real key
  if (S <= 64) {
    if (lane < S) key = mkkey(sbufw[lane]);
    wave_sort_key(key, lane);
  } else if (S <= 192) {
    int p2 = 0;
    while (p2 < S) {
      if (lane >= KNN) {
        int t = p2 + lane - KNN;
        key = (t < S) ? mkkey(sbufw[t]) : 0ULL;
      }
      wave_sort_key(key, lane);
      p2 += 64 - KNN;
    }
  } else {
    // exact full-scan fallback (never expected on this data)
    int p2 = 0;
    while (p2 < N) {
      if (lane >= KNN) {
        int t = p2 + lane - KNN;
        key = (t < N) ? mkkey(t) : 0ULL;
      }
      wave_sort_key(key, lane);
      p2 += 64 - KNN;
    }
  }
  int cm = ~((unsigned)key);  // valid in lanes 0..19

  // ---- edge geometry precompute: lane k<20 computes e/r once --------------
  // (bit-identical ops to the previous in-loop computation)
  if (lane < KNN) {
    float4 t = spt[cm];
    float nx = 0.5f * t.x, ny = 0.5f * t.y, nz = 0.5f * t.z;
    float ex = nx - qx, ey = ny - qy, ez = nz - qz;
    float rx = ny * qz - nz * qy;
    float ry = nz * qx - nx * qz;
    float rz = nx * qy - ny * qx;
    erw[2 * lane + 0] = make_float4(ex, ey, ez, 0.f);
    erw[2 * lane + 1] = make_float4(rx, ry, rz, 0.f);
  }

  // ---- edge + pos layer (lane o = channel o) -------------------------------
  // per-lane W_pos row normalization (bit-identical to old prep)
  {
    float s = (w0 + w2) + w1;
    w0 = w0 / s; w1 = w1 / s; w2 = w2 / s;
  }
  float cx = qx, cy = qy, cz = qz;  // exact raw coords (0.5 * 2x)
  float pcx = w1 * cx, pcy = w1 * cy, pcz = w1 * cz;
  float dcx = e1 * cx, dcy = e1 * cy, dcz = e1 * cz;
  float ax = 0.f, ay = 0.f, az = 0.f;
#pragma unroll 4
  for (int k = 0; k < KNN; ++k) {
    float4 e4 = erw[2 * k + 0];   // broadcast LDS reads
    float4 r4 = erw[2 * k + 1];
    float ex = e4.x, ey = e4.y, ez = e4.z;
    float rx = r4.x, ry = r4.y, rz = r4.z;
    float px = fmaf(w0, ex, fmaf(w2, rx, pcx));
    float py = fmaf(w0, ey, fmaf(w2, ry, pcy));
    float pz = fmaf(w0, ez, fmaf(w2, rz, pcz));
    float dx = fmaf(e0, ex, fmaf(e2, rx, dcx));
    float dy = fmaf(e0, ey, fmaf(e2, ry, dcy));
    float dz = fmaf(e0, ez, fmaf(e2, rz, dcz));
    float dot = fmaf(px, dx, fmaf(py, dy, pz * dz));
    float dns = fmaf(dx, dx, fmaf(dy, dy, dz * dz)) + 1e-6f;
    float r0 = __builtin_amdgcn_rcpf(dns);
    r0 = r0 * fmaf(-dns, r0, 2.0f);          // 1 Newton step
    float f = (dot < 0.f) ? dot * r0 : 0.f;
    ax = fmaf(-f, dx, px) + ax;
    ay = fmaf(-f, dy, py) + ay;
    az = fmaf(-f, dz, pz) + az;
  }
  // store channel o of pixel q; contiguous 256B per (v) wave-store
  int pbase = ((q >> 4) * 48) + (q & 15);
  unsigned short* dst = Xp0 + ((size_t)b * P + pbase) * 128 + 2 * o;
  *(unsigned int*)(dst)              = packhl(ax * (1.f / 20.f));
  *(unsigned int*)(dst + 16 * 128)   = packhl(ay * (1.f / 20.f));
  *(unsigned int*)(dst + 32 * 128)   = packhl(az * (1.f / 20.f));
}

// ---------------------------------------------------------------------------
// K9: merge 8 out shadows -> d_out (mean over N).
// ---------------------------------------------------------------------------
__global__ __launch_bounds__(256) void out_merge_kernel(
    const float* __restrict__ outs, float* __restrict__ out) {
  int idx = blockIdx.x * 256 + threadIdx.x;  // 3072
  if (idx >= B * 384) return;
  float s = 0.f;
#pragma unroll
  for (int k = 0; k < 8; ++k) s += outs[k * 3072 + idx];
  out[idx] = s * (1.f / 2048.f);
}

// ---------------------------------------------------------------------------
// K4/K6/K8: MFMA VNT layer (fragment-major weights, LDS-staged X, in-kernel
// bias prologue, LDS out-tile epilogue; unchanged from round 15).
// ---------------------------------------------------------------------------
template <int K2, bool HASPOOL, bool LAST>
__global__ __launch_bounds__(256, 4) void gemm_vnt_kernel(
    const unsigned short* __restrict__ Xp, const unsigned short* __restrict__ Wb,
    const float* __restrict__ ps, const float* __restrict__ Wt,
    unsigned short* __restrict__ Xq, float* __restrict__ pool,
    float* __restrict__ outs) {
  constexpr int KS = K2 / 32;
  constexpr int LDR = K2 + 8;   // halves; X-tile row stride
  constexpr int LDO = 132;      // floats; out-tile row stride
  __shared__ __align__(16) char smem[48 * LDO * 4];  // 25344 B, dual-purpose
  unsigned short* xt = (unsigned short*)smem;
  float* ot = (float*)smem;
  __shared__ float sb[768];
  __shared__ float spool[384];
  int tid = threadIdx.x;
  int bid = blockIdx.x;
  int b = bid >> 7;
  int nt = bid & 127;
  int p0 = nt * 48;

  // stage X tile [48][K2] -> LDS
  for (int ch = tid; ch < 48 * (K2 / 8); ch += 256) {
    int rp = ch / (K2 / 8), cc = ch % (K2 / 8);
    *(uint4*)(xt + rp * LDR + cc * 8) =
        *(const uint4*)(Xp + ((size_t)b * P + p0 + rp) * K2 + cc * 8);
  }
  if (HASPOOL) {
    // pooled mean (sum of 8 shadow copies) -> LDS
    for (int i = tid; i < 384; i += 256) {
      float x = 0.f;
#pragma unroll
      for (int k = 0; k < 8; ++k) x += ps[k * 3072 + b * 384 + i];
      spool[i] = x * (1.f / 2048.f);
    }
  }
  __syncthreads();
  if (HASPOOL) {
    // bias prologue: thread == stacked row m (0..127 = Wn, 128..255 = D)
    float s0 = 0.f, s1 = 0.f, s2 = 0.f;
#pragma unroll 4
    for (int c = 0; c < 128; ++c) {
      float x = Wt[c * 256 + tid];
      s0 = fmaf(x, spool[c * 3 + 0], s0);
      s1 = fmaf(x, spool[c * 3 + 1], s1);
      s2 = fmaf(x, spool[c * 3 + 2], s2);
    }
    sb[tid * 3 + 0] = s0;
    sb[tid * 3 + 1] = s1;
    sb[tid * 3 + 2] = s2;
    __syncthreads();
  }

  int w = tid >> 6, lane = tid & 63;
  int q = lane >> 4, cl = lane & 15;

  f32x4 acc[2][2][3] = {};  // [t][pd][v]

  bf16x8 acur[2][2], anxt[2][2];
#pragma unroll
  for (int t = 0; t < 2; ++t)
#pragma unroll
    for (int pd = 0; pd < 2; ++pd)
      acur[t][pd] = *(const bf16x8*)(Wb +
          (size_t)(32 * w + 16 * t + 128 * pd + cl) * 32 + q * 8);

#pragma unroll
  for (int ks = 0; ks < KS; ++ks) {
    if (ks + 1 < KS) {
#pragma unroll
      for (int t = 0; t < 2; ++t)
#pragma unroll
        for (int pd = 0; pd < 2; ++pd)
          anxt[t][pd] = *(const bf16x8*)(Wb +
              (size_t)(32 * w + 16 * t + 128 * pd + cl) * 32 + q * 8 +
              (ks + 1) * 8192);
    }
    bf16x8 bb[3];
#pragma unroll
    for (int v = 0; v < 3; ++v)
      bb[v] = *(const bf16x8*)(xt + (v * 16 + cl) * LDR + ks * 32 + q * 8);
#pragma unroll
    for (int t = 0; t < 2; ++t)
#pragma unroll
      for (int pd = 0; pd < 2; ++pd)
#pragma unroll
        for (int v = 0; v < 3; ++v)
          acc[t][pd][v] = __builtin_amdgcn_mfma_f32_16x16x32_bf16(
              acur[t][pd], bb[v], acc[t][pd][v], 0, 0, 0);
#pragma unroll
    for (int t = 0; t < 2; ++t)
#pragma unroll
      for (int pd = 0; pd < 2; ++pd)
        acur[t][pd] = anxt[t][pd];
  }
  __syncthreads();  // X-tile dead; buffer becomes the fp32 out-tile

#pragma unroll
  for (int t = 0; t < 2; ++t) {
    float res[3][4];
#pragma unroll
    for (int r = 0; r < 4; ++r) {
      int o = 32 * w + 16 * t + 4 * q + r;
      float pv[3], dvv[3];
#pragma unroll
      for (int v = 0; v < 3; ++v) {
        pv[v] = acc[t][0][v][r] + (HASPOOL ? sb[o * 3 + v] : 0.f);
        dvv[v] = acc[t][1][v][r] + (HASPOOL ? sb[(128 + o) * 3 + v] : 0.f);
      }
      float dot = fmaf(pv[0], dvv[0], fmaf(pv[1], dvv[1], pv[2] * dvv[2]));
      float dns = fmaf(dvv[0], dvv[0], fmaf(dvv[1], dvv[1], dvv[2] * dvv[2]));
      float f = (dot < 0.f) ? dot / (dns + 1e-6f) : 0.f;
#pragma unroll
      for (int v = 0; v < 3; ++v) res[v][r] = pv[v] - f * dvv[v];
    }
    int o0 = 32 * w + 16 * t + 4 * q;
#pragma unroll
    for (int v = 0; v < 3; ++v) {
      f32x4 rv = {res[v][0], res[v][1], res[v][2], res[v][3]};
      *(f32x4*)(ot + (v * 16 + cl) * LDO + o0) = rv;
    }
  }
  __syncthreads();

  int shadow = (nt & 7) * 3072;
  for (int s = tid; s < 384; s += 256) {
    int o = s / 3, v = s % 3;
    float a2 = 0.f;
#pragma unroll
    for (int c = 0; c < 16; ++c) a2 += ot[(v * 16 + c) * LDO + o];
    if (LAST) atomicAdd(outs + shadow + b * 384 + s, a2);
    else      atomicAdd(pool + shadow + b * 384 + s, a2);
  }

  if (!LAST) {
    for (int s = tid; s < 1536; s += 256) {
      int pix = s >> 5, c4 = s & 31;
      const float* src = ot + pix * LDO + c4 * 4;
      uint4 vv;
      vv.x = packhl(src[0]);
      vv.y = packhl(src[1]);
      vv.z = packhl(src[2]);
      vv.w = packhl(src[3]);
      *(uint4*)(Xq + ((size_t)b * P + p0 + pix) * 256 + c4 * 8) = vv;
    }
  }
}

// ---------------------------------------------------------------------------
// launch
// ---------------------------------------------------------------------------
extern "C" void kernel_launch(void* const* d_in, const int* in_sizes, int n_in,
                              void* d_out, int out_size, void* d_ws, size_t ws_size,
                              hipStream_t stream) {
  (void)in_sizes; (void)n_in; (void)out_size; (void)ws_size;
  const float* pc   = (const float*)d_in[0];
  const float* Wpos = (const float*)d_in[1];
  const float* Dpos = (const float*)d_in[2];
  const float* W1   = (const float*)d_in[3];
  const float* D1   = (const float*)d_in[4];
  const float* W2   = (const float*)d_in[5];
  const float* D2   = (const float*)d_in[6];
  const float* W3   = (const float*)d_in[7];
  const float* D3   = (const float*)d_in[8];
  float* out = (float*)d_out;
  float* ws  = (float*)d_ws;

  // fused prep + KNN + edge + pos layer -> Xp0 (+ packed weights, zeroed shadows)
  knn_edge_kernel<<<dim3(N / QPW, B), 512, 0, stream>>>(
      pc, Wpos, Dpos, W1, D1, W2, D2, W3, D3, ws);
  // layer1: K2=128 -> Xp1 + ps1 shadows
  gemm_vnt_kernel<128, false, false><<<1024, 256, 0, stream>>>(
      (const unsigned short*)(ws + OXP0), (const unsigned short*)(ws + OWB1),
      nullptr, nullptr, (unsigned short*)(ws + OXP1), ws + OPS1, nullptr);
  // layer2: bias prologue from ps1 + WT2 -> Xp2 + ps2 shadows
  gemm_vnt_kernel<256, true, false><<<1024, 256, 0, stream>>>(
      (const unsigned short*)(ws + OXP1), (const unsigned short*)(ws + OWB2),
      ws + OPS1, ws + OWT2, (unsigned short*)(ws + OXP2), ws + OPS2, nullptr);
  // layer3: bias prologue from ps2 + WT3 -> out shadows
  gemm_vnt_kernel<256, true, true><<<1024, 256, 0, stream>>>(
      (const unsigned short*)(ws + OXP2), (const unsigned short*)(ws + OWB3),
      ws + OPS2, ws + OWT3, nullptr, nullptr, ws + OOUTS);
  out_merge_kernel<<<12, 256, 0, stream>>>(ws + OOUTS, out);
}

// Round 17
// 167.441 us; speedup vs baseline: 1.3954x; 1.0561x over previous
//
#include <hip/hip_runtime.h>
#include <hip/hip_bf16.h>
#include <math.h>

// ---------------------------------------------------------------------------
// Problem constants
// ---------------------------------------------------------------------------
constexpr int B = 8;
constexpr int N = 2048;
constexpr int KNN = 20;
constexpr int H = 128;
constexpr int P = 3 * N;  // 6144 pixels per batch
constexpr int QPW = 8;    // queries (waves) per knn_edge block

// ws layout (float offsets)
constexpr int OWT2   = 8448;      // W2/D2 second-half TRANSPOSED [c<128][m<256] (32768)
constexpr int OWT3   = 41216;     // W3/D3 second-half transposed (32768)
constexpr int OPS1   = 73984;     // poolsum1 shadows [8][B][128][3] = 24576
constexpr int OPS2   = 98560;     // poolsum2 shadows = 24576
constexpr int OOUTS  = 123136;    // out shadows [8][B][384] = 24576
constexpr int OWB1   = 160000;    // Wbig1 bf16 hi/lo, FRAGMENT-MAJOR [ks][256][32h] (16384 f)
constexpr int OWB2   = 176384;    // Wbig2 fragment-major (32768 f)
constexpr int OWB3   = 209152;    // Wbig3 fragment-major (32768 f)
constexpr int OXP0   = 569600;    // Xp0 bf16 [b][P][128] (3145728 f-equiv)
constexpr int OXP2   = 569600;    // Xp2 bf16 [b][P][256] reuses Xp0 region
constexpr int OXP1   = 6861056;   // Xp1 bf16 [b][P][256] (6291456 f-equiv)
// max extent 13,152,512 floats ~= 52.6 MB

constexpr int ZERO_BASE = OPS1;   // zeroed region = ps1+ps2+outs
constexpr int ZERO_CNT  = 73728;

typedef __attribute__((ext_vector_type(8))) short bf16x8;
typedef __attribute__((ext_vector_type(4))) float f32x4;

__device__ __forceinline__ unsigned short f2bf(float x) {
  __hip_bfloat16 h = __float2bfloat16(x);
  return *(unsigned short*)&h;
}
__device__ __forceinline__ float bf2f(unsigned short u) {
  __hip_bfloat16 h;
  *(unsigned short*)&h = u;
  return __bfloat162float(h);
}
// pack x as (hi, lo) bf16 pair in one uint (hi at lower address)
__device__ __forceinline__ unsigned int packhl(float x) {
  unsigned short hi = f2bf(x);
  float lo = x - bf2f(hi);
  unsigned short ls = f2bf(lo);
  return (unsigned)hi | ((unsigned)ls << 16);
}

// ---------------------------------------------------------------------------
// Wave-wide bitonic sort of 64 u64 keys, descending (larger key = better).
// Key = ord(value)<<32 | ~index  ==>  value desc, ties -> smaller index.
// ---------------------------------------------------------------------------
__device__ __forceinline__ void wave_sort_key(unsigned long long& k, int lane) {
#pragma unroll
  for (int kk = 2; kk <= 64; kk <<= 1) {
#pragma unroll
    for (int j = kk >> 1; j > 0; j >>= 1) {
      unsigned long long pk =
          (unsigned long long)__shfl_xor((long long)k, j);
      bool iam_lower   = (lane & j) == 0;
      bool dir_desc    = (lane & kk) == 0;
      bool p_better    = pk > k;
      bool want_better = (dir_desc == iam_lower);
      k = (p_better == want_better) ? pk : k;
    }
  }
}

// ---------------------------------------------------------------------------
// K2 (FUSED): prep + exact top-20 KNN + edge + pos layer + mean-k -> Xp0.
// (unchanged from round 16)
// ---------------------------------------------------------------------------
__global__ __launch_bounds__(512, 8) void knn_edge_kernel(
    const float* __restrict__ pc, const float* __restrict__ Wpos,
    const float* __restrict__ Dp,
    const float* __restrict__ W1, const float* __restrict__ D1,
    const float* __restrict__ W2, const float* __restrict__ D2,
    const float* __restrict__ W3, const float* __restrict__ D3,
    float* __restrict__ ws) {
  __shared__ float4 spt[N];                       // 32 KB (2x,2y,2z,xx)
  __shared__ __align__(16) unsigned char sphase[QPW][640];   // 5 KB
  int tid = threadIdx.x;
  int b = blockIdx.y;
  int bid = blockIdx.y * gridDim.x + blockIdx.x;  // 0..2047
  int wv = tid >> 6, lane = tid & 63;
  unsigned short* Xp0 = (unsigned short*)(ws + OXP0);
  unsigned short* sbufw = (unsigned short*)sphase[wv];
  float4* erw = (float4*)sphase[wv];

  // hoisted edge-phase weight loads (latency hidden under distance pass)
  int o = lane;
  float w0 = Wpos[o * 3 + 0], w1 = Wpos[o * 3 + 1], w2 = Wpos[o * 3 + 2];
  float e0 = Dp[o * 3 + 0], e1 = Dp[o * 3 + 1], e2 = Dp[o * 3 + 2];

  // ---- folded prep: distributed shadow zeroing (1 store/thread) ----------
  {
    int zi = bid * 512 + tid;
    if (zi < ZERO_CNT) ws[ZERO_BASE + zi] = 0.f;
  }
  // ---- folded prep: 768 weight rows over blocks 0..95 (one wave/row) -----
  if (bid < 96) {
    int rr = bid * 8 + wv;  // 0..767
    const float* src;
    float* tdst = nullptr;
    unsigned int* pdst;   // base of fragment-major region + m*16
    int C, Cpack;
    bool norm;
    if (rr < 128)      { src = W1 + rr * 64;            C = 64;  Cpack = 64;  norm = true;
                         pdst = (unsigned int*)(ws + OWB1) + rr * 16; }
    else if (rr < 256) { int m = rr - 128; src = D1 + m * 64;  C = 64;  Cpack = 64;  norm = false;
                         pdst = (unsigned int*)(ws + OWB1) + (m + 128) * 16; }
    else if (rr < 384) { int m = rr - 256; src = W2 + m * 256; C = 256; Cpack = 128; norm = true;
                         pdst = (unsigned int*)(ws + OWB2) + m * 16; tdst = ws + OWT2 + m; }
    else if (rr < 512) { int m = rr - 384; src = D2 + m * 256; C = 256; Cpack = 128; norm = false;
                         pdst = (unsigned int*)(ws + OWB2) + (m + 128) * 16; tdst = ws + OWT2 + 128 + m; }
    else if (rr < 640) { int m = rr - 512; src = W3 + m * 256; C = 256; Cpack = 128; norm = true;
                         pdst = (unsigned int*)(ws + OWB3) + m * 16; tdst = ws + OWT3 + m; }
    else               { int m = rr - 640; src = D3 + m * 256; C = 256; Cpack = 128; norm = false;
                         pdst = (unsigned int*)(ws + OWB3) + (m + 128) * 16; tdst = ws + OWT3 + 128 + m; }
    float s = 1.f;
    if (norm) {
      float a = 0.f;
      for (int i = lane; i < C; i += 64) a += src[i];
#pragma unroll
      for (int off = 32; off > 0; off >>= 1) a += __shfl_xor(a, off);
      s = a;
    }
    for (int i = lane; i < C; i += 64) {
      float val = src[i] / s;  // exact when s==1
      if (i < Cpack) pdst[(i >> 4) * 4096 + (i & 15)] = packhl(val);
      if (tdst && i >= 128) tdst[(i - 128) * 256] = val;
    }
  }

  // ---- stage point cloud ---------------------------------------------------
  const float* pcb = pc + (size_t)b * N * 3;
  for (int i = tid; i < N; i += 512) {
    float x = pcb[i * 3 + 0], y = pcb[i * 3 + 1], z = pcb[i * 3 + 2];
    float xx = __fadd_rn(__fadd_rn(__fmul_rn(x, x), __fmul_rn(y, y)), __fmul_rn(z, z));
    spt[i] = make_float4(2.f * x, 2.f * y, 2.f * z, xx);
  }
  __syncthreads();
  int q = blockIdx.x * QPW + wv;
  float4 qp = spt[q];
  float qx = 0.5f * qp.x, qy = 0.5f * qp.y, qz = 0.5f * qp.z, qxx = qp.w;

  float dv[32];
  float lmax = -INFINITY;
#pragma unroll
  for (int i = 0; i < 32; ++i) {
    float4 m = spt[i * 64 + lane];
    float A = __fadd_rn(__fadd_rn(__fmul_rn(m.x, qx), __fmul_rn(m.y, qy)),
                        __fmul_rn(m.z, qz));
    float d = __fsub_rn(__fsub_rn(A, qxx), m.w);
    dv[i] = d;
    lmax = fmaxf(lmax, d);
  }

  // value-only bitonic sort (descending) of the 64 lane-maxes; take #19
  float sv = lmax;
#pragma unroll
  for (int k = 2; k <= 64; k <<= 1) {
#pragma unroll
    for (int j = k >> 1; j > 0; j >>= 1) {
      float pv = __shfl_xor(sv, j);
      bool keep_max = ((lane & k) == 0) == ((lane & j) == 0);
      sv = keep_max ? fmaxf(sv, pv) : fminf(sv, pv);
    }
  }
  float tval = __shfl(sv, 19);  // 20th-largest lane-max <= V20 (provable)

  // registerized compact: per-lane survivor mask + shfl prefix scan
  unsigned msk = 0u;
#pragma unroll
  for (int i = 0; i < 32; ++i) msk |= (dv[i] >= tval) ? (1u << i) : 0u;
  int cnt = __popc(msk);
  int scan = cnt;
#pragma unroll
  for (int off = 1; off < 64; off <<= 1) {
    int t = __shfl_up(scan, off);
    scan += (lane >= off) ? t : 0;
  }
  int S = __shfl(scan, 63);
  int pos = scan - cnt;  // exclusive prefix
  unsigned mm = msk;
  while (mm) {
    int i = __ffs(mm) - 1;
    mm &= mm - 1;
    if (pos < 192) sbufw[pos] = (unsigned short)(i * 64 + lane);
    ++pos;
  }

  auto distOf = [&](int m) -> float {
    float4 mp = spt[m];
    float A = __fadd_rn(__fadd_rn(__fmul_rn(mp.x, qx), __fmul_rn(mp.y, qy)),
                        __fmul_rn(mp.z, qz));
    return __fsub_rn(__fsub_rn(A, qxx), mp.w);
  };
  auto mkkey = [&](int m) -> unsigned long long {
    float d = distOf(m);
    unsigned u = __float_as_uint(d);
    u ^= (u >> 31) ? 0xFFFFFFFFu : 0x80000000u;
    return ((unsigned long long)u << 32) | (unsigned)(~m);
  };

  unsigned long long key = 0ULL;  // padding key: below every real key
  if (S <= 64) {
    if (lane < S) key = mkkey(sbufw[lane]);
    wave_sort_key(key, lane);
  } else if (S <= 192) {
    int p2 = 0;
    while (p2 < S) {
      if (lane >= KNN) {
        int t = p2 + lane - KNN;
        key = (t < S) ? mkkey(sbufw[t]) : 0ULL;
      }
      wave_sort_key(key, lane);
      p2 += 64 - KNN;
    }
  } else {
    int p2 = 0;
    while (p2 < N) {
      if (lane >= KNN) {
        int t = p2 + lane - KNN;
        key = (t < N) ? mkkey(t) : 0ULL;
      }
      wave_sort_key(key, lane);
      p2 += 64 - KNN;
    }
  }
  int cm = ~((unsigned)key);  // valid in lanes 0..19

  // ---- edge geometry precompute: lane k<20 computes e/r once --------------
  if (lane < KNN) {
    float4 t = spt[cm];
    float nx = 0.5f * t.x, ny = 0.5f * t.y, nz = 0.5f * t.z;
    float ex = nx - qx, ey = ny - qy, ez = nz - qz;
    float rx = ny * qz - nz * qy;
    float ry = nz * qx - nx * qz;
    float rz = nx * qy - ny * qx;
    erw[2 * lane + 0] = make_float4(ex, ey, ez, 0.f);
    erw[2 * lane + 1] = make_float4(rx, ry, rz, 0.f);
  }

  // ---- edge + pos layer (lane o = channel o) -------------------------------
  {
    float s = (w0 + w2) + w1;
    w0 = w0 / s; w1 = w1 / s; w2 = w2 / s;
  }
  float cx = qx, cy = qy, cz = qz;  // exact raw coords (0.5 * 2x)
  float pcx = w1 * cx, pcy = w1 * cy, pcz = w1 * cz;
  float dcx = e1 * cx, dcy = e1 * cy, dcz = e1 * cz;
  float ax = 0.f, ay = 0.f, az = 0.f;
#pragma unroll 4
  for (int k = 0; k < KNN; ++k) {
    float4 e4 = erw[2 * k + 0];   // broadcast LDS reads
    float4 r4 = erw[2 * k + 1];
    float ex = e4.x, ey = e4.y, ez = e4.z;
    float rx = r4.x, ry = r4.y, rz = r4.z;
    float px = fmaf(w0, ex, fmaf(w2, rx, pcx));
    float py = fmaf(w0, ey, fmaf(w2, ry, pcy));
    float pz = fmaf(w0, ez, fmaf(w2, rz, pcz));
    float dx = fmaf(e0, ex, fmaf(e2, rx, dcx));
    float dy = fmaf(e0, ey, fmaf(e2, ry, dcy));
    float dz = fmaf(e0, ez, fmaf(e2, rz, dcz));
    float dot = fmaf(px, dx, fmaf(py, dy, pz * dz));
    float dns = fmaf(dx, dx, fmaf(dy, dy, dz * dz)) + 1e-6f;
    float r0 = __builtin_amdgcn_rcpf(dns);
    r0 = r0 * fmaf(-dns, r0, 2.0f);          // 1 Newton step
    float f = (dot < 0.f) ? dot * r0 : 0.f;
    ax = fmaf(-f, dx, px) + ax;
    ay = fmaf(-f, dy, py) + ay;
    az = fmaf(-f, dz, pz) + az;
  }
  int pbase = ((q >> 4) * 48) + (q & 15);
  unsigned short* dst = Xp0 + ((size_t)b * P + pbase) * 128 + 2 * o;
  *(unsigned int*)(dst)              = packhl(ax * (1.f / 20.f));
  *(unsigned int*)(dst + 16 * 128)   = packhl(ay * (1.f / 20.f));
  *(unsigned int*)(dst + 32 * 128)   = packhl(az * (1.f / 20.f));
}

// ---------------------------------------------------------------------------
// K9: merge 8 out shadows -> d_out (mean over N).
// ---------------------------------------------------------------------------
__global__ __launch_bounds__(256) void out_merge_kernel(
    const float* __restrict__ outs, float* __restrict__ out) {
  int idx = blockIdx.x * 256 + threadIdx.x;  // 3072
  if (idx >= B * 384) return;
  float s = 0.f;
#pragma unroll
  for (int k = 0; k < 8; ++k) s += outs[k * 3072 + idx];
  out[idx] = s * (1.f / 2048.f);
}

// ---------------------------------------------------------------------------
// K4/K6/K8: MFMA VNT layer.  Round-17 serial-latency fixes:
//  - acur (first A-fragments) loaded BEFORE the staging barrier (global,
//    LDS-independent -> latency overlaps the barrier drain);
//  - bias prologue loop at unroll 16 (16 Wt loads in flight instead of 4;
//    fmaf chain order unchanged -> bit-identical).
// ---------------------------------------------------------------------------
template <int K2, bool HASPOOL, bool LAST>
__global__ __launch_bounds__(256, 4) void gemm_vnt_kernel(
    const unsigned short* __restrict__ Xp, const unsigned short* __restrict__ Wb,
    const float* __restrict__ ps, const float* __restrict__ Wt,
    unsigned short* __restrict__ Xq, float* __restrict__ pool,
    float* __restrict__ outs) {
  constexpr int KS = K2 / 32;
  constexpr int LDR = K2 + 8;   // halves; X-tile row stride
  constexpr int LDO = 132;      // floats; out-tile row stride
  __shared__ __align__(16) char smem[48 * LDO * 4];  // 25344 B, dual-purpose
  unsigned short* xt = (unsigned short*)smem;
  float* ot = (float*)smem;
  __shared__ float sb[768];
  __shared__ float spool[384];
  int tid = threadIdx.x;
  int bid = blockIdx.x;
  int b = bid >> 7;
  int nt = bid & 127;
  int p0 = nt * 48;

  int w = tid >> 6, lane = tid & 63;
  int q = lane >> 4, cl = lane & 15;

  // stage X tile [48][K2] -> LDS
  for (int ch = tid; ch < 48 * (K2 / 8); ch += 256) {
    int rp = ch / (K2 / 8), cc = ch % (K2 / 8);
    *(uint4*)(xt + rp * LDR + cc * 8) =
        *(const uint4*)(Xp + ((size_t)b * P + p0 + rp) * K2 + cc * 8);
  }
  if (HASPOOL) {
    // pooled mean (sum of 8 shadow copies) -> LDS
    for (int i = tid; i < 384; i += 256) {
      float x = 0.f;
#pragma unroll
      for (int k = 0; k < 8; ++k) x += ps[k * 3072 + b * 384 + i];
      spool[i] = x * (1.f / 2048.f);
    }
  }

  // first A-fragments: global, LDS-independent -> issue before the barrier
  bf16x8 acur[2][2], anxt[2][2];
#pragma unroll
  for (int t = 0; t < 2; ++t)
#pragma unroll
    for (int pd = 0; pd < 2; ++pd)
      acur[t][pd] = *(const bf16x8*)(Wb +
          (size_t)(32 * w + 16 * t + 128 * pd + cl) * 32 + q * 8);

  __syncthreads();
  if (HASPOOL) {
    // bias prologue: thread == stacked row m (0..127 = Wn, 128..255 = D)
    float s0 = 0.f, s1 = 0.f, s2 = 0.f;
#pragma unroll 16
    for (int c = 0; c < 128; ++c) {
      float x = Wt[c * 256 + tid];
      s0 = fmaf(x, spool[c * 3 + 0], s0);
      s1 = fmaf(x, spool[c * 3 + 1], s1);
      s2 = fmaf(x, spool[c * 3 + 2], s2);
    }
    sb[tid * 3 + 0] = s0;
    sb[tid * 3 + 1] = s1;
    sb[tid * 3 + 2] = s2;
    __syncthreads();
  }

  f32x4 acc[2][2][3] = {};  // [t][pd][v]

#pragma unroll
  for (int ks = 0; ks < KS; ++ks) {
    if (ks + 1 < KS) {
#pragma unroll
      for (int t = 0; t < 2; ++t)
#pragma unroll
        for (int pd = 0; pd < 2; ++pd)
          anxt[t][pd] = *(const bf16x8*)(Wb +
              (size_t)(32 * w + 16 * t + 128 * pd + cl) * 32 + q * 8 +
              (ks + 1) * 8192);
    }
    bf16x8 bb[3];
#pragma unroll
    for (int v = 0; v < 3; ++v)
      bb[v] = *(const bf16x8*)(xt + (v * 16 + cl) * LDR + ks * 32 + q * 8);
#pragma unroll
    for (int t = 0; t < 2; ++t)
#pragma unroll
      for (int pd = 0; pd < 2; ++pd)
#pragma unroll
        for (int v = 0; v < 3; ++v)
          acc[t][pd][v] = __builtin_amdgcn_mfma_f32_16x16x32_bf16(
              acur[t][pd], bb[v], acc[t][pd][v], 0, 0, 0);
#pragma unroll
    for (int t = 0; t < 2; ++t)
#pragma unroll
      for (int pd = 0; pd < 2; ++pd)
        acur[t][pd] = anxt[t][pd];
  }
  __syncthreads();  // X-tile dead; buffer becomes the fp32 out-tile

#pragma unroll
  for (int t = 0; t < 2; ++t) {
    float res[3][4];
#pragma unroll
    for (int r = 0; r < 4; ++r) {
      int o = 32 * w + 16 * t + 4 * q + r;
      float pv[3], dvv[3];
#pragma unroll
      for (int v = 0; v < 3; ++v) {
        pv[v] = acc[t][0][v][r] + (HASPOOL ? sb[o * 3 + v] : 0.f);
        dvv[v] = acc[t][1][v][r] + (HASPOOL ? sb[(128 + o) * 3 + v] : 0.f);
      }
      float dot = fmaf(pv[0], dvv[0], fmaf(pv[1], dvv[1], pv[2] * dvv[2]));
      float dns = fmaf(dvv[0], dvv[0], fmaf(dvv[1], dvv[1], dvv[2] * dvv[2]));
      float f = (dot < 0.f) ? dot / (dns + 1e-6f) : 0.f;
#pragma unroll
      for (int v = 0; v < 3; ++v) res[v][r] = pv[v] - f * dvv[v];
    }
    int o0 = 32 * w + 16 * t + 4 * q;
#pragma unroll
    for (int v = 0; v < 3; ++v) {
      f32x4 rv = {res[v][0], res[v][1], res[v][2], res[v][3]};
      *(f32x4*)(ot + (v * 16 + cl) * LDO + o0) = rv;
    }
  }
  __syncthreads();

  int shadow = (nt & 7) * 3072;
  for (int s = tid; s < 384; s += 256) {
    int o = s / 3, v = s % 3;
    float a2 = 0.f;
#pragma unroll
    for (int c = 0; c < 16; ++c) a2 += ot[(v * 16 + c) * LDO + o];
    if (LAST) atomicAdd(outs + shadow + b * 384 + s, a2);
    else      atomicAdd(pool + shadow + b * 384 + s, a2);
  }

  if (!LAST) {
    for (int s = tid; s < 1536; s += 256) {
      int pix = s >> 5, c4 = s & 31;
      const float* src = ot + pix * LDO + c4 * 4;
      uint4 vv;
      vv.x = packhl(src[0]);
      vv.y = packhl(src[1]);
      vv.z = packhl(src[2]);
      vv.w = packhl(src[3]);
      *(uint4*)(Xq + ((size_t)b * P + p0 + pix) * 256 + c4 * 8) = vv;
    }
  }
}

// ---------------------------------------------------------------------------
// launch
// ---------------------------------------------------------------------------
extern "C" void kernel_launch(void* const* d_in, const int* in_sizes, int n_in,
                              void* d_out, int out_size, void* d_ws, size_t ws_size,
                              hipStream_t stream) {
  (void)in_sizes; (void)n_in; (void)out_size; (void)ws_size;
  const float* pc   = (const float*)d_in[0];
  const float* Wpos = (const float*)d_in[1];
  const float* Dpos = (const float*)d_in[2];
  const float* W1   = (const float*)d_in[3];
  const float* D1   = (const float*)d_in[4];
  const float* W2   = (const float*)d_in[5];
  const float* D2   = (const float*)d_in[6];
  const float* W3   = (const float*)d_in[7];
  const float* D3   = (const float*)d_in[8];
  float* out = (float*)d_out;
  float* ws  = (float*)d_ws;

  // fused prep + KNN + edge + pos layer -> Xp0 (+ packed weights, zeroed shadows)
  knn_edge_kernel<<<dim3(N / QPW, B), 512, 0, stream>>>(
      pc, Wpos, Dpos, W1, D1, W2, D2, W3, D3, ws);
  // layer1: K2=128 -> Xp1 + ps1 shadows
  gemm_vnt_kernel<128, false, false><<<1024, 256, 0, stream>>>(
      (const unsigned short*)(ws + OXP0), (const unsigned short*)(ws + OWB1),
      nullptr, nullptr, (unsigned short*)(ws + OXP1), ws + OPS1, nullptr);
  // layer2: bias prologue from ps1 + WT2 -> Xp2 + ps2 shadows
  gemm_vnt_kernel<256, true, false><<<1024, 256, 0, stream>>>(
      (const unsigned short*)(ws + OXP1), (const unsigned short*)(ws + OWB2),
      ws + OPS1, ws + OWT2, (unsigned short*)(ws + OXP2), ws + OPS2, nullptr);
  // layer3: bias prologue from ps2 + WT3 -> out shadows
  gemm_vnt_kernel<256, true, true><<<1024, 256, 0, stream>>>(
      (const unsigned short*)(ws + OXP2), (const unsigned short*)(ws + OWB3),
      ws + OPS2, ws + OWT3, nullptr, nullptr, ws + OOUTS);
  out_merge_kernel<<<12, 256, 0, stream>>>(ws + OOUTS, out);
}